// Round 1
// baseline (4388.445 us; speedup 1.0000x reference)
//
#include <hip/hip_runtime.h>
#include <math.h>

#define TOK 1568      // B*N = 8*196
#define DIM 768
#define HN 12
#define SEQ 196
#define YD 64
#define MXI 3072
#define BETA_F 0.125f
#define INV_BETA 8.0f
#define LN_EPS_F 1e-5f

// ------------------------------------------------------------------
// LayerNorm forward: per-token block (256 thr, 3 elems/thread)
// ------------------------------------------------------------------
__global__ __launch_bounds__(256) void ln_fwd_k(
    const float* __restrict__ x, const float* __restrict__ gamma,
    const float* __restrict__ delta, float* __restrict__ g,
    float* __restrict__ xhat, float* __restrict__ rstd, int store_stats)
{
  __shared__ float s[4];
  int tok = blockIdx.x;
  int tid = threadIdx.x;
  const float* xp = x + (size_t)tok * DIM;
  float v0 = xp[tid], v1 = xp[tid + 256], v2 = xp[tid + 512];
  float sum = v0 + v1 + v2;
  for (int o = 32; o; o >>= 1) sum += __shfl_xor(sum, o, 64);
  if ((tid & 63) == 0) s[tid >> 6] = sum;
  __syncthreads();
  float mu = (s[0] + s[1] + s[2] + s[3]) * (1.0f / DIM);
  __syncthreads();
  float d0 = v0 - mu, d1 = v1 - mu, d2 = v2 - mu;
  float sq = d0 * d0 + d1 * d1 + d2 * d2;
  for (int o = 32; o; o >>= 1) sq += __shfl_xor(sq, o, 64);
  if ((tid & 63) == 0) s[tid >> 6] = sq;
  __syncthreads();
  float var = (s[0] + s[1] + s[2] + s[3]) * (1.0f / DIM);
  float r = rsqrtf(var + LN_EPS_F);
  float xh0 = d0 * r, xh1 = d1 * r, xh2 = d2 * r;
  size_t base = (size_t)tok * DIM;
  g[base + tid]       = gamma[tid] * xh0 + delta[tid];
  g[base + tid + 256] = gamma[tid + 256] * xh1 + delta[tid + 256];
  g[base + tid + 512] = gamma[tid + 512] * xh2 + delta[tid + 512];
  if (store_stats) {
    xhat[base + tid] = xh0; xhat[base + tid + 256] = xh1; xhat[base + tid + 512] = xh2;
    if (tid == 0) rstd[tok] = r;
  }
}

// ------------------------------------------------------------------
// LayerNorm backward: dx = r*(dxh - mean(dxh) - xhat*mean(dxh*xhat))
// ------------------------------------------------------------------
__global__ __launch_bounds__(256) void ln_bwd_k(
    const float* __restrict__ dG, const float* __restrict__ xhat,
    const float* __restrict__ rstd, const float* __restrict__ gamma,
    float* __restrict__ grad)
{
  __shared__ float s[8];
  int tok = blockIdx.x;
  int tid = threadIdx.x;
  size_t base = (size_t)tok * DIM;
  float dh0 = dG[base + tid]       * gamma[tid];
  float dh1 = dG[base + tid + 256] * gamma[tid + 256];
  float dh2 = dG[base + tid + 512] * gamma[tid + 512];
  float xh0 = xhat[base + tid], xh1 = xhat[base + tid + 256], xh2 = xhat[base + tid + 512];
  float s1 = dh0 + dh1 + dh2;
  float s2 = dh0 * xh0 + dh1 * xh1 + dh2 * xh2;
  for (int o = 32; o; o >>= 1) { s1 += __shfl_xor(s1, o, 64); s2 += __shfl_xor(s2, o, 64); }
  if ((tid & 63) == 0) { s[tid >> 6] = s1; s[4 + (tid >> 6)] = s2; }
  __syncthreads();
  float m1 = (s[0] + s[1] + s[2] + s[3]) * (1.0f / DIM);
  float m2 = (s[4] + s[5] + s[6] + s[7]) * (1.0f / DIM);
  float r = rstd[tok];
  grad[base + tid]       = r * (dh0 - m1 - xh0 * m2);
  grad[base + tid + 256] = r * (dh1 - m1 - xh1 * m2);
  grad[base + tid + 512] = r * (dh2 - m1 - xh2 * m2);
}

// ------------------------------------------------------------------
// Tiled matmul. MODE: 0 = store C (alpha, acc flag)
//                1 = store relu(C) and accumulate energy -0.5*sum relu^2
//                2 = energy only (no store)
// BT: true -> C = A[M,K] @ B[N,K]^T ; false -> C = A[M,K] @ B[K,N]
// BM=BN=64, BK=16, 256 threads, 4x4 micro-tile. N%64==0, K%16==0 assumed.
// ------------------------------------------------------------------
template <int MODE, bool BT>
__global__ __launch_bounds__(256) void mm_k(
    const float* __restrict__ A, const float* __restrict__ B,
    float* __restrict__ C, int M, int N, int K, float alpha, int acc,
    double* __restrict__ e_slot)
{
  __shared__ float As[16][65];
  __shared__ float Bs[16][65];
  int tid = threadIdx.x;
  int tx = tid & 15, ty = tid >> 4;
  int m0 = blockIdx.y * 64, n0 = blockIdx.x * 64;
  float accv[4][4] = {};
  for (int k0 = 0; k0 < K; k0 += 16) {
    for (int i = tid; i < 1024; i += 256) {
      int kk = i & 15, m = i >> 4;
      int gm = m0 + m;
      As[kk][m] = (gm < M) ? A[(size_t)gm * K + k0 + kk] : 0.f;
    }
    if (BT) {
      for (int i = tid; i < 1024; i += 256) {
        int kk = i & 15, n = i >> 4;
        Bs[kk][n] = B[(size_t)(n0 + n) * K + k0 + kk];
      }
    } else {
      for (int i = tid; i < 1024; i += 256) {
        int n = i & 63, kk = i >> 6;
        Bs[kk][n] = B[(size_t)(k0 + kk) * N + n0 + n];
      }
    }
    __syncthreads();
#pragma unroll
    for (int kk = 0; kk < 16; kk++) {
      float a[4], bv[4];
#pragma unroll
      for (int i = 0; i < 4; i++) a[i] = As[kk][ty * 4 + i];
#pragma unroll
      for (int j = 0; j < 4; j++) bv[j] = Bs[kk][tx * 4 + j];
#pragma unroll
      for (int i = 0; i < 4; i++)
#pragma unroll
        for (int j = 0; j < 4; j++) accv[i][j] += a[i] * bv[j];
    }
    __syncthreads();
  }
  float e_part = 0.f;
#pragma unroll
  for (int i = 0; i < 4; i++) {
    int m = m0 + ty * 4 + i;
    if (m >= M) continue;
#pragma unroll
    for (int j = 0; j < 4; j++) {
      int n = n0 + tx * 4 + j;
      float v = alpha * accv[i][j];
      if (MODE == 0) {
        size_t idx = (size_t)m * N + n;
        C[idx] = acc ? (C[idx] + v) : v;
      } else {
        float rl = v > 0.f ? v : 0.f;
        if (MODE == 1) C[(size_t)m * N + n] = rl;
        e_part += rl * rl;
      }
    }
  }
  if (MODE >= 1) {
    for (int o = 32; o; o >>= 1) e_part += __shfl_xor(e_part, o, 64);
    if ((tid & 63) == 0) atomicAdd(e_slot, -0.5 * (double)e_part);
  }
}

// ------------------------------------------------------------------
// Attention: per (b,h) block. S = beta*Q@K^T [196,196], rowwise LSE.
// e_att += -(1/beta)*sum LSE. If store_p: P = softmax rows.
// ------------------------------------------------------------------
__global__ __launch_bounds__(256) void attn_k(
    const float* __restrict__ Kb, const float* __restrict__ Qb,
    float* __restrict__ P, double* __restrict__ e_slot, int store_p)
{
  int bh = blockIdx.x;
  int b = bh / HN, h = bh % HN;
  const float* Kp = Kb + (size_t)(b * SEQ) * DIM + h * YD;
  const float* Qp = Qb + (size_t)(b * SEQ) * DIM + h * YD;
  __shared__ float Ks[SEQ * 65];
  __shared__ float Qr[4][64];
  int tid = threadIdx.x, lane = tid & 63, w = tid >> 6;
  for (int i = tid; i < SEQ * 64; i += 256) {
    int k = i >> 6, y = i & 63;
    Ks[k * 65 + y] = Kp[(size_t)k * DIM + y];
  }
  __syncthreads();
  double eacc = 0.0;
  for (int q = w; q < SEQ; q += 4) {   // uniform 49 iters per wave
    __syncthreads();
    Qr[w][lane] = Qp[(size_t)q * DIM + lane];
    __syncthreads();
    float t[4];
#pragma unroll
    for (int j = 0; j < 4; j++) {
      int k = lane + 64 * j;
      if (k < SEQ) {
        float dot = 0.f;
#pragma unroll
        for (int y = 0; y < 64; y++) dot += Qr[w][y] * Ks[k * 65 + y];
        t[j] = BETA_F * dot;
      } else t[j] = -INFINITY;
    }
    float m = fmaxf(fmaxf(t[0], t[1]), fmaxf(t[2], t[3]));
    for (int o = 32; o; o >>= 1) m = fmaxf(m, __shfl_xor(m, o, 64));
    float z = 0.f;
#pragma unroll
    for (int j = 0; j < 4; j++) z += (lane + 64 * j < SEQ) ? expf(t[j] - m) : 0.f;
    for (int o = 32; o; o >>= 1) z += __shfl_xor(z, o, 64);
    float lse = m + logf(z);
    eacc += (double)lse;
    if (store_p) {
      float inv_z = 1.0f / z;
      size_t prow = ((size_t)bh * SEQ + q) * SEQ;
#pragma unroll
      for (int j = 0; j < 4; j++) {
        int k = lane + 64 * j;
        if (k < SEQ) P[prow + k] = expf(t[j] - m) * inv_z;
      }
    }
  }
  if (lane == 0) atomicAdd(e_slot, -(double)INV_BETA * eacc);
}

// ------------------------------------------------------------------
// Attention backward: dQg = -(P@K), dKg = -(P^T@Q)  (per (b,h))
// ------------------------------------------------------------------
__global__ __launch_bounds__(256) void attn_bwd_k(
    const float* __restrict__ Kb, const float* __restrict__ Qb,
    const float* __restrict__ P, float* __restrict__ dQg, float* __restrict__ dKg)
{
  int bh = blockIdx.x;
  int b = bh / HN, h = bh % HN;
  const float* Kp = Kb + (size_t)(b * SEQ) * DIM + h * YD;
  const float* Qp = Qb + (size_t)(b * SEQ) * DIM + h * YD;
  __shared__ float Ts[SEQ * 65];
  int tid = threadIdx.x, lane = tid & 63, w = tid >> 6;
  // phase 1: K in LDS -> dQ
  for (int i = tid; i < SEQ * 64; i += 256) {
    int k = i >> 6, y = i & 63;
    Ts[k * 65 + y] = Kp[(size_t)k * DIM + y];
  }
  __syncthreads();
  for (int q = w; q < SEQ; q += 4) {
    const float* Prow = P + ((size_t)bh * SEQ + q) * SEQ;
    float accv = 0.f;
    for (int k = 0; k < SEQ; k++) accv += Prow[k] * Ts[k * 65 + lane];
    dQg[((size_t)(b * SEQ + q)) * DIM + h * YD + lane] = -accv;
  }
  __syncthreads();
  // phase 2: Q in LDS -> dK
  for (int i = tid; i < SEQ * 64; i += 256) {
    int n = i >> 6, y = i & 63;
    Ts[n * 65 + y] = Qp[(size_t)n * DIM + y];
  }
  __syncthreads();
  for (int k = w; k < SEQ; k += 4) {
    float accv = 0.f;
    for (int q = 0; q < SEQ; q++) accv += P[((size_t)bh * SEQ + q) * SEQ + k] * Ts[q * 65 + lane];
    dKg[((size_t)(b * SEQ + k)) * DIM + h * YD + lane] = -accv;
  }
}

// ------------------------------------------------------------------
// Small kernels
// ------------------------------------------------------------------
__global__ void init_slots_k(double* e) {
  if (threadIdx.x < 16) e[threadIdx.x] = 0.0;
}

__global__ __launch_bounds__(256) void axpy_k(
    const float* __restrict__ x, const float* __restrict__ g,
    float* __restrict__ y, float lr, int n4)
{
  int i = blockIdx.x * 256 + threadIdx.x;
  if (i < n4) {
    const float4 xv = ((const float4*)x)[i];
    const float4 gv = ((const float4*)g)[i];
    float4 o;
    o.x = xv.x - lr * gv.x; o.y = xv.y - lr * gv.y;
    o.z = xv.z - lr * gv.z; o.w = xv.w - lr * gv.w;
    ((float4*)y)[i] = o;
  }
}

__global__ void choose_k(const double* __restrict__ e, float* __restrict__ chosen) {
  if (threadIdx.x == 0) {
    double e0 = e[0];
    float c = 0.0625f;                 // lr0 * gamma^4
    if (e[4] < e0) c = 0.125f;         // kk=3
    if (e[3] < e0) c = 0.25f;          // kk=2
    if (e[2] < e0) c = 0.5f;           // kk=1
    if (e[1] < e0) c = 1.0f;           // kk=0 (highest priority)
    *chosen = c;
  }
}

__global__ __launch_bounds__(256) void update_k(
    const float* __restrict__ x, const float* __restrict__ g,
    const float* __restrict__ chosen, float* __restrict__ out, int n4)
{
  int i = blockIdx.x * 256 + threadIdx.x;
  float lr = *chosen;
  if (i < n4) {
    const float4 xv = ((const float4*)x)[i];
    const float4 gv = ((const float4*)g)[i];
    float4 o;
    o.x = xv.x - lr * gv.x; o.y = xv.y - lr * gv.y;
    o.z = xv.z - lr * gv.z; o.w = xv.w - lr * gv.w;
    ((float4*)out)[i] = o;
  }
}

// ------------------------------------------------------------------
extern "C" void kernel_launch(void* const* d_in, const int* in_sizes, int n_in,
                              void* d_out, int out_size, void* d_ws, size_t ws_size,
                              hipStream_t stream)
{
  const float* x     = (const float*)d_in[0];
  const float* gamma = (const float*)d_in[1];
  const float* delta = (const float*)d_in[2];
  const float* wk    = (const float*)d_in[3];  // [768(hy), 768(d)]
  const float* wq    = (const float*)d_in[4];
  const float* xi    = (const float*)d_in[5];  // [3072, 768]
  float* out = (float*)d_out;

  const size_t NE = (size_t)TOK * DIM;   // 1,204,224
  double* slots = (double*)d_ws;         // 16 doubles
  float* f = (float*)((char*)d_ws + 128);
  float* g    = f;
  float* xhat = g + NE;
  float* Kb   = xhat + NE;
  float* Qb   = Kb + NE;
  float* P    = Qb + NE;                       // 96*196*196
  float* rh   = P + (size_t)96 * SEQ * SEQ;    // 1568*3072
  float* dQg  = rh + (size_t)TOK * MXI;
  float* dKg  = dQg + NE;
  float* dG   = dKg + NE;
  float* grad = dG + NE;
  float* xt   = grad + NE;
  float* rstd = xt + NE;
  float* chosen = rstd + TOK;

  const int n4 = (int)(NE / 4);
  const int gM = (TOK + 63) / 64;   // 25
  dim3 blk(256);

  hipLaunchKernelGGL(init_slots_k, dim3(1), dim3(16), 0, stream, slots);

  // ---- base forward + backward ----
  hipLaunchKernelGGL(ln_fwd_k, dim3(TOK), blk, 0, stream, x, gamma, delta, g, xhat, rstd, 1);
  hipLaunchKernelGGL((mm_k<0, true>), dim3(DIM / 64, gM), blk, 0, stream,
                     g, wk, Kb, TOK, DIM, DIM, 1.f, 0, nullptr);
  hipLaunchKernelGGL((mm_k<0, true>), dim3(DIM / 64, gM), blk, 0, stream,
                     g, wq, Qb, TOK, DIM, DIM, 1.f, 0, nullptr);
  hipLaunchKernelGGL(attn_k, dim3(8 * HN), blk, 0, stream, Kb, Qb, P, slots + 0, 1);
  hipLaunchKernelGGL((mm_k<1, true>), dim3(MXI / 64, gM), blk, 0, stream,
                     g, xi, rh, TOK, MXI, DIM, 1.f, 0, slots + 0);
  hipLaunchKernelGGL(attn_bwd_k, dim3(8 * HN), blk, 0, stream, Kb, Qb, P, dQg, dKg);
  // dG = dQg@Wq + dKg@Wk - rh@xi
  hipLaunchKernelGGL((mm_k<0, false>), dim3(DIM / 64, gM), blk, 0, stream,
                     dQg, wq, dG, TOK, DIM, DIM, 1.f, 0, nullptr);
  hipLaunchKernelGGL((mm_k<0, false>), dim3(DIM / 64, gM), blk, 0, stream,
                     dKg, wk, dG, TOK, DIM, DIM, 1.f, 1, nullptr);
  hipLaunchKernelGGL((mm_k<0, false>), dim3(DIM / 64, gM), blk, 0, stream,
                     rh, xi, dG, TOK, DIM, MXI, -1.f, 1, nullptr);
  hipLaunchKernelGGL(ln_bwd_k, dim3(TOK), blk, 0, stream, dG, xhat, rstd, gamma, grad);

  // ---- Armijo trials: lr = 0.5^kk, energy into slot[1+kk] ----
  for (int kk = 3; kk >= 0; kk--) {
    float lr = 1.0f / (float)(1 << kk);
    hipLaunchKernelGGL(axpy_k, dim3((n4 + 255) / 256), blk, 0, stream, x, grad, xt, lr, n4);
    hipLaunchKernelGGL(ln_fwd_k, dim3(TOK), blk, 0, stream, xt, gamma, delta, g, xhat, rstd, 0);
    hipLaunchKernelGGL((mm_k<0, true>), dim3(DIM / 64, gM), blk, 0, stream,
                       g, wk, Kb, TOK, DIM, DIM, 1.f, 0, nullptr);
    hipLaunchKernelGGL((mm_k<0, true>), dim3(DIM / 64, gM), blk, 0, stream,
                       g, wq, Qb, TOK, DIM, DIM, 1.f, 0, nullptr);
    hipLaunchKernelGGL(attn_k, dim3(8 * HN), blk, 0, stream, Kb, Qb, P, slots + 1 + kk, 0);
    hipLaunchKernelGGL((mm_k<2, true>), dim3(MXI / 64, gM), blk, 0, stream,
                       g, xi, nullptr, TOK, MXI, DIM, 1.f, 0, slots + 1 + kk);
  }

  // ---- choose lr, final update ----
  hipLaunchKernelGGL(choose_k, dim3(1), dim3(64), 0, stream, slots, chosen);
  hipLaunchKernelGGL(update_k, dim3((n4 + 255) / 256), blk, 0, stream, x, grad, chosen, out, n4);
}

// Round 2
// 2134.340 us; speedup vs baseline: 2.0561x; 2.0561x over previous
//
#include <hip/hip_runtime.h>
#include <math.h>

#define TOK 1568      // B*N = 8*196
#define DIM 768
#define HN 12
#define SEQ 196
#define YD 64
#define MXI 3072
#define BETA_F 0.125f
#define INV_BETA 8.0f
#define LN_EPS_F 1e-5f

// ------------------------------------------------------------------
// LayerNorm forward: per-token block (256 thr, 3 elems/thread)
// ------------------------------------------------------------------
__global__ __launch_bounds__(256) void ln_fwd_k(
    const float* __restrict__ x, const float* __restrict__ gamma,
    const float* __restrict__ delta, float* __restrict__ g,
    float* __restrict__ xhat, float* __restrict__ rstd, int store_stats)
{
  __shared__ float s[4];
  int tok = blockIdx.x;
  int tid = threadIdx.x;
  const float* xp = x + (size_t)tok * DIM;
  float v0 = xp[tid], v1 = xp[tid + 256], v2 = xp[tid + 512];
  float sum = v0 + v1 + v2;
  for (int o = 32; o; o >>= 1) sum += __shfl_xor(sum, o, 64);
  if ((tid & 63) == 0) s[tid >> 6] = sum;
  __syncthreads();
  float mu = (s[0] + s[1] + s[2] + s[3]) * (1.0f / DIM);
  __syncthreads();
  float d0 = v0 - mu, d1 = v1 - mu, d2 = v2 - mu;
  float sq = d0 * d0 + d1 * d1 + d2 * d2;
  for (int o = 32; o; o >>= 1) sq += __shfl_xor(sq, o, 64);
  if ((tid & 63) == 0) s[tid >> 6] = sq;
  __syncthreads();
  float var = (s[0] + s[1] + s[2] + s[3]) * (1.0f / DIM);
  float r = rsqrtf(var + LN_EPS_F);
  float xh0 = d0 * r, xh1 = d1 * r, xh2 = d2 * r;
  size_t base = (size_t)tok * DIM;
  g[base + tid]       = gamma[tid] * xh0 + delta[tid];
  g[base + tid + 256] = gamma[tid + 256] * xh1 + delta[tid + 256];
  g[base + tid + 512] = gamma[tid + 512] * xh2 + delta[tid + 512];
  if (store_stats) {
    xhat[base + tid] = xh0; xhat[base + tid + 256] = xh1; xhat[base + tid + 512] = xh2;
    if (tid == 0) rstd[tok] = r;
  }
}

// ------------------------------------------------------------------
// LayerNorm backward
// ------------------------------------------------------------------
__global__ __launch_bounds__(256) void ln_bwd_k(
    const float* __restrict__ dG, const float* __restrict__ xhat,
    const float* __restrict__ rstd, const float* __restrict__ gamma,
    float* __restrict__ grad)
{
  __shared__ float s[8];
  int tok = blockIdx.x;
  int tid = threadIdx.x;
  size_t base = (size_t)tok * DIM;
  float dh0 = dG[base + tid]       * gamma[tid];
  float dh1 = dG[base + tid + 256] * gamma[tid + 256];
  float dh2 = dG[base + tid + 512] * gamma[tid + 512];
  float xh0 = xhat[base + tid], xh1 = xhat[base + tid + 256], xh2 = xhat[base + tid + 512];
  float s1 = dh0 + dh1 + dh2;
  float s2 = dh0 * xh0 + dh1 * xh1 + dh2 * xh2;
  for (int o = 32; o; o >>= 1) { s1 += __shfl_xor(s1, o, 64); s2 += __shfl_xor(s2, o, 64); }
  if ((tid & 63) == 0) { s[tid >> 6] = s1; s[4 + (tid >> 6)] = s2; }
  __syncthreads();
  float m1 = (s[0] + s[1] + s[2] + s[3]) * (1.0f / DIM);
  float m2 = (s[4] + s[5] + s[6] + s[7]) * (1.0f / DIM);
  float r = rstd[tok];
  grad[base + tid]       = r * (dh0 - m1 - xh0 * m2);
  grad[base + tid + 256] = r * (dh1 - m1 - xh1 * m2);
  grad[base + tid + 512] = r * (dh2 - m1 - xh2 * m2);
}

// ------------------------------------------------------------------
// mm128: C[M,N] = A[M,K] @ B[N,K]^T, 128x128 tile, BK=16, 8x8 micro.
// MODE 1: store relu(C) + energy (-0.5 sum relu^2); MODE 2: energy only.
// N % 128 == 0, K % 16 == 0. M guarded.
// LDS pad 132 -> conflict-free transposed writes; fragments split 4+4
// at offsets {t*4, t*4+64} -> conflict-free b128 reads.
// ------------------------------------------------------------------
template <int MODE>
__global__ __launch_bounds__(256) void mm128_k(
    const float* __restrict__ A, const float* __restrict__ B,
    float* __restrict__ C, int M, int N, int K, double* __restrict__ e_slot)
{
  __shared__ float As[16][132];
  __shared__ float Bs[16][132];
  int tid = threadIdx.x;
  int tx = tid & 15, ty = tid >> 4;
  int m0 = blockIdx.y * 128, n0 = blockIdx.x * 128;
  float acc[8][8] = {};
  for (int k0 = 0; k0 < K; k0 += 16) {
#pragma unroll
    for (int r = 0; r < 2; r++) {
      int f = tid + 256 * r;
      int mm = f >> 2, kc = (f & 3) << 2;
      float4 v = make_float4(0.f, 0.f, 0.f, 0.f);
      int gm = m0 + mm;
      if (gm < M) v = *(const float4*)(A + (size_t)gm * K + k0 + kc);
      As[kc + 0][mm] = v.x; As[kc + 1][mm] = v.y; As[kc + 2][mm] = v.z; As[kc + 3][mm] = v.w;
      float4 wv = *(const float4*)(B + (size_t)(n0 + mm) * K + k0 + kc);
      Bs[kc + 0][mm] = wv.x; Bs[kc + 1][mm] = wv.y; Bs[kc + 2][mm] = wv.z; Bs[kc + 3][mm] = wv.w;
    }
    __syncthreads();
#pragma unroll
    for (int kk = 0; kk < 16; kk++) {
      float a[8], b[8];
      *(float4*)&a[0] = *(const float4*)&As[kk][ty * 4];
      *(float4*)&a[4] = *(const float4*)&As[kk][ty * 4 + 64];
      *(float4*)&b[0] = *(const float4*)&Bs[kk][tx * 4];
      *(float4*)&b[4] = *(const float4*)&Bs[kk][tx * 4 + 64];
#pragma unroll
      for (int i = 0; i < 8; i++)
#pragma unroll
        for (int j = 0; j < 8; j++)
          acc[i][j] = fmaf(a[i], b[j], acc[i][j]);
    }
    __syncthreads();
  }
  float e_part = 0.f;
#pragma unroll
  for (int i = 0; i < 8; i++) {
    int m = m0 + ((i < 4) ? (ty * 4 + i) : (64 + ty * 4 + (i - 4)));
    if (m >= M) continue;
    float v[8];
#pragma unroll
    for (int j = 0; j < 8; j++) {
      v[j] = fmaxf(acc[i][j], 0.f);
      e_part += v[j] * v[j];
    }
    if (MODE == 1) {
      float* c0 = C + (size_t)m * N + n0 + tx * 4;
      *(float4*)c0        = make_float4(v[0], v[1], v[2], v[3]);
      *(float4*)(c0 + 64) = make_float4(v[4], v[5], v[6], v[7]);
    }
  }
  for (int o = 32; o; o >>= 1) e_part += __shfl_xor(e_part, o, 64);
  if ((tid & 63) == 0) atomicAdd(e_slot, -0.5 * (double)e_part);
}

// ------------------------------------------------------------------
// mm64: C[M,N] = alpha * A[M,K] @ op(B) (+C if accflag).
// BT: B[N,K]^T else B[K,N]. 64x64 tile, BK=16, 4x4 micro, b128 LDS reads.
// N % 64 == 0, K % 16 == 0. M guarded.
// ------------------------------------------------------------------
template <bool BT>
__global__ __launch_bounds__(256) void mm64_k(
    const float* __restrict__ A, const float* __restrict__ B,
    float* __restrict__ C, int M, int N, int K, float alpha, int accflag)
{
  __shared__ float As[16][68];
  __shared__ float Bs[16][68];
  int tid = threadIdx.x;
  int tx = tid & 15, ty = tid >> 4;
  int m0 = blockIdx.y * 64, n0 = blockIdx.x * 64;
  float acc[4][4] = {};
  for (int k0 = 0; k0 < K; k0 += 16) {
    {
      int mm = tid >> 2, kc = (tid & 3) << 2;
      float4 v = make_float4(0.f, 0.f, 0.f, 0.f);
      int gm = m0 + mm;
      if (gm < M) v = *(const float4*)(A + (size_t)gm * K + k0 + kc);
      As[kc + 0][mm] = v.x; As[kc + 1][mm] = v.y; As[kc + 2][mm] = v.z; As[kc + 3][mm] = v.w;
      if (BT) {
        float4 wv = *(const float4*)(B + (size_t)(n0 + mm) * K + k0 + kc);
        Bs[kc + 0][mm] = wv.x; Bs[kc + 1][mm] = wv.y; Bs[kc + 2][mm] = wv.z; Bs[kc + 3][mm] = wv.w;
      } else {
        int kk = tid >> 4, nc = (tid & 15) << 2;
        *(float4*)&Bs[kk][nc] = *(const float4*)(B + (size_t)(k0 + kk) * N + n0 + nc);
      }
    }
    __syncthreads();
#pragma unroll
    for (int kk = 0; kk < 16; kk++) {
      float a[4], b[4];
      *(float4*)a = *(const float4*)&As[kk][ty * 4];
      *(float4*)b = *(const float4*)&Bs[kk][tx * 4];
#pragma unroll
      for (int i = 0; i < 4; i++)
#pragma unroll
        for (int j = 0; j < 4; j++)
          acc[i][j] = fmaf(a[i], b[j], acc[i][j]);
    }
    __syncthreads();
  }
#pragma unroll
  for (int i = 0; i < 4; i++) {
    int m = m0 + ty * 4 + i;
    if (m >= M) continue;
    float* c0 = C + (size_t)m * N + n0 + tx * 4;
    float4 o = make_float4(alpha * acc[i][0], alpha * acc[i][1],
                           alpha * acc[i][2], alpha * acc[i][3]);
    if (accflag) {
      float4 p = *(const float4*)c0;
      o.x += p.x; o.y += p.y; o.z += p.z; o.w += p.w;
    }
    *(float4*)c0 = o;
  }
}

// ------------------------------------------------------------------
// Attention fwd: per (b,h). K staged as [y4][k] float4 (contiguous b128).
// 2 Q-rows per wave (qa=qp, qb=qp+98) share each K read; wave-local Q
// staging with explicit lgkmcnt(0) wait (no block barrier needed).
// ------------------------------------------------------------------
__global__ __launch_bounds__(256) void attn_k(
    const float* __restrict__ Kb, const float* __restrict__ Qb,
    float* __restrict__ P, double* __restrict__ e_slot, int store_p)
{
  int bh = blockIdx.x;
  int b = bh / HN, h = bh - b * HN;
  const float* Kp = Kb + (size_t)(b * SEQ) * DIM + h * YD;
  const float* Qp = Qb + (size_t)(b * SEQ) * DIM + h * YD;
  __shared__ float4 Ks4[16 * SEQ + 64];   // [y4][k], +64 pad for OOB j=3 lanes
  __shared__ float4 Qs4[4][2][16];
  int tid = threadIdx.x, lane = tid & 63, w = tid >> 6;
  for (int i = tid; i < SEQ * 16; i += 256) {
    int k = i >> 4, y4 = i & 15;
    Ks4[y4 * SEQ + k] = *(const float4*)(Kp + (size_t)k * DIM + y4 * 4);
  }
  __syncthreads();
  double eacc = 0.0;
  for (int qp = w; qp < 98; qp += 4) {
    int qa = qp, qb2 = qp + 98;
    if (lane < 32) {
      int which = lane >> 4, yy = lane & 15;
      int q = which ? qb2 : qa;
      Qs4[w][which][yy] = *(const float4*)(Qp + (size_t)q * DIM + yy * 4);
    }
    __builtin_amdgcn_s_waitcnt(0xc07f);  // lgkmcnt(0): wave-local LDS visibility
    float da[4] = {0.f, 0.f, 0.f, 0.f}, db[4] = {0.f, 0.f, 0.f, 0.f};
#pragma unroll
    for (int y4 = 0; y4 < 16; y4++) {
      float4 a4 = Qs4[w][0][y4];
      float4 b4 = Qs4[w][1][y4];
#pragma unroll
      for (int j = 0; j < 4; j++) {
        float4 kv = Ks4[y4 * SEQ + lane + 64 * j];
        da[j] = fmaf(kv.x, a4.x, da[j]); da[j] = fmaf(kv.y, a4.y, da[j]);
        da[j] = fmaf(kv.z, a4.z, da[j]); da[j] = fmaf(kv.w, a4.w, da[j]);
        db[j] = fmaf(kv.x, b4.x, db[j]); db[j] = fmaf(kv.y, b4.y, db[j]);
        db[j] = fmaf(kv.z, b4.z, db[j]); db[j] = fmaf(kv.w, b4.w, db[j]);
      }
    }
    float ta[4], tb[4];
#pragma unroll
    for (int j = 0; j < 4; j++) {
      bool valid = (lane + 64 * j) < SEQ;
      ta[j] = valid ? BETA_F * da[j] : -INFINITY;
      tb[j] = valid ? BETA_F * db[j] : -INFINITY;
    }
    float ma = fmaxf(fmaxf(ta[0], ta[1]), fmaxf(ta[2], ta[3]));
    float mb = fmaxf(fmaxf(tb[0], tb[1]), fmaxf(tb[2], tb[3]));
    for (int o = 32; o; o >>= 1) {
      ma = fmaxf(ma, __shfl_xor(ma, o, 64));
      mb = fmaxf(mb, __shfl_xor(mb, o, 64));
    }
    float za = 0.f, zb = 0.f;
#pragma unroll
    for (int j = 0; j < 4; j++) { za += expf(ta[j] - ma); zb += expf(tb[j] - mb); }
    for (int o = 32; o; o >>= 1) { za += __shfl_xor(za, o, 64); zb += __shfl_xor(zb, o, 64); }
    eacc += (double)(ma + logf(za)) + (double)(mb + logf(zb));
    if (store_p) {
      float ia = 1.f / za, ib = 1.f / zb;
      float* Pa  = P + ((size_t)bh * SEQ + qa) * SEQ;
      float* Pb2 = P + ((size_t)bh * SEQ + qb2) * SEQ;
#pragma unroll
      for (int j = 0; j < 4; j++) {
        int k = lane + 64 * j;
        if (k < SEQ) {
          Pa[k]  = expf(ta[j] - ma) * ia;
          Pb2[k] = expf(tb[j] - mb) * ib;
        }
      }
    }
  }
  if (lane == 0) atomicAdd(e_slot, -(double)INV_BETA * eacc);
}

// ------------------------------------------------------------------
// Attention bwd as batched tiled GEMM. grid (96 bh, 4 mtiles, 2):
//   z=0: dQ[q,y] = -sum_k P[q,k]*K[k,y]   (A = P)
//   z=1: dK[k,y] = -sum_q P[q,k]*Q[q,y]   (A = P^T, coalesced column-tile load)
// ------------------------------------------------------------------
__global__ __launch_bounds__(256) void attn_bwd_k(
    const float* __restrict__ Kb, const float* __restrict__ Qb,
    const float* __restrict__ P, float* __restrict__ dQg, float* __restrict__ dKg)
{
  int bh = blockIdx.x;
  int b = bh / HN, h = bh - b * HN;
  int m0 = blockIdx.y * 64;
  int is_dk = blockIdx.z;
  const float* Bsrc = (is_dk ? Qb : Kb) + (size_t)(b * SEQ) * DIM + h * YD;
  const float* Pb = P + (size_t)bh * SEQ * SEQ;
  float* Dst = (is_dk ? dKg : dQg) + (size_t)(b * SEQ) * DIM + h * YD;
  __shared__ float As[16][68];
  __shared__ float Bs[16][68];
  int tid = threadIdx.x;
  int tx = tid & 15, ty = tid >> 4;
  float acc[4][4] = {};
  for (int k0 = 0; k0 < SEQ; k0 += 16) {
    if (!is_dk) {
      int mm = tid >> 2, kc = (tid & 3) << 2;
      float4 v = make_float4(0.f, 0.f, 0.f, 0.f);
      if (m0 + mm < SEQ && k0 + kc < SEQ)
        v = *(const float4*)(Pb + (size_t)(m0 + mm) * SEQ + k0 + kc);
      As[kc + 0][mm] = v.x; As[kc + 1][mm] = v.y; As[kc + 2][mm] = v.z; As[kc + 3][mm] = v.w;
    } else {
      int kk = tid >> 4, mc = (tid & 15) << 2;
      float4 v = make_float4(0.f, 0.f, 0.f, 0.f);
      if (k0 + kk < SEQ && m0 + mc < SEQ)
        v = *(const float4*)(Pb + (size_t)(k0 + kk) * SEQ + m0 + mc);
      *(float4*)&As[kk][mc] = v;
    }
    {
      int kk = tid >> 4, yc = (tid & 15) << 2;
      float4 v = make_float4(0.f, 0.f, 0.f, 0.f);
      if (k0 + kk < SEQ)
        v = *(const float4*)(Bsrc + (size_t)(k0 + kk) * DIM + yc);
      *(float4*)&Bs[kk][yc] = v;
    }
    __syncthreads();
#pragma unroll
    for (int kk = 0; kk < 16; kk++) {
      float a[4], bb[4];
      *(float4*)a  = *(const float4*)&As[kk][ty * 4];
      *(float4*)bb = *(const float4*)&Bs[kk][tx * 4];
#pragma unroll
      for (int i = 0; i < 4; i++)
#pragma unroll
        for (int j = 0; j < 4; j++)
          acc[i][j] = fmaf(a[i], bb[j], acc[i][j]);
    }
    __syncthreads();
  }
#pragma unroll
  for (int i = 0; i < 4; i++) {
    int m = m0 + ty * 4 + i;
    if (m < SEQ) {
      *(float4*)(Dst + (size_t)m * DIM + tx * 4) =
          make_float4(-acc[i][0], -acc[i][1], -acc[i][2], -acc[i][3]);
    }
  }
}

// ------------------------------------------------------------------
// Small kernels
// ------------------------------------------------------------------
__global__ void init_slots_k(double* e) {
  if (threadIdx.x < 16) e[threadIdx.x] = 0.0;
}

__global__ __launch_bounds__(256) void axpy_k(
    const float* __restrict__ x, const float* __restrict__ g,
    float* __restrict__ y, float lr, int n4)
{
  int i = blockIdx.x * 256 + threadIdx.x;
  if (i < n4) {
    const float4 xv = ((const float4*)x)[i];
    const float4 gv = ((const float4*)g)[i];
    float4 o;
    o.x = xv.x - lr * gv.x; o.y = xv.y - lr * gv.y;
    o.z = xv.z - lr * gv.z; o.w = xv.w - lr * gv.w;
    ((float4*)y)[i] = o;
  }
}

__global__ void choose_k(const double* __restrict__ e, float* __restrict__ chosen) {
  if (threadIdx.x == 0) {
    double e0 = e[0];
    float c = 0.0625f;                 // lr0 * gamma^4
    if (e[4] < e0) c = 0.125f;         // kk=3
    if (e[3] < e0) c = 0.25f;          // kk=2
    if (e[2] < e0) c = 0.5f;           // kk=1
    if (e[1] < e0) c = 1.0f;           // kk=0 (highest priority)
    *chosen = c;
  }
}

__global__ __launch_bounds__(256) void update_k(
    const float* __restrict__ x, const float* __restrict__ g,
    const float* __restrict__ chosen, float* __restrict__ out, int n4)
{
  int i = blockIdx.x * 256 + threadIdx.x;
  float lr = *chosen;
  if (i < n4) {
    const float4 xv = ((const float4*)x)[i];
    const float4 gv = ((const float4*)g)[i];
    float4 o;
    o.x = xv.x - lr * gv.x; o.y = xv.y - lr * gv.y;
    o.z = xv.z - lr * gv.z; o.w = xv.w - lr * gv.w;
    ((float4*)out)[i] = o;
  }
}

// ------------------------------------------------------------------
extern "C" void kernel_launch(void* const* d_in, const int* in_sizes, int n_in,
                              void* d_out, int out_size, void* d_ws, size_t ws_size,
                              hipStream_t stream)
{
  const float* x     = (const float*)d_in[0];
  const float* gamma = (const float*)d_in[1];
  const float* delta = (const float*)d_in[2];
  const float* wk    = (const float*)d_in[3];  // [768(hy), 768(d)]
  const float* wq    = (const float*)d_in[4];
  const float* xi    = (const float*)d_in[5];  // [3072, 768]
  float* out = (float*)d_out;

  const size_t NE = (size_t)TOK * DIM;   // 1,204,224
  double* slots = (double*)d_ws;         // 16 doubles
  float* f = (float*)((char*)d_ws + 128);
  float* g    = f;
  float* xhat = g + NE;
  float* Kb   = xhat + NE;
  float* Qb   = Kb + NE;
  float* P    = Qb + NE;                       // 96*196*196
  float* rh   = P + (size_t)96 * SEQ * SEQ;    // 1568*3072
  float* dQg  = rh + (size_t)TOK * MXI;
  float* dKg  = dQg + NE;
  float* dG   = dKg + NE;
  float* grad = dG + NE;
  float* xt   = grad + NE;
  float* rstd = xt + NE;
  float* chosen = rstd + TOK;

  const int n4 = (int)(NE / 4);
  dim3 blk(256);
  dim3 g64(DIM / 64, (TOK + 63) / 64);      // (12, 25)
  dim3 g128(MXI / 128, (TOK + 127) / 128);  // (24, 13)

  hipLaunchKernelGGL(init_slots_k, dim3(1), dim3(16), 0, stream, slots);

  // ---- base forward + backward ----
  hipLaunchKernelGGL(ln_fwd_k, dim3(TOK), blk, 0, stream, x, gamma, delta, g, xhat, rstd, 1);
  hipLaunchKernelGGL((mm64_k<true>), g64, blk, 0, stream, g, wk, Kb, TOK, DIM, DIM, 1.f, 0);
  hipLaunchKernelGGL((mm64_k<true>), g64, blk, 0, stream, g, wq, Qb, TOK, DIM, DIM, 1.f, 0);
  hipLaunchKernelGGL(attn_k, dim3(8 * HN), blk, 0, stream, Kb, Qb, P, slots + 0, 1);
  hipLaunchKernelGGL((mm128_k<1>), g128, blk, 0, stream, g, xi, rh, TOK, MXI, DIM, slots + 0);
  hipLaunchKernelGGL(attn_bwd_k, dim3(8 * HN, 4, 2), blk, 0, stream, Kb, Qb, P, dQg, dKg);
  // dG = dQg@wq + dKg@wk - rh@xi
  hipLaunchKernelGGL((mm64_k<false>), g64, blk, 0, stream, dQg, wq, dG, TOK, DIM, DIM, 1.f, 0);
  hipLaunchKernelGGL((mm64_k<false>), g64, blk, 0, stream, dKg, wk, dG, TOK, DIM, DIM, 1.f, 1);
  hipLaunchKernelGGL((mm64_k<false>), g64, blk, 0, stream, rh, xi, dG, TOK, DIM, MXI, -1.f, 1);
  hipLaunchKernelGGL(ln_bwd_k, dim3(TOK), blk, 0, stream, dG, xhat, rstd, gamma, grad);

  // ---- Armijo trials: lr = 0.5^kk, energy into slot[1+kk] ----
  for (int kk = 3; kk >= 0; kk--) {
    float lr = 1.0f / (float)(1 << kk);
    hipLaunchKernelGGL(axpy_k, dim3((n4 + 255) / 256), blk, 0, stream, x, grad, xt, lr, n4);
    hipLaunchKernelGGL(ln_fwd_k, dim3(TOK), blk, 0, stream, xt, gamma, delta, g, xhat, rstd, 0);
    hipLaunchKernelGGL((mm64_k<true>), g64, blk, 0, stream, g, wk, Kb, TOK, DIM, DIM, 1.f, 0);
    hipLaunchKernelGGL((mm64_k<true>), g64, blk, 0, stream, g, wq, Qb, TOK, DIM, DIM, 1.f, 0);
    hipLaunchKernelGGL(attn_k, dim3(8 * HN), blk, 0, stream, Kb, Qb, P, slots + 1 + kk, 0);
    hipLaunchKernelGGL((mm128_k<2>), g128, blk, 0, stream, g, xi, (float*)nullptr, TOK, MXI, DIM, slots + 1 + kk);
  }

  // ---- choose lr, final update ----
  hipLaunchKernelGGL(choose_k, dim3(1), dim3(64), 0, stream, slots, chosen);
  hipLaunchKernelGGL(update_k, dim3((n4 + 255) / 256), blk, 0, stream, x, grad, chosen, out, n4);
}

// Round 3
// 778.480 us; speedup vs baseline: 5.6372x; 2.7417x over previous
//
#include <hip/hip_runtime.h>
#include <math.h>

#define TOK 1568      // B*N = 8*196
#define MPAD 1664     // 13 * 128
#define DIM 768
#define HN 12
#define SEQ 196
#define YD 64
#define MXI 3072
#define BETA_F 0.125f
#define INV_BETA 8.0f
#define LN_EPS_F 1e-5f

typedef __bf16 v8bf __attribute__((ext_vector_type(8)));
typedef __bf16 v4bf __attribute__((ext_vector_type(4)));
typedef float  v4f  __attribute__((ext_vector_type(4)));

// ------------------------------------------------------------------
// LayerNorm forward -> bf16 g (+ fp32 xhat/rstd when store_stats)
// ------------------------------------------------------------------
__global__ __launch_bounds__(256) void ln_fwd_k(
    const float* __restrict__ x, const float* __restrict__ gamma,
    const float* __restrict__ delta, __bf16* __restrict__ g,
    float* __restrict__ xhat, float* __restrict__ rstd, int store_stats)
{
  __shared__ float s[4];
  int tok = blockIdx.x;
  int tid = threadIdx.x;
  const float* xp = x + (size_t)tok * DIM;
  float v0 = xp[tid], v1 = xp[tid + 256], v2 = xp[tid + 512];
  float sum = v0 + v1 + v2;
  for (int o = 32; o; o >>= 1) sum += __shfl_xor(sum, o, 64);
  if ((tid & 63) == 0) s[tid >> 6] = sum;
  __syncthreads();
  float mu = (s[0] + s[1] + s[2] + s[3]) * (1.0f / DIM);
  __syncthreads();
  float d0 = v0 - mu, d1 = v1 - mu, d2 = v2 - mu;
  float sq = d0 * d0 + d1 * d1 + d2 * d2;
  for (int o = 32; o; o >>= 1) sq += __shfl_xor(sq, o, 64);
  if ((tid & 63) == 0) s[tid >> 6] = sq;
  __syncthreads();
  float var = (s[0] + s[1] + s[2] + s[3]) * (1.0f / DIM);
  float r = rsqrtf(var + LN_EPS_F);
  float xh0 = d0 * r, xh1 = d1 * r, xh2 = d2 * r;
  size_t base = (size_t)tok * DIM;
  g[base + tid]       = (__bf16)(gamma[tid] * xh0 + delta[tid]);
  g[base + tid + 256] = (__bf16)(gamma[tid + 256] * xh1 + delta[tid + 256]);
  g[base + tid + 512] = (__bf16)(gamma[tid + 512] * xh2 + delta[tid + 512]);
  if (store_stats) {
    xhat[base + tid] = xh0; xhat[base + tid + 256] = xh1; xhat[base + tid + 512] = xh2;
    if (tid == 0) rstd[tok] = r;
  }
}

// ------------------------------------------------------------------
// LayerNorm backward (fp32)
// ------------------------------------------------------------------
__global__ __launch_bounds__(256) void ln_bwd_k(
    const float* __restrict__ dG, const float* __restrict__ xhat,
    const float* __restrict__ rstd, const float* __restrict__ gamma,
    float* __restrict__ grad)
{
  __shared__ float s[8];
  int tok = blockIdx.x;
  int tid = threadIdx.x;
  size_t base = (size_t)tok * DIM;
  float dh0 = dG[base + tid]       * gamma[tid];
  float dh1 = dG[base + tid + 256] * gamma[tid + 256];
  float dh2 = dG[base + tid + 512] * gamma[tid + 512];
  float xh0 = xhat[base + tid], xh1 = xhat[base + tid + 256], xh2 = xhat[base + tid + 512];
  float s1 = dh0 + dh1 + dh2;
  float s2 = dh0 * xh0 + dh1 * xh1 + dh2 * xh2;
  for (int o = 32; o; o >>= 1) { s1 += __shfl_xor(s1, o, 64); s2 += __shfl_xor(s2, o, 64); }
  if ((tid & 63) == 0) { s[tid >> 6] = s1; s[4 + (tid >> 6)] = s2; }
  __syncthreads();
  float m1 = (s[0] + s[1] + s[2] + s[3]) * (1.0f / DIM);
  float m2 = (s[4] + s[5] + s[6] + s[7]) * (1.0f / DIM);
  float r = rstd[tok];
  grad[base + tid]       = r * (dh0 - m1 - xh0 * m2);
  grad[base + tid + 256] = r * (dh1 - m1 - xh1 * m2);
  grad[base + tid + 512] = r * (dh2 - m1 - xh2 * m2);
}

// ------------------------------------------------------------------
// MFMA GEMM: C[M,N] = A[M,K] @ B[N,K]^T, bf16 in, fp32 accum.
// 128x128 tile, BK=32, 4 waves (2x2 of 64x64), 4x4 MFMA 16x16x32 each.
// global_load_lds width=16 staging; row-major [128][32] bf16 LDS.
// M is always MPAD (padded, pad rows of A are zero -> C pad rows zero).
// MODE 0: store fp32 C (blockIdx.z==1 -> B=B1, C=(float*)Cb   [KQ dual])
// MODE 1: relu -> store bf16 Cb + energy atomicAdd(-0.5*sum relu^2)
// MODE 2: relu energy only
// MODE 3: three K-segments (A0,B0,K0)+(A1,B1,K1)+(A2,B2,K2) -> fp32 C
// ------------------------------------------------------------------
template <int MODE>
__global__ __launch_bounds__(256) void gemm_k(
    const __bf16* __restrict__ A0, const __bf16* __restrict__ B0, int K0,
    const __bf16* __restrict__ A1, const __bf16* __restrict__ B1, int K1,
    const __bf16* __restrict__ A2, const __bf16* __restrict__ B2, int K2,
    float* __restrict__ Cf, __bf16* __restrict__ Cb, int N,
    double* __restrict__ e_slot)
{
  __shared__ __align__(16) __bf16 As[128 * 32];
  __shared__ __align__(16) __bf16 Bs[128 * 32];
  int tid = threadIdx.x, lane = tid & 63, w = tid >> 6;
  int wm = (w & 1) << 6, wn = (w >> 1) << 6;
  int m0 = blockIdx.y * 128, n0 = blockIdx.x * 128;
  const __bf16* Bsel = B0;
  float* Csel = Cf;
  if (MODE == 0 && blockIdx.z) { Bsel = B1; Csel = (float*)Cb; }

  v4f zero = {0.f, 0.f, 0.f, 0.f};
  v4f acc[4][4];
#pragma unroll
  for (int i = 0; i < 4; i++)
#pragma unroll
    for (int j = 0; j < 4; j++) acc[i][j] = zero;

  const int nseg = (MODE == 3) ? 3 : 1;
  for (int seg = 0; seg < nseg; seg++) {
    const __bf16* A = (seg == 0) ? A0 : (seg == 1) ? A1 : A2;
    const __bf16* B = (seg == 0) ? Bsel : (seg == 1) ? B1 : B2;
    const int K = (seg == 0) ? K0 : (seg == 1) ? K1 : K2;
    for (int k0 = 0; k0 < K; k0 += 32) {
      // stage A,B tiles: 512 chunks of 16B each; chunk c -> LDS offset c*16
      // (row-major [128][32] bf16: c*16 == (c>>2)*64 + (c&3)*16). LDS dest
      // for global_load_lds = wave-uniform base + lane*16.
#pragma unroll
      for (int r = 0; r < 2; r++) {
        int ch = (r << 8) + tid;
        int row = ch >> 2, col = (ch & 3) << 3;
        __builtin_amdgcn_global_load_lds(
            (__attribute__((address_space(1))) uint32_t*)(A + (size_t)(m0 + row) * K + k0 + col),
            (__attribute__((address_space(3))) uint32_t*)(As + (r << 11) + (w << 9)),
            16, 0, 0);
        __builtin_amdgcn_global_load_lds(
            (__attribute__((address_space(1))) uint32_t*)(B + (size_t)(n0 + row) * K + k0 + col),
            (__attribute__((address_space(3))) uint32_t*)(Bs + (r << 11) + (w << 9)),
            16, 0, 0);
      }
      __syncthreads();
      // fragments: A[m=lane&15][k=quad*8+j]  (verified m89/m91 layouts)
      int mrow = lane & 15, ksel = (lane >> 4) << 3;
      v8bf af[4], bfr[4];
#pragma unroll
      for (int i = 0; i < 4; i++) {
        af[i]  = *(const v8bf*)(As + (wm + (i << 4) + mrow) * 32 + ksel);
        bfr[i] = *(const v8bf*)(Bs + (wn + (i << 4) + mrow) * 32 + ksel);
      }
#pragma unroll
      for (int i = 0; i < 4; i++)
#pragma unroll
        for (int j = 0; j < 4; j++)
          acc[i][j] = __builtin_amdgcn_mfma_f32_16x16x32_bf16(af[i], bfr[j], acc[i][j], 0, 0, 0);
      __syncthreads();
    }
  }

  // C/D: col = lane&15, row = quad*4 + reg
  int quad = lane >> 4, ncol = lane & 15;
  if (MODE == 0 || MODE == 3) {
#pragma unroll
    for (int i = 0; i < 4; i++)
#pragma unroll
      for (int j = 0; j < 4; j++) {
        int row = m0 + wm + (i << 4) + (quad << 2);
        int col = n0 + wn + (j << 4) + ncol;
#pragma unroll
        for (int r = 0; r < 4; r++)
          Csel[(size_t)(row + r) * N + col] = acc[i][j][r];
      }
  } else {
    float e = 0.f;
#pragma unroll
    for (int i = 0; i < 4; i++)
#pragma unroll
      for (int j = 0; j < 4; j++) {
        int row = m0 + wm + (i << 4) + (quad << 2);
        int col = n0 + wn + (j << 4) + ncol;
#pragma unroll
        for (int r = 0; r < 4; r++) {
          float v = acc[i][j][r];
          v = v > 0.f ? v : 0.f;
          e += v * v;
          if (MODE == 1) Cb[(size_t)(row + r) * N + col] = (__bf16)v;
        }
      }
    for (int o = 32; o; o >>= 1) e += __shfl_xor(e, o, 64);
    if (lane == 0) atomicAdd(e_slot, -0.5 * (double)e);
  }
}

// ------------------------------------------------------------------
// Attention fwd: grid (96 bh, 2 q-halves). fp32 VALU (0.94 GF total).
// ------------------------------------------------------------------
__global__ __launch_bounds__(256) void attn_k(
    const float* __restrict__ Kb, const float* __restrict__ Qb,
    float* __restrict__ P, double* __restrict__ e_slot, int store_p)
{
  int bh = blockIdx.x;
  int z = blockIdx.y;
  int b = bh / HN, h = bh - b * HN;
  const float* Kp = Kb + (size_t)(b * SEQ) * DIM + h * YD;
  const float* Qp = Qb + (size_t)(b * SEQ) * DIM + h * YD;
  __shared__ float4 Ks4[16 * SEQ + 64];
  __shared__ float4 Qs4[4][2][16];
  int tid = threadIdx.x, lane = tid & 63, w = tid >> 6;
  for (int i = tid; i < SEQ * 16; i += 256) {
    int k = i >> 4, y4 = i & 15;
    Ks4[y4 * SEQ + k] = *(const float4*)(Kp + (size_t)k * DIM + y4 * 4);
  }
  __syncthreads();
  double eacc = 0.0;
  for (int qp = 49 * z + w; qp < 49 * (z + 1); qp += 4) {
    int qa = qp, qb2 = qp + 98;
    if (lane < 32) {
      int which = lane >> 4, yy = lane & 15;
      int q = which ? qb2 : qa;
      Qs4[w][which][yy] = *(const float4*)(Qp + (size_t)q * DIM + yy * 4);
    }
    __builtin_amdgcn_s_waitcnt(0xc07f);  // lgkmcnt(0): wave-local LDS visibility
    float da[4] = {0.f, 0.f, 0.f, 0.f}, db[4] = {0.f, 0.f, 0.f, 0.f};
#pragma unroll
    for (int y4 = 0; y4 < 16; y4++) {
      float4 a4 = Qs4[w][0][y4];
      float4 b4 = Qs4[w][1][y4];
#pragma unroll
      for (int j = 0; j < 4; j++) {
        float4 kv = Ks4[y4 * SEQ + lane + 64 * j];
        da[j] = fmaf(kv.x, a4.x, da[j]); da[j] = fmaf(kv.y, a4.y, da[j]);
        da[j] = fmaf(kv.z, a4.z, da[j]); da[j] = fmaf(kv.w, a4.w, da[j]);
        db[j] = fmaf(kv.x, b4.x, db[j]); db[j] = fmaf(kv.y, b4.y, db[j]);
        db[j] = fmaf(kv.z, b4.z, db[j]); db[j] = fmaf(kv.w, b4.w, db[j]);
      }
    }
    float ta[4], tb[4];
#pragma unroll
    for (int j = 0; j < 4; j++) {
      bool valid = (lane + 64 * j) < SEQ;
      ta[j] = valid ? BETA_F * da[j] : -INFINITY;
      tb[j] = valid ? BETA_F * db[j] : -INFINITY;
    }
    float ma = fmaxf(fmaxf(ta[0], ta[1]), fmaxf(ta[2], ta[3]));
    float mb = fmaxf(fmaxf(tb[0], tb[1]), fmaxf(tb[2], tb[3]));
    for (int o = 32; o; o >>= 1) {
      ma = fmaxf(ma, __shfl_xor(ma, o, 64));
      mb = fmaxf(mb, __shfl_xor(mb, o, 64));
    }
    float za = 0.f, zb = 0.f;
#pragma unroll
    for (int j = 0; j < 4; j++) { za += expf(ta[j] - ma); zb += expf(tb[j] - mb); }
    for (int o = 32; o; o >>= 1) { za += __shfl_xor(za, o, 64); zb += __shfl_xor(zb, o, 64); }
    eacc += (double)(ma + logf(za)) + (double)(mb + logf(zb));
    if (store_p) {
      float ia = 1.f / za, ib = 1.f / zb;
      float* Pa  = P + ((size_t)bh * SEQ + qa) * SEQ;
      float* Pb2 = P + ((size_t)bh * SEQ + qb2) * SEQ;
#pragma unroll
      for (int j = 0; j < 4; j++) {
        int k = lane + 64 * j;
        if (k < SEQ) {
          Pa[k]  = expf(ta[j] - ma) * ia;
          Pb2[k] = expf(tb[j] - mb) * ib;
        }
      }
    }
  }
  if (lane == 0) atomicAdd(e_slot, -(double)INV_BETA * eacc);
}

// ------------------------------------------------------------------
// Attention bwd (fp32 compute, bf16 out). grid (96 bh, 4 mtiles, 2):
//   z=0: dQ[q,y] = -(P@K);  z=1: dK[k,y] = -(P^T@Q)
// ------------------------------------------------------------------
__global__ __launch_bounds__(256) void attn_bwd_k(
    const float* __restrict__ Kb, const float* __restrict__ Qb,
    const float* __restrict__ P, __bf16* __restrict__ dQg, __bf16* __restrict__ dKg)
{
  int bh = blockIdx.x;
  int b = bh / HN, h = bh - b * HN;
  int m0 = blockIdx.y * 64;
  int is_dk = blockIdx.z;
  const float* Bsrc = (is_dk ? Qb : Kb) + (size_t)(b * SEQ) * DIM + h * YD;
  const float* Pb = P + (size_t)bh * SEQ * SEQ;
  __bf16* Dst = (is_dk ? dKg : dQg) + (size_t)(b * SEQ) * DIM + h * YD;
  __shared__ float As[16][68];
  __shared__ float Bs[16][68];
  int tid = threadIdx.x;
  int tx = tid & 15, ty = tid >> 4;
  float acc[4][4] = {};
  for (int k0 = 0; k0 < SEQ; k0 += 16) {
    if (!is_dk) {
      int mm = tid >> 2, kc = (tid & 3) << 2;
      float4 v = make_float4(0.f, 0.f, 0.f, 0.f);
      if (m0 + mm < SEQ && k0 + kc < SEQ)
        v = *(const float4*)(Pb + (size_t)(m0 + mm) * SEQ + k0 + kc);
      As[kc + 0][mm] = v.x; As[kc + 1][mm] = v.y; As[kc + 2][mm] = v.z; As[kc + 3][mm] = v.w;
    } else {
      int kk = tid >> 4, mc = (tid & 15) << 2;
      float4 v = make_float4(0.f, 0.f, 0.f, 0.f);
      if (k0 + kk < SEQ && m0 + mc < SEQ)
        v = *(const float4*)(Pb + (size_t)(k0 + kk) * SEQ + m0 + mc);
      *(float4*)&As[kk][mc] = v;
    }
    {
      int kk = tid >> 4, yc = (tid & 15) << 2;
      float4 v = make_float4(0.f, 0.f, 0.f, 0.f);
      if (k0 + kk < SEQ)
        v = *(const float4*)(Bsrc + (size_t)(k0 + kk) * DIM + yc);
      *(float4*)&Bs[kk][yc] = v;
    }
    __syncthreads();
#pragma unroll
    for (int kk = 0; kk < 16; kk++) {
      float a[4], bb[4];
      *(float4*)a  = *(const float4*)&As[kk][ty * 4];
      *(float4*)bb = *(const float4*)&Bs[kk][tx * 4];
#pragma unroll
      for (int i = 0; i < 4; i++)
#pragma unroll
        for (int j = 0; j < 4; j++)
          acc[i][j] = fmaf(a[i], bb[j], acc[i][j]);
    }
    __syncthreads();
  }
#pragma unroll
  for (int i = 0; i < 4; i++) {
    int m = m0 + ty * 4 + i;
    if (m < SEQ) {
      v4bf o = { (__bf16)(-acc[i][0]), (__bf16)(-acc[i][1]),
                 (__bf16)(-acc[i][2]), (__bf16)(-acc[i][3]) };
      *(v4bf*)(Dst + (size_t)m * DIM + tx * 4) = o;
    }
  }
}

// ------------------------------------------------------------------
// Setup kernels
// ------------------------------------------------------------------
__global__ __launch_bounds__(256) void init_k(
    double* __restrict__ slots, __bf16* __restrict__ g,
    __bf16* __restrict__ dq, __bf16* __restrict__ dk)
{
  int i = blockIdx.x * 256 + threadIdx.x;
  if (i < 16) slots[i] = 0.0;
  size_t o = (size_t)TOK * DIM + i;   // pad rows [1568,1664)
  if (i < (MPAD - TOK) * DIM) {
    g[o] = (__bf16)0.f; dq[o] = (__bf16)0.f; dk[o] = (__bf16)0.f;
  }
}

__global__ __launch_bounds__(256) void cvt_k(
    const float* __restrict__ src, __bf16* __restrict__ dst, int n4)
{
  int i = blockIdx.x * 256 + threadIdx.x;
  if (i < n4) {
    float4 v = ((const float4*)src)[i];
    v4bf o = { (__bf16)v.x, (__bf16)v.y, (__bf16)v.z, (__bf16)v.w };
    *(v4bf*)(dst + 4 * (size_t)i) = o;
  }
}

// dst[c*R + r] = scale * src[r*C + c]; src [R,C]. R,C multiples of 32.
__global__ __launch_bounds__(256) void cvtT_k(
    const float* __restrict__ src, __bf16* __restrict__ dst,
    int R, int C, float scale)
{
  __shared__ float t[32][33];
  int r0 = blockIdx.y * 32, c0 = blockIdx.x * 32;
  int tx = threadIdx.x & 31, ty = threadIdx.x >> 5;
  for (int rr = ty; rr < 32; rr += 8)
    t[rr][tx] = src[(size_t)(r0 + rr) * C + c0 + tx];
  __syncthreads();
  for (int rr = ty; rr < 32; rr += 8)
    dst[(size_t)(c0 + rr) * R + r0 + tx] = (__bf16)(scale * t[tx][rr]);
}

__global__ __launch_bounds__(256) void axpy_k(
    const float* __restrict__ x, const float* __restrict__ g,
    float* __restrict__ y, float lr, int n4)
{
  int i = blockIdx.x * 256 + threadIdx.x;
  if (i < n4) {
    const float4 xv = ((const float4*)x)[i];
    const float4 gv = ((const float4*)g)[i];
    float4 o;
    o.x = xv.x - lr * gv.x; o.y = xv.y - lr * gv.y;
    o.z = xv.z - lr * gv.z; o.w = xv.w - lr * gv.w;
    ((float4*)y)[i] = o;
  }
}

__global__ void choose_k(const double* __restrict__ e, float* __restrict__ chosen) {
  if (threadIdx.x == 0) {
    double e0 = e[0];
    float c = 0.0625f;                 // lr0 * gamma^4
    if (e[4] < e0) c = 0.125f;         // kk=3
    if (e[3] < e0) c = 0.25f;          // kk=2
    if (e[2] < e0) c = 0.5f;           // kk=1
    if (e[1] < e0) c = 1.0f;           // kk=0 (highest priority)
    *chosen = c;
  }
}

__global__ __launch_bounds__(256) void update_k(
    const float* __restrict__ x, const float* __restrict__ g,
    const float* __restrict__ chosen, float* __restrict__ out, int n4)
{
  int i = blockIdx.x * 256 + threadIdx.x;
  float lr = *chosen;
  if (i < n4) {
    const float4 xv = ((const float4*)x)[i];
    const float4 gv = ((const float4*)g)[i];
    float4 o;
    o.x = xv.x - lr * gv.x; o.y = xv.y - lr * gv.y;
    o.z = xv.z - lr * gv.z; o.w = xv.w - lr * gv.w;
    ((float4*)out)[i] = o;
  }
}

// ------------------------------------------------------------------
extern "C" void kernel_launch(void* const* d_in, const int* in_sizes, int n_in,
                              void* d_out, int out_size, void* d_ws, size_t ws_size,
                              hipStream_t stream)
{
  const float* x     = (const float*)d_in[0];
  const float* gamma = (const float*)d_in[1];
  const float* delta = (const float*)d_in[2];
  const float* wk    = (const float*)d_in[3];  // [768(hy), 768(d)]
  const float* wq    = (const float*)d_in[4];
  const float* xi    = (const float*)d_in[5];  // [3072, 768]
  float* out = (float*)d_out;

  const size_t NE = (size_t)TOK * DIM;
  const size_t NP = (size_t)MPAD * DIM;

  double* slots = (double*)d_ws;
  float* fp = (float*)((char*)d_ws + 128);
  float* xhat = fp;  fp += NE;
  float* Kb   = fp;  fp += NP;
  float* Qb   = fp;  fp += NP;
  float* P    = fp;  fp += (size_t)96 * SEQ * SEQ;
  float* dG   = fp;  fp += NP;
  float* grad = fp;  fp += NE;
  float* xt   = fp;  fp += NE;
  float* rstd = fp;  fp += TOK;
  float* chosen = fp; fp += 16;
  __bf16* bp = (__bf16*)(((uintptr_t)fp + 15) & ~(uintptr_t)15);
  __bf16* g_bf   = bp;  bp += NP;
  __bf16* dQg_bf = bp;  bp += NP;
  __bf16* dKg_bf = bp;  bp += NP;
  __bf16* rh_bf  = bp;  bp += (size_t)MPAD * MXI;
  __bf16* wk_bf  = bp;  bp += (size_t)DIM * DIM;
  __bf16* wq_bf  = bp;  bp += (size_t)DIM * DIM;
  __bf16* wkT_bf = bp;  bp += (size_t)DIM * DIM;
  __bf16* wqT_bf = bp;  bp += (size_t)DIM * DIM;
  __bf16* xi_bf  = bp;  bp += (size_t)MXI * DIM;
  __bf16* xiT_bf = bp;  bp += (size_t)DIM * MXI;

  const int n4 = (int)(NE / 4);
  dim3 blk(256);
  dim3 gKQ(DIM / 128, MPAD / 128, 2);   // (6,13,2)
  dim3 gHop(MXI / 128, MPAD / 128);     // (24,13)
  dim3 gBwd(DIM / 128, MPAD / 128);     // (6,13)

  // ---- setup: zero slots/pads, bf16 conversions ----
  hipLaunchKernelGGL(init_k, dim3(((MPAD - TOK) * DIM + 255) / 256), blk, 0, stream,
                     slots, g_bf, dQg_bf, dKg_bf);
  hipLaunchKernelGGL(cvt_k, dim3((DIM * DIM / 4 + 255) / 256), blk, 0, stream, wk, wk_bf, DIM * DIM / 4);
  hipLaunchKernelGGL(cvt_k, dim3((DIM * DIM / 4 + 255) / 256), blk, 0, stream, wq, wq_bf, DIM * DIM / 4);
  hipLaunchKernelGGL(cvt_k, dim3((MXI * DIM / 4 + 255) / 256), blk, 0, stream, xi, xi_bf, MXI * DIM / 4);
  hipLaunchKernelGGL(cvtT_k, dim3(DIM / 32, DIM / 32), blk, 0, stream, wk, wkT_bf, DIM, DIM, 1.f);
  hipLaunchKernelGGL(cvtT_k, dim3(DIM / 32, DIM / 32), blk, 0, stream, wq, wqT_bf, DIM, DIM, 1.f);
  hipLaunchKernelGGL(cvtT_k, dim3(DIM / 32, MXI / 32), blk, 0, stream, xi, xiT_bf, MXI, DIM, -1.f);

  // ---- base forward ----
  hipLaunchKernelGGL(ln_fwd_k, dim3(TOK), blk, 0, stream, x, gamma, delta, g_bf, xhat, rstd, 1);
  hipLaunchKernelGGL(gemm_k<0>, gKQ, blk, 0, stream,
                     g_bf, wk_bf, DIM, (const __bf16*)nullptr, wq_bf, 0,
                     (const __bf16*)nullptr, (const __bf16*)nullptr, 0,
                     Kb, (__bf16*)Qb, DIM, (double*)nullptr);
  hipLaunchKernelGGL(attn_k, dim3(8 * HN, 2), blk, 0, stream, Kb, Qb, P, slots + 0, 1);
  hipLaunchKernelGGL(gemm_k<1>, gHop, blk, 0, stream,
                     g_bf, xi_bf, DIM, (const __bf16*)nullptr, (const __bf16*)nullptr, 0,
                     (const __bf16*)nullptr, (const __bf16*)nullptr, 0,
                     (float*)nullptr, rh_bf, MXI, slots + 0);
  // ---- backward ----
  hipLaunchKernelGGL(attn_bwd_k, dim3(8 * HN, 4, 2), blk, 0, stream, Kb, Qb, P, dQg_bf, dKg_bf);
  hipLaunchKernelGGL(gemm_k<3>, gBwd, blk, 0, stream,
                     dQg_bf, wqT_bf, DIM, dKg_bf, wkT_bf, DIM, rh_bf, xiT_bf, MXI,
                     dG, (__bf16*)nullptr, DIM, (double*)nullptr);
  hipLaunchKernelGGL(ln_bwd_k, dim3(TOK), blk, 0, stream, dG, xhat, rstd, gamma, grad);

  // ---- Armijo trials ----
  for (int kk = 3; kk >= 0; kk--) {
    float lr = 1.0f / (float)(1 << kk);
    hipLaunchKernelGGL(axpy_k, dim3((n4 + 255) / 256), blk, 0, stream, x, grad, xt, lr, n4);
    hipLaunchKernelGGL(ln_fwd_k, dim3(TOK), blk, 0, stream, xt, gamma, delta, g_bf, xhat, rstd, 0);
    hipLaunchKernelGGL(gemm_k<0>, gKQ, blk, 0, stream,
                       g_bf, wk_bf, DIM, (const __bf16*)nullptr, wq_bf, 0,
                       (const __bf16*)nullptr, (const __bf16*)nullptr, 0,
                       Kb, (__bf16*)Qb, DIM, (double*)nullptr);
    hipLaunchKernelGGL(attn_k, dim3(8 * HN, 2), blk, 0, stream, Kb, Qb, P, slots + 1 + kk, 0);
    hipLaunchKernelGGL(gemm_k<2>, gHop, blk, 0, stream,
                       g_bf, xi_bf, DIM, (const __bf16*)nullptr, (const __bf16*)nullptr, 0,
                       (const __bf16*)nullptr, (const __bf16*)nullptr, 0,
                       (float*)nullptr, (__bf16*)nullptr, MXI, slots + 1 + kk);
  }

  // ---- choose lr, final update ----
  hipLaunchKernelGGL(choose_k, dim3(1), dim3(64), 0, stream, slots, chosen);
  hipLaunchKernelGGL(update_k, dim3((n4 + 255) / 256), blk, 0, stream, x, grad, chosen, out, n4);
}

// Round 4
// 519.208 us; speedup vs baseline: 8.4522x; 1.4994x over previous
//
#include <hip/hip_runtime.h>
#include <math.h>

#define TOK 1568      // B*N = 8*196
#define MPAD 1664     // 13 * 128
#define DIM 768
#define HN 12
#define SEQ 196
#define YD 64
#define MXI 3072
#define BETA_F 0.125f
#define INV_BETA 8.0f
#define LN_EPS_F 1e-5f

typedef __bf16 v8bf __attribute__((ext_vector_type(8)));
typedef __bf16 v4bf __attribute__((ext_vector_type(4)));
typedef float  v4f  __attribute__((ext_vector_type(4)));

// ------------------------------------------------------------------
// LayerNorm forward -> bf16 g (+ fp32 xhat/rstd when store_stats)
// ------------------------------------------------------------------
__global__ __launch_bounds__(256) void ln_fwd_k(
    const float* __restrict__ x, const float* __restrict__ gamma,
    const float* __restrict__ delta, __bf16* __restrict__ g,
    float* __restrict__ xhat, float* __restrict__ rstd, int store_stats)
{
  __shared__ float s[4];
  int tok = blockIdx.x;
  int tid = threadIdx.x;
  const float* xp = x + (size_t)tok * DIM;
  float v0 = xp[tid], v1 = xp[tid + 256], v2 = xp[tid + 512];
  float sum = v0 + v1 + v2;
  for (int o = 32; o; o >>= 1) sum += __shfl_xor(sum, o, 64);
  if ((tid & 63) == 0) s[tid >> 6] = sum;
  __syncthreads();
  float mu = (s[0] + s[1] + s[2] + s[3]) * (1.0f / DIM);
  __syncthreads();
  float d0 = v0 - mu, d1 = v1 - mu, d2 = v2 - mu;
  float sq = d0 * d0 + d1 * d1 + d2 * d2;
  for (int o = 32; o; o >>= 1) sq += __shfl_xor(sq, o, 64);
  if ((tid & 63) == 0) s[tid >> 6] = sq;
  __syncthreads();
  float var = (s[0] + s[1] + s[2] + s[3]) * (1.0f / DIM);
  float r = rsqrtf(var + LN_EPS_F);
  float xh0 = d0 * r, xh1 = d1 * r, xh2 = d2 * r;
  size_t base = (size_t)tok * DIM;
  g[base + tid]       = (__bf16)(gamma[tid] * xh0 + delta[tid]);
  g[base + tid + 256] = (__bf16)(gamma[tid + 256] * xh1 + delta[tid + 256]);
  g[base + tid + 512] = (__bf16)(gamma[tid + 512] * xh2 + delta[tid + 512]);
  if (store_stats) {
    xhat[base + tid] = xh0; xhat[base + tid + 256] = xh1; xhat[base + tid + 512] = xh2;
    if (tid == 0) rstd[tok] = r;
  }
}

// ------------------------------------------------------------------
// Fused trial step + LayerNorm: v = x - lr(t)*grad, LN(v) -> g_tr[t]
// grid (TOK, 4)
// ------------------------------------------------------------------
__global__ __launch_bounds__(256) void axpyln_k(
    const float* __restrict__ x, const float* __restrict__ grad,
    const float* __restrict__ gamma, const float* __restrict__ delta,
    __bf16* __restrict__ gt)
{
  __shared__ float s[4];
  int tok = blockIdx.x, t = blockIdx.y;
  float lr = 1.0f / (float)(1 << t);   // t == kk, lr = 0.5^kk
  int tid = threadIdx.x;
  const float* xp = x + (size_t)tok * DIM;
  const float* gp = grad + (size_t)tok * DIM;
  float v0 = xp[tid]       - lr * gp[tid];
  float v1 = xp[tid + 256] - lr * gp[tid + 256];
  float v2 = xp[tid + 512] - lr * gp[tid + 512];
  float sum = v0 + v1 + v2;
  for (int o = 32; o; o >>= 1) sum += __shfl_xor(sum, o, 64);
  if ((tid & 63) == 0) s[tid >> 6] = sum;
  __syncthreads();
  float mu = (s[0] + s[1] + s[2] + s[3]) * (1.0f / DIM);
  __syncthreads();
  float d0 = v0 - mu, d1 = v1 - mu, d2 = v2 - mu;
  float sq = d0 * d0 + d1 * d1 + d2 * d2;
  for (int o = 32; o; o >>= 1) sq += __shfl_xor(sq, o, 64);
  if ((tid & 63) == 0) s[tid >> 6] = sq;
  __syncthreads();
  float var = (s[0] + s[1] + s[2] + s[3]) * (1.0f / DIM);
  float r = rsqrtf(var + LN_EPS_F);
  __bf16* out = gt + ((size_t)t * MPAD + tok) * DIM;
  out[tid]       = (__bf16)(gamma[tid] * (d0 * r) + delta[tid]);
  out[tid + 256] = (__bf16)(gamma[tid + 256] * (d1 * r) + delta[tid + 256]);
  out[tid + 512] = (__bf16)(gamma[tid + 512] * (d2 * r) + delta[tid + 512]);
}

// ------------------------------------------------------------------
// LayerNorm backward (fp32)
// ------------------------------------------------------------------
__global__ __launch_bounds__(256) void ln_bwd_k(
    const float* __restrict__ dG, const float* __restrict__ xhat,
    const float* __restrict__ rstd, const float* __restrict__ gamma,
    float* __restrict__ grad)
{
  __shared__ float s[8];
  int tok = blockIdx.x;
  int tid = threadIdx.x;
  size_t base = (size_t)tok * DIM;
  float dh0 = dG[base + tid]       * gamma[tid];
  float dh1 = dG[base + tid + 256] * gamma[tid + 256];
  float dh2 = dG[base + tid + 512] * gamma[tid + 512];
  float xh0 = xhat[base + tid], xh1 = xhat[base + tid + 256], xh2 = xhat[base + tid + 512];
  float s1 = dh0 + dh1 + dh2;
  float s2 = dh0 * xh0 + dh1 * xh1 + dh2 * xh2;
  for (int o = 32; o; o >>= 1) { s1 += __shfl_xor(s1, o, 64); s2 += __shfl_xor(s2, o, 64); }
  if ((tid & 63) == 0) { s[tid >> 6] = s1; s[4 + (tid >> 6)] = s2; }
  __syncthreads();
  float m1 = (s[0] + s[1] + s[2] + s[3]) * (1.0f / DIM);
  float m2 = (s[4] + s[5] + s[6] + s[7]) * (1.0f / DIM);
  float r = rstd[tok];
  grad[base + tid]       = r * (dh0 - m1 - xh0 * m2);
  grad[base + tid + 256] = r * (dh1 - m1 - xh1 * m2);
  grad[base + tid + 512] = r * (dh2 - m1 - xh2 * m2);
}

// ------------------------------------------------------------------
// Stage one 128x32 bf16 tile into LDS via global_load_lds width=16.
// ------------------------------------------------------------------
__device__ __forceinline__ void stage_tile(
    const __bf16* __restrict__ G, int ldK, int r0, int k0,
    __bf16* S, int tid, int w)
{
#pragma unroll
  for (int r = 0; r < 2; r++) {
    int ch = (r << 8) + tid;
    int row = ch >> 2, col = (ch & 3) << 3;
    __builtin_amdgcn_global_load_lds(
        (__attribute__((address_space(1))) uint32_t*)(G + (size_t)(r0 + row) * ldK + k0 + col),
        (__attribute__((address_space(3))) uint32_t*)(S + (r << 11) + (w << 9)),
        16, 0, 0);
  }
}

// ------------------------------------------------------------------
// MFMA GEMM: C[M,N] = A[M,K] @ B[N,K]^T, bf16 in, fp32 accum.
// 128x128 tile, BK=32, double-buffered LDS, 4 waves (2x2 of 64x64).
// MODE 0: dual fp32 store (z: B0->Cf, B1->(float*)Cb)          [base KQ]
// MODE 1: relu -> bf16 Cb + energy into e_slot[0]              [base hopfield]
// MODE 3: three K-segments -> fp32 Cf                          [fused bwd]
// MODE 4: dual bf16 store (z: B0->(bf16*)Cf, B1->Cb)           [trial KQ]
// MODE 5: relu energy only, slot = e_slot[blockIdx.y/13]       [trial hopfield]
// ------------------------------------------------------------------
template <int MODE>
__global__ __launch_bounds__(256) void gemm_k(
    const __bf16* __restrict__ A0, const __bf16* __restrict__ B0, int K0,
    const __bf16* __restrict__ A1, const __bf16* __restrict__ B1, int K1,
    const __bf16* __restrict__ A2, const __bf16* __restrict__ B2, int K2,
    float* __restrict__ Cf, __bf16* __restrict__ Cb, int N,
    double* __restrict__ e_slot)
{
  __shared__ __align__(16) __bf16 As[2][4096];
  __shared__ __align__(16) __bf16 Bs[2][4096];
  int tid = threadIdx.x, lane = tid & 63, w = tid >> 6;
  int wm = (w & 1) << 6, wn = (w >> 1) << 6;
  int m0 = blockIdx.y * 128, n0 = blockIdx.x * 128;

  const __bf16* Bsel = B0;
  if ((MODE == 0 || MODE == 4) && blockIdx.z) Bsel = B1;

  v4f zero = {0.f, 0.f, 0.f, 0.f};
  v4f acc[4][4];
#pragma unroll
  for (int i = 0; i < 4; i++)
#pragma unroll
    for (int j = 0; j < 4; j++) acc[i][j] = zero;

  const int nseg = (MODE == 3) ? 3 : 1;
  for (int seg = 0; seg < nseg; seg++) {
    const __bf16* A = (seg == 0) ? A0 : (seg == 1) ? A1 : A2;
    const __bf16* B = (seg == 0) ? Bsel : (seg == 1) ? B1 : B2;
    const int K = (seg == 0) ? K0 : (seg == 1) ? K1 : K2;
    const int nk = K >> 5;   // always even here (24 or 96)
    stage_tile(A, K, m0, 0, As[0], tid, w);
    stage_tile(B, K, n0, 0, Bs[0], tid, w);
    for (int kt = 0; kt < nk; kt++) {
      __syncthreads();   // buf[kt] staged (vmcnt drain) + prev compute done
      int nxt = kt + 1;
      if (nxt < nk) {
        stage_tile(A, K, m0, nxt << 5, As[nxt & 1], tid, w);
        stage_tile(B, K, n0, nxt << 5, Bs[nxt & 1], tid, w);
      }
      const __bf16* Ac = As[kt & 1];
      const __bf16* Bc = Bs[kt & 1];
      int mrow = lane & 15, ksel = (lane >> 4) << 3;
      v8bf af[4], bfr[4];
#pragma unroll
      for (int i = 0; i < 4; i++) {
        af[i]  = *(const v8bf*)(Ac + (wm + (i << 4) + mrow) * 32 + ksel);
        bfr[i] = *(const v8bf*)(Bc + (wn + (i << 4) + mrow) * 32 + ksel);
      }
#pragma unroll
      for (int i = 0; i < 4; i++)
#pragma unroll
        for (int j = 0; j < 4; j++)
          acc[i][j] = __builtin_amdgcn_mfma_f32_16x16x32_bf16(af[i], bfr[j], acc[i][j], 0, 0, 0);
    }
  }

  // C/D: col = lane&15, row = quad*4 + reg  (verified layout)
  int quad = lane >> 4, ncol = lane & 15;
  if (MODE == 0 || MODE == 3) {
    float* Csel = (MODE == 0 && blockIdx.z) ? (float*)Cb : Cf;
#pragma unroll
    for (int i = 0; i < 4; i++)
#pragma unroll
      for (int j = 0; j < 4; j++) {
        int row = m0 + wm + (i << 4) + (quad << 2);
        int col = n0 + wn + (j << 4) + ncol;
#pragma unroll
        for (int r = 0; r < 4; r++)
          Csel[(size_t)(row + r) * N + col] = acc[i][j][r];
      }
  } else if (MODE == 4) {
    __bf16* Cout = blockIdx.z ? Cb : (__bf16*)Cf;
#pragma unroll
    for (int i = 0; i < 4; i++)
#pragma unroll
      for (int j = 0; j < 4; j++) {
        int row = m0 + wm + (i << 4) + (quad << 2);
        int col = n0 + wn + (j << 4) + ncol;
#pragma unroll
        for (int r = 0; r < 4; r++)
          Cout[(size_t)(row + r) * N + col] = (__bf16)acc[i][j][r];
      }
  } else {  // MODE 1 / 5: relu energy (+ bf16 store for MODE 1)
    float e = 0.f;
#pragma unroll
    for (int i = 0; i < 4; i++)
#pragma unroll
      for (int j = 0; j < 4; j++) {
        int row = m0 + wm + (i << 4) + (quad << 2);
        int col = n0 + wn + (j << 4) + ncol;
#pragma unroll
        for (int r = 0; r < 4; r++) {
          float v = acc[i][j][r];
          v = v > 0.f ? v : 0.f;
          e += v * v;
          if (MODE == 1) Cb[(size_t)(row + r) * N + col] = (__bf16)v;
        }
      }
    for (int o = 32; o; o >>= 1) e += __shfl_xor(e, o, 64);
    double* slot = (MODE == 5) ? (e_slot + blockIdx.y / 13) : e_slot;
    if (lane == 0) atomicAdd(slot, -0.5 * (double)e);
  }
}

// ------------------------------------------------------------------
// Attention fwd (base, fp32 K/Q): grid (96 bh, 2 q-halves). Stores P.
// ------------------------------------------------------------------
__global__ __launch_bounds__(256) void attn_k(
    const float* __restrict__ Kb, const float* __restrict__ Qb,
    float* __restrict__ P, double* __restrict__ e_slot)
{
  int bh = blockIdx.x;
  int z = blockIdx.y;
  int b = bh / HN, h = bh - b * HN;
  const float* Kp = Kb + (size_t)(b * SEQ) * DIM + h * YD;
  const float* Qp = Qb + (size_t)(b * SEQ) * DIM + h * YD;
  __shared__ float4 Ks4[16 * SEQ + 64];
  __shared__ float4 Qs4[4][2][16];
  int tid = threadIdx.x, lane = tid & 63, w = tid >> 6;
  for (int i = tid; i < SEQ * 16; i += 256) {
    int k = i >> 4, y4 = i & 15;
    Ks4[y4 * SEQ + k] = *(const float4*)(Kp + (size_t)k * DIM + y4 * 4);
  }
  __syncthreads();
  double eacc = 0.0;
  for (int qp = 49 * z + w; qp < 49 * (z + 1); qp += 4) {
    int qa = qp, qb2 = qp + 98;
    if (lane < 32) {
      int which = lane >> 4, yy = lane & 15;
      int q = which ? qb2 : qa;
      Qs4[w][which][yy] = *(const float4*)(Qp + (size_t)q * DIM + yy * 4);
    }
    __builtin_amdgcn_s_waitcnt(0xc07f);  // lgkmcnt(0)
    float da[4] = {0.f, 0.f, 0.f, 0.f}, db[4] = {0.f, 0.f, 0.f, 0.f};
#pragma unroll
    for (int y4 = 0; y4 < 16; y4++) {
      float4 a4 = Qs4[w][0][y4];
      float4 b4 = Qs4[w][1][y4];
#pragma unroll
      for (int j = 0; j < 4; j++) {
        float4 kv = Ks4[y4 * SEQ + lane + 64 * j];
        da[j] = fmaf(kv.x, a4.x, da[j]); da[j] = fmaf(kv.y, a4.y, da[j]);
        da[j] = fmaf(kv.z, a4.z, da[j]); da[j] = fmaf(kv.w, a4.w, da[j]);
        db[j] = fmaf(kv.x, b4.x, db[j]); db[j] = fmaf(kv.y, b4.y, db[j]);
        db[j] = fmaf(kv.z, b4.z, db[j]); db[j] = fmaf(kv.w, b4.w, db[j]);
      }
    }
    float ta[4], tb[4];
#pragma unroll
    for (int j = 0; j < 4; j++) {
      bool valid = (lane + 64 * j) < SEQ;
      ta[j] = valid ? BETA_F * da[j] : -INFINITY;
      tb[j] = valid ? BETA_F * db[j] : -INFINITY;
    }
    float ma = fmaxf(fmaxf(ta[0], ta[1]), fmaxf(ta[2], ta[3]));
    float mb = fmaxf(fmaxf(tb[0], tb[1]), fmaxf(tb[2], tb[3]));
    for (int o = 32; o; o >>= 1) {
      ma = fmaxf(ma, __shfl_xor(ma, o, 64));
      mb = fmaxf(mb, __shfl_xor(mb, o, 64));
    }
    float za = 0.f, zb = 0.f;
#pragma unroll
    for (int j = 0; j < 4; j++) { za += expf(ta[j] - ma); zb += expf(tb[j] - mb); }
    for (int o = 32; o; o >>= 1) { za += __shfl_xor(za, o, 64); zb += __shfl_xor(zb, o, 64); }
    eacc += (double)(ma + logf(za)) + (double)(mb + logf(zb));
    {
      float ia = 1.f / za, ib = 1.f / zb;
      float* Pa  = P + ((size_t)bh * SEQ + qa) * SEQ;
      float* Pb2 = P + ((size_t)bh * SEQ + qb2) * SEQ;
#pragma unroll
      for (int j = 0; j < 4; j++) {
        int k = lane + 64 * j;
        if (k < SEQ) {
          Pa[k]  = expf(ta[j] - ma) * ia;
          Pb2[k] = expf(tb[j] - mb) * ib;
        }
      }
    }
  }
  if (lane == 0) atomicAdd(e_slot, -(double)INV_BETA * eacc);
}

// ------------------------------------------------------------------
// Attention fwd (trials, bf16 K/Q): grid (96 bh, 2 q-halves, 4 trials).
// Energy only -> slots[1 + t].
// ------------------------------------------------------------------
__global__ __launch_bounds__(256) void attn_bf_k(
    const __bf16* __restrict__ Kt, const __bf16* __restrict__ Qt,
    double* __restrict__ slots)
{
  int bh = blockIdx.x;
  int z = blockIdx.y;
  int t = blockIdx.z;
  int b = bh / HN, h = bh - b * HN;
  const __bf16* Kp = Kt + ((size_t)t * MPAD + b * SEQ) * DIM + h * YD;
  const __bf16* Qp = Qt + ((size_t)t * MPAD + b * SEQ) * DIM + h * YD;
  __shared__ float4 Ks4[16 * SEQ + 64];
  __shared__ float4 Qs4[4][2][16];
  int tid = threadIdx.x, lane = tid & 63, w = tid >> 6;
  for (int i = tid; i < SEQ * 16; i += 256) {
    int k = i >> 4, y4 = i & 15;
    v4bf kv = *(const v4bf*)(Kp + (size_t)k * DIM + y4 * 4);
    Ks4[y4 * SEQ + k] = make_float4((float)kv[0], (float)kv[1], (float)kv[2], (float)kv[3]);
  }
  __syncthreads();
  double eacc = 0.0;
  for (int qp = 49 * z + w; qp < 49 * (z + 1); qp += 4) {
    int qa = qp, qb2 = qp + 98;
    if (lane < 32) {
      int which = lane >> 4, yy = lane & 15;
      int q = which ? qb2 : qa;
      v4bf qv = *(const v4bf*)(Qp + (size_t)q * DIM + yy * 4);
      Qs4[w][which][yy] = make_float4((float)qv[0], (float)qv[1], (float)qv[2], (float)qv[3]);
    }
    __builtin_amdgcn_s_waitcnt(0xc07f);  // lgkmcnt(0)
    float da[4] = {0.f, 0.f, 0.f, 0.f}, db[4] = {0.f, 0.f, 0.f, 0.f};
#pragma unroll
    for (int y4 = 0; y4 < 16; y4++) {
      float4 a4 = Qs4[w][0][y4];
      float4 b4 = Qs4[w][1][y4];
#pragma unroll
      for (int j = 0; j < 4; j++) {
        float4 kv = Ks4[y4 * SEQ + lane + 64 * j];
        da[j] = fmaf(kv.x, a4.x, da[j]); da[j] = fmaf(kv.y, a4.y, da[j]);
        da[j] = fmaf(kv.z, a4.z, da[j]); da[j] = fmaf(kv.w, a4.w, da[j]);
        db[j] = fmaf(kv.x, b4.x, db[j]); db[j] = fmaf(kv.y, b4.y, db[j]);
        db[j] = fmaf(kv.z, b4.z, db[j]); db[j] = fmaf(kv.w, b4.w, db[j]);
      }
    }
    float ta[4], tb[4];
#pragma unroll
    for (int j = 0; j < 4; j++) {
      bool valid = (lane + 64 * j) < SEQ;
      ta[j] = valid ? BETA_F * da[j] : -INFINITY;
      tb[j] = valid ? BETA_F * db[j] : -INFINITY;
    }
    float ma = fmaxf(fmaxf(ta[0], ta[1]), fmaxf(ta[2], ta[3]));
    float mb = fmaxf(fmaxf(tb[0], tb[1]), fmaxf(tb[2], tb[3]));
    for (int o = 32; o; o >>= 1) {
      ma = fmaxf(ma, __shfl_xor(ma, o, 64));
      mb = fmaxf(mb, __shfl_xor(mb, o, 64));
    }
    float za = 0.f, zb = 0.f;
#pragma unroll
    for (int j = 0; j < 4; j++) { za += expf(ta[j] - ma); zb += expf(tb[j] - mb); }
    for (int o = 32; o; o >>= 1) { za += __shfl_xor(za, o, 64); zb += __shfl_xor(zb, o, 64); }
    eacc += (double)(ma + logf(za)) + (double)(mb + logf(zb));
  }
  if (lane == 0) atomicAdd(slots + 1 + t, -(double)INV_BETA * eacc);
}

// ------------------------------------------------------------------
// Attention bwd (fp32 compute, bf16 out). grid (96 bh, 4 mtiles, 2).
// ------------------------------------------------------------------
__global__ __launch_bounds__(256) void attn_bwd_k(
    const float* __restrict__ Kb, const float* __restrict__ Qb,
    const float* __restrict__ P, __bf16* __restrict__ dQg, __bf16* __restrict__ dKg)
{
  int bh = blockIdx.x;
  int b = bh / HN, h = bh - b * HN;
  int m0 = blockIdx.y * 64;
  int is_dk = blockIdx.z;
  const float* Bsrc = (is_dk ? Qb : Kb) + (size_t)(b * SEQ) * DIM + h * YD;
  const float* Pb = P + (size_t)bh * SEQ * SEQ;
  __bf16* Dst = (is_dk ? dKg : dQg) + (size_t)(b * SEQ) * DIM + h * YD;
  __shared__ float As[16][68];
  __shared__ float Bs[16][68];
  int tid = threadIdx.x;
  int tx = tid & 15, ty = tid >> 4;
  float acc[4][4] = {};
  for (int k0 = 0; k0 < SEQ; k0 += 16) {
    if (!is_dk) {
      int mm = tid >> 2, kc = (tid & 3) << 2;
      float4 v = make_float4(0.f, 0.f, 0.f, 0.f);
      if (m0 + mm < SEQ && k0 + kc < SEQ)
        v = *(const float4*)(Pb + (size_t)(m0 + mm) * SEQ + k0 + kc);
      As[kc + 0][mm] = v.x; As[kc + 1][mm] = v.y; As[kc + 2][mm] = v.z; As[kc + 3][mm] = v.w;
    } else {
      int kk = tid >> 4, mc = (tid & 15) << 2;
      float4 v = make_float4(0.f, 0.f, 0.f, 0.f);
      if (k0 + kk < SEQ && m0 + mc < SEQ)
        v = *(const float4*)(Pb + (size_t)(k0 + kk) * SEQ + m0 + mc);
      *(float4*)&As[kk][mc] = v;
    }
    {
      int kk = tid >> 4, yc = (tid & 15) << 2;
      float4 v = make_float4(0.f, 0.f, 0.f, 0.f);
      if (k0 + kk < SEQ)
        v = *(const float4*)(Bsrc + (size_t)(k0 + kk) * DIM + yc);
      *(float4*)&Bs[kk][yc] = v;
    }
    __syncthreads();
#pragma unroll
    for (int kk = 0; kk < 16; kk++) {
      float a[4], bb[4];
      *(float4*)a  = *(const float4*)&As[kk][ty * 4];
      *(float4*)bb = *(const float4*)&Bs[kk][tx * 4];
#pragma unroll
      for (int i = 0; i < 4; i++)
#pragma unroll
        for (int j = 0; j < 4; j++)
          acc[i][j] = fmaf(a[i], bb[j], acc[i][j]);
    }
    __syncthreads();
  }
#pragma unroll
  for (int i = 0; i < 4; i++) {
    int m = m0 + ty * 4 + i;
    if (m < SEQ) {
      v4bf o = { (__bf16)(-acc[i][0]), (__bf16)(-acc[i][1]),
                 (__bf16)(-acc[i][2]), (__bf16)(-acc[i][3]) };
      *(v4bf*)(Dst + (size_t)m * DIM + tx * 4) = o;
    }
  }
}

// ------------------------------------------------------------------
// Setup kernels
// ------------------------------------------------------------------
__global__ __launch_bounds__(256) void init_k(
    double* __restrict__ slots, __bf16* __restrict__ g,
    __bf16* __restrict__ gt, __bf16* __restrict__ dq, __bf16* __restrict__ dk)
{
  int i = blockIdx.x * 256 + threadIdx.x;
  if (i < 16) slots[i] = 0.0;
  const int PADN = (MPAD - TOK) * DIM;   // 73728
  if (i < PADN) {
    size_t o = (size_t)TOK * DIM + i;
    g[o] = (__bf16)0.f; dq[o] = (__bf16)0.f; dk[o] = (__bf16)0.f;
#pragma unroll
    for (int t = 0; t < 4; t++)
      gt[(size_t)t * MPAD * DIM + o] = (__bf16)0.f;
  }
}

__global__ __launch_bounds__(256) void cvt_k(
    const float* __restrict__ src, __bf16* __restrict__ dst, int n4)
{
  int i = blockIdx.x * 256 + threadIdx.x;
  if (i < n4) {
    float4 v = ((const float4*)src)[i];
    v4bf o = { (__bf16)v.x, (__bf16)v.y, (__bf16)v.z, (__bf16)v.w };
    *(v4bf*)(dst + 4 * (size_t)i) = o;
  }
}

// dst[c*R + r] = scale * src[r*C + c]; src [R,C]. R,C multiples of 32.
__global__ __launch_bounds__(256) void cvtT_k(
    const float* __restrict__ src, __bf16* __restrict__ dst,
    int R, int C, float scale)
{
  __shared__ float t[32][33];
  int r0 = blockIdx.y * 32, c0 = blockIdx.x * 32;
  int tx = threadIdx.x & 31, ty = threadIdx.x >> 5;
  for (int rr = ty; rr < 32; rr += 8)
    t[rr][tx] = src[(size_t)(r0 + rr) * C + c0 + tx];
  __syncthreads();
  for (int rr = ty; rr < 32; rr += 8)
    dst[(size_t)(c0 + rr) * R + r0 + tx] = (__bf16)(scale * t[tx][rr]);
}

__global__ void choose_k(const double* __restrict__ e, float* __restrict__ chosen) {
  if (threadIdx.x == 0) {
    double e0 = e[0];
    float c = 0.0625f;                 // lr0 * gamma^4
    if (e[4] < e0) c = 0.125f;         // kk=3
    if (e[3] < e0) c = 0.25f;          // kk=2
    if (e[2] < e0) c = 0.5f;           // kk=1
    if (e[1] < e0) c = 1.0f;           // kk=0 (highest priority)
    *chosen = c;
  }
}

__global__ __launch_bounds__(256) void update_k(
    const float* __restrict__ x, const float* __restrict__ g,
    const float* __restrict__ chosen, float* __restrict__ out, int n4)
{
  int i = blockIdx.x * 256 + threadIdx.x;
  float lr = *chosen;
  if (i < n4) {
    const float4 xv = ((const float4*)x)[i];
    const float4 gv = ((const float4*)g)[i];
    float4 o;
    o.x = xv.x - lr * gv.x; o.y = xv.y - lr * gv.y;
    o.z = xv.z - lr * gv.z; o.w = xv.w - lr * gv.w;
    ((float4*)out)[i] = o;
  }
}

// ------------------------------------------------------------------
extern "C" void kernel_launch(void* const* d_in, const int* in_sizes, int n_in,
                              void* d_out, int out_size, void* d_ws, size_t ws_size,
                              hipStream_t stream)
{
  const float* x     = (const float*)d_in[0];
  const float* gamma = (const float*)d_in[1];
  const float* delta = (const float*)d_in[2];
  const float* wk    = (const float*)d_in[3];  // [768(hy), 768(d)]
  const float* wq    = (const float*)d_in[4];
  const float* xi    = (const float*)d_in[5];  // [3072, 768]
  float* out = (float*)d_out;

  const size_t NE = (size_t)TOK * DIM;
  const size_t NP = (size_t)MPAD * DIM;

  double* slots = (double*)d_ws;
  float* fp = (float*)((char*)d_ws + 128);
  float* xhat = fp;  fp += NE;
  float* Kb   = fp;  fp += NP;
  float* Qb   = fp;  fp += NP;
  float* P    = fp;  fp += (size_t)96 * SEQ * SEQ;
  float* dG   = fp;  fp += NP;
  float* grad = fp;  fp += NE;
  float* rstd = fp;  fp += TOK;
  float* chosen = fp; fp += 16;
  __bf16* bp = (__bf16*)(((uintptr_t)fp + 15) & ~(uintptr_t)15);
  __bf16* g_bf   = bp;  bp += NP;
  __bf16* g_tr   = bp;  bp += 4 * NP;
  __bf16* dQg_bf = bp;  bp += NP;
  __bf16* dKg_bf = bp;  bp += NP;
  __bf16* rh_bf  = bp;  bp += (size_t)MPAD * MXI;
  __bf16* wk_bf  = bp;  bp += (size_t)DIM * DIM;
  __bf16* wq_bf  = bp;  bp += (size_t)DIM * DIM;
  __bf16* wkT_bf = bp;  bp += (size_t)DIM * DIM;
  __bf16* wqT_bf = bp;  bp += (size_t)DIM * DIM;
  __bf16* xi_bf  = bp;  bp += (size_t)MXI * DIM;
  __bf16* xiT_bf = bp;  bp += (size_t)DIM * MXI;
  __bf16* KbT_bf = bp;  bp += 4 * NP;
  __bf16* QbT_bf = bp;  bp += 4 * NP;

  const int n4 = (int)(NE / 4);
  dim3 blk(256);
  dim3 gKQ(DIM / 128, MPAD / 128, 2);       // (6,13,2)
  dim3 gHop(MXI / 128, MPAD / 128);         // (24,13)
  dim3 gBwd(DIM / 128, MPAD / 128);         // (6,13)
  dim3 gKQt(DIM / 128, 4 * MPAD / 128, 2);  // (6,52,2)
  dim3 gHopT(MXI / 128, 4 * MPAD / 128);    // (24,52)

  // ---- setup ----
  hipLaunchKernelGGL(init_k, dim3(((MPAD - TOK) * DIM + 255) / 256), blk, 0, stream,
                     slots, g_bf, g_tr, dQg_bf, dKg_bf);
  hipLaunchKernelGGL(cvt_k, dim3((DIM * DIM / 4 + 255) / 256), blk, 0, stream, wk, wk_bf, DIM * DIM / 4);
  hipLaunchKernelGGL(cvt_k, dim3((DIM * DIM / 4 + 255) / 256), blk, 0, stream, wq, wq_bf, DIM * DIM / 4);
  hipLaunchKernelGGL(cvt_k, dim3((MXI * DIM / 4 + 255) / 256), blk, 0, stream, xi, xi_bf, MXI * DIM / 4);
  hipLaunchKernelGGL(cvtT_k, dim3(DIM / 32, DIM / 32), blk, 0, stream, wk, wkT_bf, DIM, DIM, 1.f);
  hipLaunchKernelGGL(cvtT_k, dim3(DIM / 32, DIM / 32), blk, 0, stream, wq, wqT_bf, DIM, DIM, 1.f);
  hipLaunchKernelGGL(cvtT_k, dim3(DIM / 32, MXI / 32), blk, 0, stream, xi, xiT_bf, MXI, DIM, -1.f);

  // ---- base forward ----
  hipLaunchKernelGGL(ln_fwd_k, dim3(TOK), blk, 0, stream, x, gamma, delta, g_bf, xhat, rstd, 1);
  hipLaunchKernelGGL(gemm_k<0>, gKQ, blk, 0, stream,
                     g_bf, wk_bf, DIM, (const __bf16*)nullptr, wq_bf, 0,
                     (const __bf16*)nullptr, (const __bf16*)nullptr, 0,
                     Kb, (__bf16*)Qb, DIM, (double*)nullptr);
  hipLaunchKernelGGL(attn_k, dim3(8 * HN, 2), blk, 0, stream, Kb, Qb, P, slots + 0);
  hipLaunchKernelGGL(gemm_k<1>, gHop, blk, 0, stream,
                     g_bf, xi_bf, DIM, (const __bf16*)nullptr, (const __bf16*)nullptr, 0,
                     (const __bf16*)nullptr, (const __bf16*)nullptr, 0,
                     (float*)nullptr, rh_bf, MXI, slots + 0);
  // ---- backward ----
  hipLaunchKernelGGL(attn_bwd_k, dim3(8 * HN, 4, 2), blk, 0, stream, Kb, Qb, P, dQg_bf, dKg_bf);
  hipLaunchKernelGGL(gemm_k<3>, gBwd, blk, 0, stream,
                     dQg_bf, wqT_bf, DIM, dKg_bf, wkT_bf, DIM, rh_bf, xiT_bf, MXI,
                     dG, (__bf16*)nullptr, DIM, (double*)nullptr);
  hipLaunchKernelGGL(ln_bwd_k, dim3(TOK), blk, 0, stream, dG, xhat, rstd, gamma, grad);

  // ---- Armijo trials (all 4 batched) ----
  hipLaunchKernelGGL(axpyln_k, dim3(TOK, 4), blk, 0, stream, x, grad, gamma, delta, g_tr);
  hipLaunchKernelGGL(gemm_k<4>, gKQt, blk, 0, stream,
                     g_tr, wk_bf, DIM, (const __bf16*)nullptr, wq_bf, 0,
                     (const __bf16*)nullptr, (const __bf16*)nullptr, 0,
                     (float*)KbT_bf, QbT_bf, DIM, (double*)nullptr);
  hipLaunchKernelGGL(attn_bf_k, dim3(8 * HN, 2, 4), blk, 0, stream, KbT_bf, QbT_bf, slots);
  hipLaunchKernelGGL(gemm_k<5>, gHopT, blk, 0, stream,
                     g_tr, xi_bf, DIM, (const __bf16*)nullptr, (const __bf16*)nullptr, 0,
                     (const __bf16*)nullptr, (const __bf16*)nullptr, 0,
                     (float*)nullptr, (__bf16*)nullptr, MXI, slots + 1);

  // ---- choose lr, final update ----
  hipLaunchKernelGGL(choose_k, dim3(1), dim3(64), 0, stream, slots, chosen);
  hipLaunchKernelGGL(update_k, dim3((n4 + 255) / 256), blk, 0, stream, x, grad, chosen, out, n4);
}

// Round 5
// 384.933 us; speedup vs baseline: 11.4005x; 1.3488x over previous
//
#include <hip/hip_runtime.h>
#include <math.h>

#define TOK 1568      // B*N = 8*196
#define MPAD 1664     // 13 * 128
#define DIM 768
#define HN 12
#define SEQ 196
#define YD 64
#define MXI 3072
#define BETA_F 0.125f
#define INV_BETA 8.0f
#define LN_EPS_F 1e-5f

// energy-partials layout (doubles): [0,192) attn base | [192,504) hop base
// | [504,1272) attn trials (t*192) | [1272,2520) hop trials (t*312)
#define EP_ATTN0 0
#define EP_HOP0  192
#define EP_ATTNT 504
#define EP_HOPT  1272
#define EP_TOTAL 2520

typedef __bf16 v8bf __attribute__((ext_vector_type(8)));
typedef __bf16 v4bf __attribute__((ext_vector_type(4)));
typedef float  v4f  __attribute__((ext_vector_type(4)));

// ------------------------------------------------------------------
// LayerNorm forward -> bf16 g (+ fp32 xhat/rstd when store_stats)
// ------------------------------------------------------------------
__global__ __launch_bounds__(256) void ln_fwd_k(
    const float* __restrict__ x, const float* __restrict__ gamma,
    const float* __restrict__ delta, __bf16* __restrict__ g,
    float* __restrict__ xhat, float* __restrict__ rstd, int store_stats)
{
  __shared__ float s[4];
  int tok = blockIdx.x;
  int tid = threadIdx.x;
  const float* xp = x + (size_t)tok * DIM;
  float v0 = xp[tid], v1 = xp[tid + 256], v2 = xp[tid + 512];
  float sum = v0 + v1 + v2;
  for (int o = 32; o; o >>= 1) sum += __shfl_xor(sum, o, 64);
  if ((tid & 63) == 0) s[tid >> 6] = sum;
  __syncthreads();
  float mu = (s[0] + s[1] + s[2] + s[3]) * (1.0f / DIM);
  __syncthreads();
  float d0 = v0 - mu, d1 = v1 - mu, d2 = v2 - mu;
  float sq = d0 * d0 + d1 * d1 + d2 * d2;
  for (int o = 32; o; o >>= 1) sq += __shfl_xor(sq, o, 64);
  if ((tid & 63) == 0) s[tid >> 6] = sq;
  __syncthreads();
  float var = (s[0] + s[1] + s[2] + s[3]) * (1.0f / DIM);
  float r = rsqrtf(var + LN_EPS_F);
  float xh0 = d0 * r, xh1 = d1 * r, xh2 = d2 * r;
  size_t base = (size_t)tok * DIM;
  g[base + tid]       = (__bf16)(gamma[tid] * xh0 + delta[tid]);
  g[base + tid + 256] = (__bf16)(gamma[tid + 256] * xh1 + delta[tid + 256]);
  g[base + tid + 512] = (__bf16)(gamma[tid + 512] * xh2 + delta[tid + 512]);
  if (store_stats) {
    xhat[base + tid] = xh0; xhat[base + tid + 256] = xh1; xhat[base + tid + 512] = xh2;
    if (tid == 0) rstd[tok] = r;
  }
}

// ------------------------------------------------------------------
// Fused trial step + LayerNorm: v = x - lr(t)*grad, LN(v) -> g_tr[t]
// grid (TOK, 4)
// ------------------------------------------------------------------
__global__ __launch_bounds__(256) void axpyln_k(
    const float* __restrict__ x, const float* __restrict__ grad,
    const float* __restrict__ gamma, const float* __restrict__ delta,
    __bf16* __restrict__ gt)
{
  __shared__ float s[4];
  int tok = blockIdx.x, t = blockIdx.y;
  float lr = 1.0f / (float)(1 << t);   // t == kk, lr = 0.5^kk
  int tid = threadIdx.x;
  const float* xp = x + (size_t)tok * DIM;
  const float* gp = grad + (size_t)tok * DIM;
  float v0 = xp[tid]       - lr * gp[tid];
  float v1 = xp[tid + 256] - lr * gp[tid + 256];
  float v2 = xp[tid + 512] - lr * gp[tid + 512];
  float sum = v0 + v1 + v2;
  for (int o = 32; o; o >>= 1) sum += __shfl_xor(sum, o, 64);
  if ((tid & 63) == 0) s[tid >> 6] = sum;
  __syncthreads();
  float mu = (s[0] + s[1] + s[2] + s[3]) * (1.0f / DIM);
  __syncthreads();
  float d0 = v0 - mu, d1 = v1 - mu, d2 = v2 - mu;
  float sq = d0 * d0 + d1 * d1 + d2 * d2;
  for (int o = 32; o; o >>= 1) sq += __shfl_xor(sq, o, 64);
  if ((tid & 63) == 0) s[tid >> 6] = sq;
  __syncthreads();
  float var = (s[0] + s[1] + s[2] + s[3]) * (1.0f / DIM);
  float r = rsqrtf(var + LN_EPS_F);
  __bf16* out = gt + ((size_t)t * MPAD + tok) * DIM;
  out[tid]       = (__bf16)(gamma[tid] * (d0 * r) + delta[tid]);
  out[tid + 256] = (__bf16)(gamma[tid + 256] * (d1 * r) + delta[tid + 256]);
  out[tid + 512] = (__bf16)(gamma[tid + 512] * (d2 * r) + delta[tid + 512]);
}

// ------------------------------------------------------------------
// LayerNorm backward (fp32); dG = p0 + p1 + p2 (3-way split-K partials)
// ------------------------------------------------------------------
__global__ __launch_bounds__(256) void ln_bwd_k(
    const float* __restrict__ p0, const float* __restrict__ p1,
    const float* __restrict__ p2, const float* __restrict__ xhat,
    const float* __restrict__ rstd, const float* __restrict__ gamma,
    float* __restrict__ grad)
{
  __shared__ float s[8];
  int tok = blockIdx.x;
  int tid = threadIdx.x;
  size_t base = (size_t)tok * DIM;
  float g0 = p0[base + tid]       + p1[base + tid]       + p2[base + tid];
  float g1 = p0[base + tid + 256] + p1[base + tid + 256] + p2[base + tid + 256];
  float g2 = p0[base + tid + 512] + p1[base + tid + 512] + p2[base + tid + 512];
  float dh0 = g0 * gamma[tid];
  float dh1 = g1 * gamma[tid + 256];
  float dh2 = g2 * gamma[tid + 512];
  float xh0 = xhat[base + tid], xh1 = xhat[base + tid + 256], xh2 = xhat[base + tid + 512];
  float s1 = dh0 + dh1 + dh2;
  float s2 = dh0 * xh0 + dh1 * xh1 + dh2 * xh2;
  for (int o = 32; o; o >>= 1) { s1 += __shfl_xor(s1, o, 64); s2 += __shfl_xor(s2, o, 64); }
  if ((tid & 63) == 0) { s[tid >> 6] = s1; s[4 + (tid >> 6)] = s2; }
  __syncthreads();
  float m1 = (s[0] + s[1] + s[2] + s[3]) * (1.0f / DIM);
  float m2 = (s[4] + s[5] + s[6] + s[7]) * (1.0f / DIM);
  float r = rstd[tok];
  grad[base + tid]       = r * (dh0 - m1 - xh0 * m2);
  grad[base + tid + 256] = r * (dh1 - m1 - xh1 * m2);
  grad[base + tid + 512] = r * (dh2 - m1 - xh2 * m2);
}

// ------------------------------------------------------------------
// Stage one 128x32 bf16 tile into LDS via global_load_lds width=16.
// ------------------------------------------------------------------
__device__ __forceinline__ void stage_tile(
    const __bf16* __restrict__ G, int ldK, int r0, int k0,
    __bf16* S, int tid, int w)
{
#pragma unroll
  for (int r = 0; r < 2; r++) {
    int ch = (r << 8) + tid;
    int row = ch >> 2, col = (ch & 3) << 3;
    __builtin_amdgcn_global_load_lds(
        (__attribute__((address_space(1))) uint32_t*)(G + (size_t)(r0 + row) * ldK + k0 + col),
        (__attribute__((address_space(3))) uint32_t*)(S + (r << 11) + (w << 9)),
        16, 0, 0);
  }
}

// ------------------------------------------------------------------
// MFMA GEMM: C[M,N] = A[M,K] @ B[N,K]^T, bf16 in, fp32 accum.
// 128x128 tile, BK=32, double-buffered LDS, 4 waves (2x2 of 64x64).
// MODE 0: dual fp32 store (z: B0->Cf, B1->(float*)Cb)          [base KQ]
// MODE 1: relu -> bf16 Cb + energy partial -> ep[EP_HOP0+idx]  [base hopfield]
// MODE 4: dual bf16 store (z: B0->(bf16*)Cf, B1->Cb)           [trial KQ]
// MODE 5: relu energy partial -> ep[EP_HOPT + t*312 + idx]     [trial hopfield]
// ------------------------------------------------------------------
template <int MODE>
__global__ __launch_bounds__(256) void gemm_k(
    const __bf16* __restrict__ A0, const __bf16* __restrict__ B0, int K0,
    const __bf16* __restrict__ B1,
    float* __restrict__ Cf, __bf16* __restrict__ Cb, int N,
    double* __restrict__ ep)
{
  __shared__ __align__(16) __bf16 As[2][4096];
  __shared__ __align__(16) __bf16 Bs[2][4096];
  __shared__ double ered[4];
  int tid = threadIdx.x, lane = tid & 63, w = tid >> 6;
  int wm = (w & 1) << 6, wn = (w >> 1) << 6;
  int m0 = blockIdx.y * 128, n0 = blockIdx.x * 128;

  const __bf16* Bsel = B0;
  if ((MODE == 0 || MODE == 4) && blockIdx.z) Bsel = B1;

  v4f zero = {0.f, 0.f, 0.f, 0.f};
  v4f acc[4][4];
#pragma unroll
  for (int i = 0; i < 4; i++)
#pragma unroll
    for (int j = 0; j < 4; j++) acc[i][j] = zero;

  const int nk = K0 >> 5;
  stage_tile(A0, K0, m0, 0, As[0], tid, w);
  stage_tile(Bsel, K0, n0, 0, Bs[0], tid, w);
  for (int kt = 0; kt < nk; kt++) {
    __syncthreads();   // buf[kt] staged + prev compute done
    int nxt = kt + 1;
    if (nxt < nk) {
      stage_tile(A0, K0, m0, nxt << 5, As[nxt & 1], tid, w);
      stage_tile(Bsel, K0, n0, nxt << 5, Bs[nxt & 1], tid, w);
    }
    const __bf16* Ac = As[kt & 1];
    const __bf16* Bc = Bs[kt & 1];
    int mrow = lane & 15, ksel = (lane >> 4) << 3;
    v8bf af[4], bfr[4];
#pragma unroll
    for (int i = 0; i < 4; i++) {
      af[i]  = *(const v8bf*)(Ac + (wm + (i << 4) + mrow) * 32 + ksel);
      bfr[i] = *(const v8bf*)(Bc + (wn + (i << 4) + mrow) * 32 + ksel);
    }
#pragma unroll
    for (int i = 0; i < 4; i++)
#pragma unroll
      for (int j = 0; j < 4; j++)
        acc[i][j] = __builtin_amdgcn_mfma_f32_16x16x32_bf16(af[i], bfr[j], acc[i][j], 0, 0, 0);
  }

  // C/D: col = lane&15, row = quad*4 + reg  (verified layout)
  int quad = lane >> 4, ncol = lane & 15;
  if (MODE == 0) {
    float* Csel = blockIdx.z ? (float*)Cb : Cf;
#pragma unroll
    for (int i = 0; i < 4; i++)
#pragma unroll
      for (int j = 0; j < 4; j++) {
        int row = m0 + wm + (i << 4) + (quad << 2);
        int col = n0 + wn + (j << 4) + ncol;
#pragma unroll
        for (int r = 0; r < 4; r++)
          Csel[(size_t)(row + r) * N + col] = acc[i][j][r];
      }
  } else if (MODE == 4) {
    __bf16* Cout = blockIdx.z ? Cb : (__bf16*)Cf;
#pragma unroll
    for (int i = 0; i < 4; i++)
#pragma unroll
      for (int j = 0; j < 4; j++) {
        int row = m0 + wm + (i << 4) + (quad << 2);
        int col = n0 + wn + (j << 4) + ncol;
#pragma unroll
        for (int r = 0; r < 4; r++)
          Cout[(size_t)(row + r) * N + col] = (__bf16)acc[i][j][r];
      }
  } else {  // MODE 1 / 5: relu energy (+ bf16 store for MODE 1)
    float e = 0.f;
#pragma unroll
    for (int i = 0; i < 4; i++)
#pragma unroll
      for (int j = 0; j < 4; j++) {
        int row = m0 + wm + (i << 4) + (quad << 2);
        int col = n0 + wn + (j << 4) + ncol;
#pragma unroll
        for (int r = 0; r < 4; r++) {
          float v = acc[i][j][r];
          v = v > 0.f ? v : 0.f;
          e += v * v;
          if (MODE == 1) Cb[(size_t)(row + r) * N + col] = (__bf16)v;
        }
      }
    for (int o = 32; o; o >>= 1) e += __shfl_xor(e, o, 64);
    if (lane == 0) ered[w] = (double)e;
    __syncthreads();
    if (tid == 0) {
      double tot = (ered[0] + ered[1]) + (ered[2] + ered[3]);
      int idx;
      if (MODE == 1) idx = EP_HOP0 + blockIdx.y * 24 + blockIdx.x;
      else {
        int tt = blockIdx.y / 13, ry = blockIdx.y - tt * 13;
        idx = EP_HOPT + tt * 312 + ry * 24 + blockIdx.x;
      }
      ep[idx] = -0.5 * tot;
    }
  }
}

// ------------------------------------------------------------------
// Backward fused GEMM, 3-way z-split (all z: 48 K-tiles of 32):
//  z=0: dQg@wqT + dKg@wkT -> C0 ; z=1: rh@xiT[:,0:1536] -> C1
//  z=2: rh@xiT[:,1536:3072] -> C2.  (xiT carries the minus sign.)
// grid (6, 13, 3)
// ------------------------------------------------------------------
__global__ __launch_bounds__(256) void gemm_bwd_k(
    const __bf16* __restrict__ dQg, const __bf16* __restrict__ wqT,
    const __bf16* __restrict__ dKg, const __bf16* __restrict__ wkT,
    const __bf16* __restrict__ rh, const __bf16* __restrict__ xiT,
    float* __restrict__ C0, float* __restrict__ C1, float* __restrict__ C2)
{
  __shared__ __align__(16) __bf16 As[2][4096];
  __shared__ __align__(16) __bf16 Bs[2][4096];
  int tid = threadIdx.x, lane = tid & 63, w = tid >> 6;
  int wm = (w & 1) << 6, wn = (w >> 1) << 6;
  int m0 = blockIdx.y * 128, n0 = blockIdx.x * 128;
  int z = blockIdx.z;

  const __bf16 *Aa, *Ba;
  int lda, ka;
#define TILE_OF(t)                                                        \
  do {                                                                    \
    if (z == 0) {                                                         \
      if ((t) < 24) { Aa = dQg; Ba = wqT; lda = 768; ka = (t) << 5; }     \
      else { Aa = dKg; Ba = wkT; lda = 768; ka = ((t) - 24) << 5; }       \
    } else if (z == 1) { Aa = rh; Ba = xiT; lda = 3072; ka = (t) << 5; }  \
    else { Aa = rh; Ba = xiT; lda = 3072; ka = 1536 + ((t) << 5); }       \
  } while (0)

  v4f zero = {0.f, 0.f, 0.f, 0.f};
  v4f acc[4][4];
#pragma unroll
  for (int i = 0; i < 4; i++)
#pragma unroll
    for (int j = 0; j < 4; j++) acc[i][j] = zero;

  TILE_OF(0);
  stage_tile(Aa, lda, m0, ka, As[0], tid, w);
  stage_tile(Ba, lda, n0, ka, Bs[0], tid, w);
  for (int kt = 0; kt < 48; kt++) {
    __syncthreads();
    int nxt = kt + 1;
    if (nxt < 48) {
      TILE_OF(nxt);
      stage_tile(Aa, lda, m0, ka, As[nxt & 1], tid, w);
      stage_tile(Ba, lda, n0, ka, Bs[nxt & 1], tid, w);
    }
    const __bf16* Ac = As[kt & 1];
    const __bf16* Bc = Bs[kt & 1];
    int mrow = lane & 15, ksel = (lane >> 4) << 3;
    v8bf af[4], bfr[4];
#pragma unroll
    for (int i = 0; i < 4; i++) {
      af[i]  = *(const v8bf*)(Ac + (wm + (i << 4) + mrow) * 32 + ksel);
      bfr[i] = *(const v8bf*)(Bc + (wn + (i << 4) + mrow) * 32 + ksel);
    }
#pragma unroll
    for (int i = 0; i < 4; i++)
#pragma unroll
      for (int j = 0; j < 4; j++)
        acc[i][j] = __builtin_amdgcn_mfma_f32_16x16x32_bf16(af[i], bfr[j], acc[i][j], 0, 0, 0);
  }
#undef TILE_OF

  float* Cz = (z == 0) ? C0 : (z == 1) ? C1 : C2;
  int quad = lane >> 4, ncol = lane & 15;
#pragma unroll
  for (int i = 0; i < 4; i++)
#pragma unroll
    for (int j = 0; j < 4; j++) {
      int row = m0 + wm + (i << 4) + (quad << 2);
      int col = n0 + wn + (j << 4) + ncol;
#pragma unroll
      for (int r = 0; r < 4; r++)
        Cz[(size_t)(row + r) * DIM + col] = acc[i][j][r];
    }
}

// ------------------------------------------------------------------
// Attention fwd (base, fp32 K/Q): grid (96 bh, 2 q-halves). Stores P.
// Energy partial -> ep[EP_ATTN0 + bh*2 + z].
// ------------------------------------------------------------------
__global__ __launch_bounds__(256) void attn_k(
    const float* __restrict__ Kb, const float* __restrict__ Qb,
    float* __restrict__ P, double* __restrict__ ep)
{
  int bh = blockIdx.x;
  int z = blockIdx.y;
  int b = bh / HN, h = bh - b * HN;
  const float* Kp = Kb + (size_t)(b * SEQ) * DIM + h * YD;
  const float* Qp = Qb + (size_t)(b * SEQ) * DIM + h * YD;
  __shared__ float4 Ks4[16 * SEQ + 64];
  __shared__ float4 Qs4[4][2][16];
  __shared__ double er[4];
  int tid = threadIdx.x, lane = tid & 63, w = tid >> 6;
  for (int i = tid; i < SEQ * 16; i += 256) {
    int k = i >> 4, y4 = i & 15;
    Ks4[y4 * SEQ + k] = *(const float4*)(Kp + (size_t)k * DIM + y4 * 4);
  }
  __syncthreads();
  double eacc = 0.0;
  for (int qp = 49 * z + w; qp < 49 * (z + 1); qp += 4) {
    int qa = qp, qb2 = qp + 98;
    if (lane < 32) {
      int which = lane >> 4, yy = lane & 15;
      int q = which ? qb2 : qa;
      Qs4[w][which][yy] = *(const float4*)(Qp + (size_t)q * DIM + yy * 4);
    }
    __builtin_amdgcn_s_waitcnt(0xc07f);  // lgkmcnt(0)
    float da[4] = {0.f, 0.f, 0.f, 0.f}, db[4] = {0.f, 0.f, 0.f, 0.f};
#pragma unroll
    for (int y4 = 0; y4 < 16; y4++) {
      float4 a4 = Qs4[w][0][y4];
      float4 b4 = Qs4[w][1][y4];
#pragma unroll
      for (int j = 0; j < 4; j++) {
        float4 kv = Ks4[y4 * SEQ + lane + 64 * j];
        da[j] = fmaf(kv.x, a4.x, da[j]); da[j] = fmaf(kv.y, a4.y, da[j]);
        da[j] = fmaf(kv.z, a4.z, da[j]); da[j] = fmaf(kv.w, a4.w, da[j]);
        db[j] = fmaf(kv.x, b4.x, db[j]); db[j] = fmaf(kv.y, b4.y, db[j]);
        db[j] = fmaf(kv.z, b4.z, db[j]); db[j] = fmaf(kv.w, b4.w, db[j]);
      }
    }
    float ta[4], tb[4];
#pragma unroll
    for (int j = 0; j < 4; j++) {
      bool valid = (lane + 64 * j) < SEQ;
      ta[j] = valid ? BETA_F * da[j] : -INFINITY;
      tb[j] = valid ? BETA_F * db[j] : -INFINITY;
    }
    float ma = fmaxf(fmaxf(ta[0], ta[1]), fmaxf(ta[2], ta[3]));
    float mb = fmaxf(fmaxf(tb[0], tb[1]), fmaxf(tb[2], tb[3]));
    for (int o = 32; o; o >>= 1) {
      ma = fmaxf(ma, __shfl_xor(ma, o, 64));
      mb = fmaxf(mb, __shfl_xor(mb, o, 64));
    }
    float za = 0.f, zb = 0.f;
#pragma unroll
    for (int j = 0; j < 4; j++) { za += expf(ta[j] - ma); zb += expf(tb[j] - mb); }
    for (int o = 32; o; o >>= 1) { za += __shfl_xor(za, o, 64); zb += __shfl_xor(zb, o, 64); }
    eacc += (double)(ma + logf(za)) + (double)(mb + logf(zb));
    {
      float ia = 1.f / za, ib = 1.f / zb;
      float* Pa  = P + ((size_t)bh * SEQ + qa) * SEQ;
      float* Pb2 = P + ((size_t)bh * SEQ + qb2) * SEQ;
#pragma unroll
      for (int j = 0; j < 4; j++) {
        int k = lane + 64 * j;
        if (k < SEQ) {
          Pa[k]  = expf(ta[j] - ma) * ia;
          Pb2[k] = expf(tb[j] - mb) * ib;
        }
      }
    }
  }
  if (lane == 0) er[w] = eacc;
  __syncthreads();
  if (tid == 0)
    ep[EP_ATTN0 + bh * 2 + z] = -(double)INV_BETA * ((er[0] + er[1]) + (er[2] + er[3]));
}

// ------------------------------------------------------------------
// Attention fwd (trials, bf16 K/Q): grid (96 bh, 2 q-halves, 4 trials).
// Energy partial -> ep[EP_ATTNT + t*192 + bh*2 + z].
// ------------------------------------------------------------------
__global__ __launch_bounds__(256) void attn_bf_k(
    const __bf16* __restrict__ Kt, const __bf16* __restrict__ Qt,
    double* __restrict__ ep)
{
  int bh = blockIdx.x;
  int z = blockIdx.y;
  int t = blockIdx.z;
  int b = bh / HN, h = bh - b * HN;
  const __bf16* Kp = Kt + ((size_t)t * MPAD + b * SEQ) * DIM + h * YD;
  const __bf16* Qp = Qt + ((size_t)t * MPAD + b * SEQ) * DIM + h * YD;
  __shared__ float4 Ks4[16 * SEQ + 64];
  __shared__ float4 Qs4[4][2][16];
  __shared__ double er[4];
  int tid = threadIdx.x, lane = tid & 63, w = tid >> 6;
  for (int i = tid; i < SEQ * 16; i += 256) {
    int k = i >> 4, y4 = i & 15;
    v4bf kv = *(const v4bf*)(Kp + (size_t)k * DIM + y4 * 4);
    Ks4[y4 * SEQ + k] = make_float4((float)kv[0], (float)kv[1], (float)kv[2], (float)kv[3]);
  }
  __syncthreads();
  double eacc = 0.0;
  for (int qp = 49 * z + w; qp < 49 * (z + 1); qp += 4) {
    int qa = qp, qb2 = qp + 98;
    if (lane < 32) {
      int which = lane >> 4, yy = lane & 15;
      int q = which ? qb2 : qa;
      v4bf qv = *(const v4bf*)(Qp + (size_t)q * DIM + yy * 4);
      Qs4[w][which][yy] = make_float4((float)qv[0], (float)qv[1], (float)qv[2], (float)qv[3]);
    }
    __builtin_amdgcn_s_waitcnt(0xc07f);  // lgkmcnt(0)
    float da[4] = {0.f, 0.f, 0.f, 0.f}, db[4] = {0.f, 0.f, 0.f, 0.f};
#pragma unroll
    for (int y4 = 0; y4 < 16; y4++) {
      float4 a4 = Qs4[w][0][y4];
      float4 b4 = Qs4[w][1][y4];
#pragma unroll
      for (int j = 0; j < 4; j++) {
        float4 kv = Ks4[y4 * SEQ + lane + 64 * j];
        da[j] = fmaf(kv.x, a4.x, da[j]); da[j] = fmaf(kv.y, a4.y, da[j]);
        da[j] = fmaf(kv.z, a4.z, da[j]); da[j] = fmaf(kv.w, a4.w, da[j]);
        db[j] = fmaf(kv.x, b4.x, db[j]); db[j] = fmaf(kv.y, b4.y, db[j]);
        db[j] = fmaf(kv.z, b4.z, db[j]); db[j] = fmaf(kv.w, b4.w, db[j]);
      }
    }
    float ta[4], tb[4];
#pragma unroll
    for (int j = 0; j < 4; j++) {
      bool valid = (lane + 64 * j) < SEQ;
      ta[j] = valid ? BETA_F * da[j] : -INFINITY;
      tb[j] = valid ? BETA_F * db[j] : -INFINITY;
    }
    float ma = fmaxf(fmaxf(ta[0], ta[1]), fmaxf(ta[2], ta[3]));
    float mb = fmaxf(fmaxf(tb[0], tb[1]), fmaxf(tb[2], tb[3]));
    for (int o = 32; o; o >>= 1) {
      ma = fmaxf(ma, __shfl_xor(ma, o, 64));
      mb = fmaxf(mb, __shfl_xor(mb, o, 64));
    }
    float za = 0.f, zb = 0.f;
#pragma unroll
    for (int j = 0; j < 4; j++) { za += expf(ta[j] - ma); zb += expf(tb[j] - mb); }
    for (int o = 32; o; o >>= 1) { za += __shfl_xor(za, o, 64); zb += __shfl_xor(zb, o, 64); }
    eacc += (double)(ma + logf(za)) + (double)(mb + logf(zb));
  }
  if (lane == 0) er[w] = eacc;
  __syncthreads();
  if (tid == 0)
    ep[EP_ATTNT + t * 192 + bh * 2 + z] =
        -(double)INV_BETA * ((er[0] + er[1]) + (er[2] + er[3]));
}

// ------------------------------------------------------------------
// Attention bwd (fp32 compute, bf16 out). grid (96 bh, 4 mtiles, 2).
// ------------------------------------------------------------------
__global__ __launch_bounds__(256) void attn_bwd_k(
    const float* __restrict__ Kb, const float* __restrict__ Qb,
    const float* __restrict__ P, __bf16* __restrict__ dQg, __bf16* __restrict__ dKg)
{
  int bh = blockIdx.x;
  int b = bh / HN, h = bh - b * HN;
  int m0 = blockIdx.y * 64;
  int is_dk = blockIdx.z;
  const float* Bsrc = (is_dk ? Qb : Kb) + (size_t)(b * SEQ) * DIM + h * YD;
  const float* Pb = P + (size_t)bh * SEQ * SEQ;
  __bf16* Dst = (is_dk ? dKg : dQg) + (size_t)(b * SEQ) * DIM + h * YD;
  __shared__ float As[16][68];
  __shared__ float Bs[16][68];
  int tid = threadIdx.x;
  int tx = tid & 15, ty = tid >> 4;
  float acc[4][4] = {};
  for (int k0 = 0; k0 < SEQ; k0 += 16) {
    if (!is_dk) {
      int mm = tid >> 2, kc = (tid & 3) << 2;
      float4 v = make_float4(0.f, 0.f, 0.f, 0.f);
      if (m0 + mm < SEQ && k0 + kc < SEQ)
        v = *(const float4*)(Pb + (size_t)(m0 + mm) * SEQ + k0 + kc);
      As[kc + 0][mm] = v.x; As[kc + 1][mm] = v.y; As[kc + 2][mm] = v.z; As[kc + 3][mm] = v.w;
    } else {
      int kk = tid >> 4, mc = (tid & 15) << 2;
      float4 v = make_float4(0.f, 0.f, 0.f, 0.f);
      if (k0 + kk < SEQ && m0 + mc < SEQ)
        v = *(const float4*)(Pb + (size_t)(k0 + kk) * SEQ + m0 + mc);
      *(float4*)&As[kk][mc] = v;
    }
    {
      int kk = tid >> 4, yc = (tid & 15) << 2;
      float4 v = make_float4(0.f, 0.f, 0.f, 0.f);
      if (k0 + kk < SEQ)
        v = *(const float4*)(Bsrc + (size_t)(k0 + kk) * DIM + yc);
      *(float4*)&Bs[kk][yc] = v;
    }
    __syncthreads();
#pragma unroll
    for (int kk = 0; kk < 16; kk++) {
      float a[4], bb[4];
      *(float4*)a  = *(const float4*)&As[kk][ty * 4];
      *(float4*)bb = *(const float4*)&Bs[kk][tx * 4];
#pragma unroll
      for (int i = 0; i < 4; i++)
#pragma unroll
        for (int j = 0; j < 4; j++)
          acc[i][j] = fmaf(a[i], bb[j], acc[i][j]);
    }
    __syncthreads();
  }
#pragma unroll
  for (int i = 0; i < 4; i++) {
    int m = m0 + ty * 4 + i;
    if (m < SEQ) {
      v4bf o = { (__bf16)(-acc[i][0]), (__bf16)(-acc[i][1]),
                 (__bf16)(-acc[i][2]), (__bf16)(-acc[i][3]) };
      *(v4bf*)(Dst + (size_t)m * DIM + tx * 4) = o;
    }
  }
}

// ------------------------------------------------------------------
// Reduce energy partials -> slots[0..4]. grid(5).
// ------------------------------------------------------------------
__global__ __launch_bounds__(256) void reduce_k(
    const double* __restrict__ ep, double* __restrict__ slots)
{
  int s = blockIdx.x;
  int tid = threadIdx.x;
  double acc = 0.0;
  if (s == 0) {
    for (int i = tid; i < 504; i += 256) acc += ep[i];          // attn0 + hop0
  } else {
    const double* c = ep + EP_ATTNT + (s - 1) * 192;
    for (int i = tid; i < 192; i += 256) acc += c[i];
    const double* d = ep + EP_HOPT + (s - 1) * 312;
    for (int i = tid; i < 312; i += 256) acc += d[i];
  }
  for (int o = 32; o; o >>= 1) acc += __shfl_xor(acc, o, 64);
  __shared__ double sm[4];
  if ((tid & 63) == 0) sm[tid >> 6] = acc;
  __syncthreads();
  if (tid == 0) slots[s] = (sm[0] + sm[1]) + (sm[2] + sm[3]);
}

// ------------------------------------------------------------------
// Setup kernels
// ------------------------------------------------------------------
__global__ __launch_bounds__(256) void init_k(
    __bf16* __restrict__ g, __bf16* __restrict__ gt,
    __bf16* __restrict__ dq, __bf16* __restrict__ dk)
{
  int i = blockIdx.x * 256 + threadIdx.x;
  const int PADN = (MPAD - TOK) * DIM;   // 73728
  if (i < PADN) {
    size_t o = (size_t)TOK * DIM + i;
    g[o] = (__bf16)0.f; dq[o] = (__bf16)0.f; dk[o] = (__bf16)0.f;
#pragma unroll
    for (int t = 0; t < 4; t++)
      gt[(size_t)t * MPAD * DIM + o] = (__bf16)0.f;
  }
}

__global__ __launch_bounds__(256) void cvt_k(
    const float* __restrict__ src, __bf16* __restrict__ dst, int n4)
{
  int i = blockIdx.x * 256 + threadIdx.x;
  if (i < n4) {
    float4 v = ((const float4*)src)[i];
    v4bf o = { (__bf16)v.x, (__bf16)v.y, (__bf16)v.z, (__bf16)v.w };
    *(v4bf*)(dst + 4 * (size_t)i) = o;
  }
}

// dst[c*R + r] = scale * src[r*C + c]; src [R,C]. R,C multiples of 32.
__global__ __launch_bounds__(256) void cvtT_k(
    const float* __restrict__ src, __bf16* __restrict__ dst,
    int R, int C, float scale)
{
  __shared__ float t[32][33];
  int r0 = blockIdx.y * 32, c0 = blockIdx.x * 32;
  int tx = threadIdx.x & 31, ty = threadIdx.x >> 5;
  for (int rr = ty; rr < 32; rr += 8)
    t[rr][tx] = src[(size_t)(r0 + rr) * C + c0 + tx];
  __syncthreads();
  for (int rr = ty; rr < 32; rr += 8)
    dst[(size_t)(c0 + rr) * R + r0 + tx] = (__bf16)(scale * t[tx][rr]);
}

__global__ void choose_k(const double* __restrict__ e, float* __restrict__ chosen) {
  if (threadIdx.x == 0) {
    double e0 = e[0];
    float c = 0.0625f;                 // lr0 * gamma^4
    if (e[4] < e0) c = 0.125f;         // kk=3
    if (e[3] < e0) c = 0.25f;          // kk=2
    if (e[2] < e0) c = 0.5f;           // kk=1
    if (e[1] < e0) c = 1.0f;           // kk=0 (highest priority)
    *chosen = c;
  }
}

__global__ __launch_bounds__(256) void update_k(
    const float* __restrict__ x, const float* __restrict__ g,
    const float* __restrict__ chosen, float* __restrict__ out, int n4)
{
  int i = blockIdx.x * 256 + threadIdx.x;
  float lr = *chosen;
  if (i < n4) {
    const float4 xv = ((const float4*)x)[i];
    const float4 gv = ((const float4*)g)[i];
    float4 o;
    o.x = xv.x - lr * gv.x; o.y = xv.y - lr * gv.y;
    o.z = xv.z - lr * gv.z; o.w = xv.w - lr * gv.w;
    ((float4*)out)[i] = o;
  }
}

// ------------------------------------------------------------------
extern "C" void kernel_launch(void* const* d_in, const int* in_sizes, int n_in,
                              void* d_out, int out_size, void* d_ws, size_t ws_size,
                              hipStream_t stream)
{
  const float* x     = (const float*)d_in[0];
  const float* gamma = (const float*)d_in[1];
  const float* delta = (const float*)d_in[2];
  const float* wk    = (const float*)d_in[3];  // [768(hy), 768(d)]
  const float* wq    = (const float*)d_in[4];
  const float* xi    = (const float*)d_in[5];  // [3072, 768]
  float* out = (float*)d_out;

  const size_t NE = (size_t)TOK * DIM;
  const size_t NP = (size_t)MPAD * DIM;

  double* slots = (double*)d_ws;                 // 16 doubles
  double* eparts = slots + 16;                   // 2520 doubles
  float* fp = (float*)(eparts + EP_TOTAL);
  float* xhat = fp;  fp += NE;
  float* Kb   = fp;  fp += NP;
  float* Qb   = fp;  fp += NP;
  float* P    = fp;  fp += (size_t)96 * SEQ * SEQ;
  float* grad = fp;  fp += NE;
  float* rstd = fp;  fp += TOK;
  float* chosen = fp; fp += 16;
  __bf16* bp = (__bf16*)(((uintptr_t)fp + 15) & ~(uintptr_t)15);
  __bf16* g_bf   = bp;  bp += NP;
  __bf16* g_tr   = bp;  bp += 4 * NP;
  __bf16* dQg_bf = bp;  bp += NP;
  __bf16* dKg_bf = bp;  bp += NP;
  __bf16* rh_bf  = bp;  bp += (size_t)MPAD * MXI;
  __bf16* wk_bf  = bp;  bp += (size_t)DIM * DIM;
  __bf16* wq_bf  = bp;  bp += (size_t)DIM * DIM;
  __bf16* wkT_bf = bp;  bp += (size_t)DIM * DIM;
  __bf16* wqT_bf = bp;  bp += (size_t)DIM * DIM;
  __bf16* xi_bf  = bp;  bp += (size_t)MXI * DIM;
  __bf16* xiT_bf = bp;  bp += (size_t)DIM * MXI;
  __bf16* KbT_bf = bp;  bp += 4 * NP;
  __bf16* QbT_bf = bp;  bp += 4 * NP;
  // dG split-K partials alias KbT/QbT (consumed by ln_bwd BEFORE gemm<4>
  // writes KbT/QbT): 3*NP floats = 12*NP bytes <= 16*NP bytes available.
  float* dGp0 = (float*)KbT_bf;
  float* dGp1 = dGp0 + NP;
  float* dGp2 = dGp1 + NP;

  const int n4 = (int)(NE / 4);
  dim3 blk(256);
  dim3 gKQ(DIM / 128, MPAD / 128, 2);       // (6,13,2)
  dim3 gHop(MXI / 128, MPAD / 128);         // (24,13)
  dim3 gBwd(DIM / 128, MPAD / 128, 3);      // (6,13,3)
  dim3 gKQt(DIM / 128, 4 * MPAD / 128, 2);  // (6,52,2)
  dim3 gHopT(MXI / 128, 4 * MPAD / 128);    // (24,52)

  // ---- setup ----
  hipLaunchKernelGGL(init_k, dim3(((MPAD - TOK) * DIM + 255) / 256), blk, 0, stream,
                     g_bf, g_tr, dQg_bf, dKg_bf);
  hipLaunchKernelGGL(cvt_k, dim3((DIM * DIM / 4 + 255) / 256), blk, 0, stream, wk, wk_bf, DIM * DIM / 4);
  hipLaunchKernelGGL(cvt_k, dim3((DIM * DIM / 4 + 255) / 256), blk, 0, stream, wq, wq_bf, DIM * DIM / 4);
  hipLaunchKernelGGL(cvt_k, dim3((MXI * DIM / 4 + 255) / 256), blk, 0, stream, xi, xi_bf, MXI * DIM / 4);
  hipLaunchKernelGGL(cvtT_k, dim3(DIM / 32, DIM / 32), blk, 0, stream, wk, wkT_bf, DIM, DIM, 1.f);
  hipLaunchKernelGGL(cvtT_k, dim3(DIM / 32, DIM / 32), blk, 0, stream, wq, wqT_bf, DIM, DIM, 1.f);
  hipLaunchKernelGGL(cvtT_k, dim3(DIM / 32, MXI / 32), blk, 0, stream, xi, xiT_bf, MXI, DIM, -1.f);

  // ---- base forward ----
  hipLaunchKernelGGL(ln_fwd_k, dim3(TOK), blk, 0, stream, x, gamma, delta, g_bf, xhat, rstd, 1);
  hipLaunchKernelGGL(gemm_k<0>, gKQ, blk, 0, stream,
                     g_bf, wk_bf, DIM, wq_bf, Kb, (__bf16*)Qb, DIM, (double*)nullptr);
  hipLaunchKernelGGL(attn_k, dim3(8 * HN, 2), blk, 0, stream, Kb, Qb, P, eparts);
  hipLaunchKernelGGL(gemm_k<1>, gHop, blk, 0, stream,
                     g_bf, xi_bf, DIM, (const __bf16*)nullptr,
                     (float*)nullptr, rh_bf, MXI, eparts);
  // ---- backward ----
  hipLaunchKernelGGL(attn_bwd_k, dim3(8 * HN, 4, 2), blk, 0, stream, Kb, Qb, P, dQg_bf, dKg_bf);
  hipLaunchKernelGGL(gemm_bwd_k, gBwd, blk, 0, stream,
                     dQg_bf, wqT_bf, dKg_bf, wkT_bf, rh_bf, xiT_bf, dGp0, dGp1, dGp2);
  hipLaunchKernelGGL(ln_bwd_k, dim3(TOK), blk, 0, stream,
                     dGp0, dGp1, dGp2, xhat, rstd, gamma, grad);

  // ---- Armijo trials (all 4 batched) ----
  hipLaunchKernelGGL(axpyln_k, dim3(TOK, 4), blk, 0, stream, x, grad, gamma, delta, g_tr);
  hipLaunchKernelGGL(gemm_k<4>, gKQt, blk, 0, stream,
                     g_tr, wk_bf, DIM, wq_bf, (float*)KbT_bf, QbT_bf, DIM, (double*)nullptr);
  hipLaunchKernelGGL(attn_bf_k, dim3(8 * HN, 2, 4), blk, 0, stream, KbT_bf, QbT_bf, eparts);
  hipLaunchKernelGGL(gemm_k<5>, gHopT, blk, 0, stream,
                     g_tr, xi_bf, DIM, (const __bf16*)nullptr,
                     (float*)nullptr, (__bf16*)nullptr, MXI, eparts);

  // ---- reduce energies, choose lr, final update ----
  hipLaunchKernelGGL(reduce_k, dim3(5), blk, 0, stream, eparts, slots);
  hipLaunchKernelGGL(choose_k, dim3(1), dim3(64), 0, stream, slots, chosen);
  hipLaunchKernelGGL(update_k, dim3((n4 + 255) / 256), blk, 0, stream, x, grad, chosen, out, n4);
}

// Round 6
// 334.749 us; speedup vs baseline: 13.1097x; 1.1499x over previous
//
#include <hip/hip_runtime.h>
#include <math.h>

#define TOK 1568      // B*N = 8*196
#define MPAD 1664     // 13 * 128
#define DIM 768
#define HN 12
#define SEQ 196
#define YD 64
#define MXI 3072
#define BETA_F 0.125f
#define INV_BETA 8.0f
#define LN_EPS_F 1e-5f

// P/PT padded geometry: rows 208 (13*16), cols 224 (7*32)
#define PROWS 208
#define PCOLS 224
#define PAREA (PROWS * PCOLS)

// energy partials (doubles): attn ver*96+bh, ver 0..4 -> [0,480)
// hop base [480,792) ; hop trial t*312 -> [792,2040)
#define EP_HOPB 480
#define EP_HOPT 792
#define EP_TOTAL 2040

typedef __bf16 v8bf __attribute__((ext_vector_type(8)));
typedef __bf16 v4bf __attribute__((ext_vector_type(4)));
typedef float  v4f  __attribute__((ext_vector_type(4)));

__device__ __forceinline__ v8bf zero8() {
  v8bf v = { (__bf16)0.f, (__bf16)0.f, (__bf16)0.f, (__bf16)0.f,
             (__bf16)0.f, (__bf16)0.f, (__bf16)0.f, (__bf16)0.f };
  return v;
}

// ------------------------------------------------------------------
// LayerNorm forward -> bf16 g + fp32 xhat/rstd
// ------------------------------------------------------------------
__global__ __launch_bounds__(256) void ln_fwd_k(
    const float* __restrict__ x, const float* __restrict__ gamma,
    const float* __restrict__ delta, __bf16* __restrict__ g,
    float* __restrict__ xhat, float* __restrict__ rstd)
{
  __shared__ float s[4];
  int tok = blockIdx.x;
  int tid = threadIdx.x;
  const float* xp = x + (size_t)tok * DIM;
  float v0 = xp[tid], v1 = xp[tid + 256], v2 = xp[tid + 512];
  float sum = v0 + v1 + v2;
  for (int o = 32; o; o >>= 1) sum += __shfl_xor(sum, o, 64);
  if ((tid & 63) == 0) s[tid >> 6] = sum;
  __syncthreads();
  float mu = (s[0] + s[1] + s[2] + s[3]) * (1.0f / DIM);
  __syncthreads();
  float d0 = v0 - mu, d1 = v1 - mu, d2 = v2 - mu;
  float sq = d0 * d0 + d1 * d1 + d2 * d2;
  for (int o = 32; o; o >>= 1) sq += __shfl_xor(sq, o, 64);
  if ((tid & 63) == 0) s[tid >> 6] = sq;
  __syncthreads();
  float var = (s[0] + s[1] + s[2] + s[3]) * (1.0f / DIM);
  float r = rsqrtf(var + LN_EPS_F);
  float xh0 = d0 * r, xh1 = d1 * r, xh2 = d2 * r;
  size_t base = (size_t)tok * DIM;
  g[base + tid]       = (__bf16)(gamma[tid] * xh0 + delta[tid]);
  g[base + tid + 256] = (__bf16)(gamma[tid + 256] * xh1 + delta[tid + 256]);
  g[base + tid + 512] = (__bf16)(gamma[tid + 512] * xh2 + delta[tid + 512]);
  xhat[base + tid] = xh0; xhat[base + tid + 256] = xh1; xhat[base + tid + 512] = xh2;
  if (tid == 0) rstd[tok] = r;
}

// ------------------------------------------------------------------
// Fused trial step + LayerNorm. grid (TOK, 4)
// ------------------------------------------------------------------
__global__ __launch_bounds__(256) void axpyln_k(
    const float* __restrict__ x, const float* __restrict__ grad,
    const float* __restrict__ gamma, const float* __restrict__ delta,
    __bf16* __restrict__ gt)
{
  __shared__ float s[4];
  int tok = blockIdx.x, t = blockIdx.y;
  float lr = 1.0f / (float)(1 << t);   // lr = 0.5^t
  int tid = threadIdx.x;
  const float* xp = x + (size_t)tok * DIM;
  const float* gp = grad + (size_t)tok * DIM;
  float v0 = xp[tid]       - lr * gp[tid];
  float v1 = xp[tid + 256] - lr * gp[tid + 256];
  float v2 = xp[tid + 512] - lr * gp[tid + 512];
  float sum = v0 + v1 + v2;
  for (int o = 32; o; o >>= 1) sum += __shfl_xor(sum, o, 64);
  if ((tid & 63) == 0) s[tid >> 6] = sum;
  __syncthreads();
  float mu = (s[0] + s[1] + s[2] + s[3]) * (1.0f / DIM);
  __syncthreads();
  float d0 = v0 - mu, d1 = v1 - mu, d2 = v2 - mu;
  float sq = d0 * d0 + d1 * d1 + d2 * d2;
  for (int o = 32; o; o >>= 1) sq += __shfl_xor(sq, o, 64);
  if ((tid & 63) == 0) s[tid >> 6] = sq;
  __syncthreads();
  float var = (s[0] + s[1] + s[2] + s[3]) * (1.0f / DIM);
  float r = rsqrtf(var + LN_EPS_F);
  __bf16* out = gt + ((size_t)t * MPAD + tok) * DIM;
  out[tid]       = (__bf16)(gamma[tid] * (d0 * r) + delta[tid]);
  out[tid + 256] = (__bf16)(gamma[tid + 256] * (d1 * r) + delta[tid + 256]);
  out[tid + 512] = (__bf16)(gamma[tid + 512] * (d2 * r) + delta[tid + 512]);
}

// ------------------------------------------------------------------
// LayerNorm backward; dG = p0 + p1 + p2 (split-K partials)
// ------------------------------------------------------------------
__global__ __launch_bounds__(256) void ln_bwd_k(
    const float* __restrict__ p0, const float* __restrict__ p1,
    const float* __restrict__ p2, const float* __restrict__ xhat,
    const float* __restrict__ rstd, const float* __restrict__ gamma,
    float* __restrict__ grad)
{
  __shared__ float s[8];
  int tok = blockIdx.x;
  int tid = threadIdx.x;
  size_t base = (size_t)tok * DIM;
  float g0 = p0[base + tid]       + p1[base + tid]       + p2[base + tid];
  float g1 = p0[base + tid + 256] + p1[base + tid + 256] + p2[base + tid + 256];
  float g2 = p0[base + tid + 512] + p1[base + tid + 512] + p2[base + tid + 512];
  float dh0 = g0 * gamma[tid];
  float dh1 = g1 * gamma[tid + 256];
  float dh2 = g2 * gamma[tid + 512];
  float xh0 = xhat[base + tid], xh1 = xhat[base + tid + 256], xh2 = xhat[base + tid + 512];
  float s1 = dh0 + dh1 + dh2;
  float s2 = dh0 * xh0 + dh1 * xh1 + dh2 * xh2;
  for (int o = 32; o; o >>= 1) { s1 += __shfl_xor(s1, o, 64); s2 += __shfl_xor(s2, o, 64); }
  if ((tid & 63) == 0) { s[tid >> 6] = s1; s[4 + (tid >> 6)] = s2; }
  __syncthreads();
  float m1 = (s[0] + s[1] + s[2] + s[3]) * (1.0f / DIM);
  float m2 = (s[4] + s[5] + s[6] + s[7]) * (1.0f / DIM);
  float r = rstd[tok];
  grad[base + tid]       = r * (dh0 - m1 - xh0 * m2);
  grad[base + tid + 256] = r * (dh1 - m1 - xh1 * m2);
  grad[base + tid + 512] = r * (dh2 - m1 - xh2 * m2);
}

// ------------------------------------------------------------------
// Stage one 128x32 bf16 tile into LDS via global_load_lds width=16.
// ------------------------------------------------------------------
__device__ __forceinline__ void stage_tile(
    const __bf16* __restrict__ G, int ldK, int r0, int k0,
    __bf16* S, int tid, int w)
{
#pragma unroll
  for (int r = 0; r < 2; r++) {
    int ch = (r << 8) + tid;
    int row = ch >> 2, col = (ch & 3) << 3;
    __builtin_amdgcn_global_load_lds(
        (__attribute__((address_space(1))) uint32_t*)(G + (size_t)(r0 + row) * ldK + k0 + col),
        (__attribute__((address_space(3))) uint32_t*)(S + (r << 11) + (w << 9)),
        16, 0, 0);
  }
}

// ------------------------------------------------------------------
// MFMA GEMM: C[M,N] = A[M,K] @ B[N,K]^T, bf16 in, fp32 accum.
// 128x128 tile, BK=32, double-buffered LDS, 4 waves (2x2 of 64x64).
// MODE 1: relu -> bf16 Cb + energy partial ep[EP_HOPB + idx]  [base hop]
// MODE 4: dual bf16 store (z: B0->(bf16*)Cf, B1->Cb)          [KQ]
// MODE 5: relu energy partial ep[EP_HOPT + t*312 + idx]       [trial hop]
// ------------------------------------------------------------------
template <int MODE>
__global__ __launch_bounds__(256) void gemm_k(
    const __bf16* __restrict__ A0, const __bf16* __restrict__ B0, int K0,
    const __bf16* __restrict__ B1,
    float* __restrict__ Cf, __bf16* __restrict__ Cb, int N,
    double* __restrict__ ep)
{
  __shared__ __align__(16) __bf16 As[2][4096];
  __shared__ __align__(16) __bf16 Bs[2][4096];
  __shared__ double ered[4];
  int tid = threadIdx.x, lane = tid & 63, w = tid >> 6;
  int wm = (w & 1) << 6, wn = (w >> 1) << 6;
  int m0 = blockIdx.y * 128, n0 = blockIdx.x * 128;

  const __bf16* Bsel = B0;
  if (MODE == 4 && blockIdx.z) Bsel = B1;

  v4f zero = {0.f, 0.f, 0.f, 0.f};
  v4f acc[4][4];
#pragma unroll
  for (int i = 0; i < 4; i++)
#pragma unroll
    for (int j = 0; j < 4; j++) acc[i][j] = zero;

  const int nk = K0 >> 5;
  stage_tile(A0, K0, m0, 0, As[0], tid, w);
  stage_tile(Bsel, K0, n0, 0, Bs[0], tid, w);
  for (int kt = 0; kt < nk; kt++) {
    __syncthreads();
    int nxt = kt + 1;
    if (nxt < nk) {
      stage_tile(A0, K0, m0, nxt << 5, As[nxt & 1], tid, w);
      stage_tile(Bsel, K0, n0, nxt << 5, Bs[nxt & 1], tid, w);
    }
    const __bf16* Ac = As[kt & 1];
    const __bf16* Bc = Bs[kt & 1];
    int mrow = lane & 15, ksel = (lane >> 4) << 3;
    v8bf af[4], bfr[4];
#pragma unroll
    for (int i = 0; i < 4; i++) {
      af[i]  = *(const v8bf*)(Ac + (wm + (i << 4) + mrow) * 32 + ksel);
      bfr[i] = *(const v8bf*)(Bc + (wn + (i << 4) + mrow) * 32 + ksel);
    }
#pragma unroll
    for (int i = 0; i < 4; i++)
#pragma unroll
      for (int j = 0; j < 4; j++)
        acc[i][j] = __builtin_amdgcn_mfma_f32_16x16x32_bf16(af[i], bfr[j], acc[i][j], 0, 0, 0);
  }

  // C/D: col = lane&15, row = quad*4 + reg
  int quad = lane >> 4, ncol = lane & 15;
  if (MODE == 4) {
    __bf16* Cout = blockIdx.z ? Cb : (__bf16*)Cf;
#pragma unroll
    for (int i = 0; i < 4; i++)
#pragma unroll
      for (int j = 0; j < 4; j++) {
        int row = m0 + wm + (i << 4) + (quad << 2);
        int col = n0 + wn + (j << 4) + ncol;
#pragma unroll
        for (int r = 0; r < 4; r++)
          Cout[(size_t)(row + r) * N + col] = (__bf16)acc[i][j][r];
      }
  } else {  // MODE 1 / 5
    float e = 0.f;
#pragma unroll
    for (int i = 0; i < 4; i++)
#pragma unroll
      for (int j = 0; j < 4; j++) {
        int row = m0 + wm + (i << 4) + (quad << 2);
        int col = n0 + wn + (j << 4) + ncol;
#pragma unroll
        for (int r = 0; r < 4; r++) {
          float v = acc[i][j][r];
          v = v > 0.f ? v : 0.f;
          e += v * v;
          if (MODE == 1) Cb[(size_t)(row + r) * N + col] = (__bf16)v;
        }
      }
    for (int o = 32; o; o >>= 1) e += __shfl_xor(e, o, 64);
    if (lane == 0) ered[w] = (double)e;
    __syncthreads();
    if (tid == 0) {
      double tot = (ered[0] + ered[1]) + (ered[2] + ered[3]);
      int idx;
      if (MODE == 1) idx = EP_HOPB + blockIdx.y * 24 + blockIdx.x;
      else {
        int tt = blockIdx.y / 13, ry = blockIdx.y - tt * 13;
        idx = EP_HOPT + tt * 312 + ry * 24 + blockIdx.x;
      }
      ep[idx] = -0.5 * tot;
    }
  }
}

// ------------------------------------------------------------------
// Backward fused GEMM, 3-way z-split. grid (6, 13, 3)
// ------------------------------------------------------------------
__global__ __launch_bounds__(256) void gemm_bwd_k(
    const __bf16* __restrict__ dQg, const __bf16* __restrict__ wqT,
    const __bf16* __restrict__ dKg, const __bf16* __restrict__ wkT,
    const __bf16* __restrict__ rh, const __bf16* __restrict__ xiT,
    float* __restrict__ C0, float* __restrict__ C1, float* __restrict__ C2)
{
  __shared__ __align__(16) __bf16 As[2][4096];
  __shared__ __align__(16) __bf16 Bs[2][4096];
  int tid = threadIdx.x, lane = tid & 63, w = tid >> 6;
  int wm = (w & 1) << 6, wn = (w >> 1) << 6;
  int m0 = blockIdx.y * 128, n0 = blockIdx.x * 128;
  int z = blockIdx.z;

  const __bf16 *Aa, *Ba;
  int lda, ka;
#define TILE_OF(t)                                                        \
  do {                                                                    \
    if (z == 0) {                                                         \
      if ((t) < 24) { Aa = dQg; Ba = wqT; lda = 768; ka = (t) << 5; }     \
      else { Aa = dKg; Ba = wkT; lda = 768; ka = ((t) - 24) << 5; }       \
    } else if (z == 1) { Aa = rh; Ba = xiT; lda = 3072; ka = (t) << 5; }  \
    else { Aa = rh; Ba = xiT; lda = 3072; ka = 1536 + ((t) << 5); }       \
  } while (0)

  v4f zero = {0.f, 0.f, 0.f, 0.f};
  v4f acc[4][4];
#pragma unroll
  for (int i = 0; i < 4; i++)
#pragma unroll
    for (int j = 0; j < 4; j++) acc[i][j] = zero;

  TILE_OF(0);
  stage_tile(Aa, lda, m0, ka, As[0], tid, w);
  stage_tile(Ba, lda, n0, ka, Bs[0], tid, w);
  for (int kt = 0; kt < 48; kt++) {
    __syncthreads();
    int nxt = kt + 1;
    if (nxt < 48) {
      TILE_OF(nxt);
      stage_tile(Aa, lda, m0, ka, As[nxt & 1], tid, w);
      stage_tile(Ba, lda, n0, ka, Bs[nxt & 1], tid, w);
    }
    const __bf16* Ac = As[kt & 1];
    const __bf16* Bc = Bs[kt & 1];
    int mrow = lane & 15, ksel = (lane >> 4) << 3;
    v8bf af[4], bfr[4];
#pragma unroll
    for (int i = 0; i < 4; i++) {
      af[i]  = *(const v8bf*)(Ac + (wm + (i << 4) + mrow) * 32 + ksel);
      bfr[i] = *(const v8bf*)(Bc + (wn + (i << 4) + mrow) * 32 + ksel);
    }
#pragma unroll
    for (int i = 0; i < 4; i++)
#pragma unroll
      for (int j = 0; j < 4; j++)
        acc[i][j] = __builtin_amdgcn_mfma_f32_16x16x32_bf16(af[i], bfr[j], acc[i][j], 0, 0, 0);
  }
#undef TILE_OF

  float* Cz = (z == 0) ? C0 : (z == 1) ? C1 : C2;
  int quad = lane >> 4, ncol = lane & 15;
#pragma unroll
  for (int i = 0; i < 4; i++)
#pragma unroll
    for (int j = 0; j < 4; j++) {
      int row = m0 + wm + (i << 4) + (quad << 2);
      int col = n0 + wn + (j << 4) + ncol;
#pragma unroll
      for (int r = 0; r < 4; r++)
        Cz[(size_t)(row + r) * DIM + col] = acc[i][j][r];
    }
}

// ------------------------------------------------------------------
// MFMA attention forward. STOREP=1: base (grid 96), stores P + energy.
// STOREP=0: trials (grid 96 x 4), energy only.
// S[q,k] = beta * sum_y Q[q,y] K[k,y]; LSE rowwise; E = -(1/beta) sum LSE.
// K,Q staged in LDS rows stride 72 (2-way bank pattern, free).
// ------------------------------------------------------------------
template <int STOREP>
__global__ __launch_bounds__(256) void attn_mfma_k(
    const __bf16* __restrict__ Ksrc, const __bf16* __restrict__ Qsrc,
    __bf16* __restrict__ P, double* __restrict__ ep)
{
  __shared__ __align__(16) __bf16 Ks[PROWS * 72];
  __shared__ __align__(16) __bf16 Qs[PROWS * 72];
  __shared__ double er[4];
  int bh = blockIdx.x;
  int ver = STOREP ? 0 : (blockIdx.y + 1);
  int b = bh / HN, h = bh - b * HN;
  size_t voff = STOREP ? 0 : (size_t)blockIdx.y * MPAD * DIM;
  const __bf16* Kp = Ksrc + voff + (size_t)(b * SEQ) * DIM + h * YD;
  const __bf16* Qp = Qsrc + voff + (size_t)(b * SEQ) * DIM + h * YD;
  int tid = threadIdx.x;

  for (int i = tid; i < PROWS * 8; i += 256) {
    int row = i >> 3, c = i & 7;
    v8bf kv = zero8(), qv = zero8();
    if (row < SEQ) {
      kv = *(const v8bf*)(Kp + (size_t)row * DIM + c * 8);
      qv = *(const v8bf*)(Qp + (size_t)row * DIM + c * 8);
    }
    *(v8bf*)(Ks + row * 72 + c * 8) = kv;
    *(v8bf*)(Qs + row * 72 + c * 8) = qv;
  }
  __syncthreads();

  int lane = tid & 63, w = tid >> 6;
  int mrow = lane & 15, quad = lane >> 4, ncol = mrow;
  int ksel = quad * 8;
  v4f zero = {0.f, 0.f, 0.f, 0.f};
  double eacc = 0.0;

  for (int mt = w; mt < 13; mt += 4) {
    int m0 = mt * 16;
    v8bf af0 = *(const v8bf*)(Qs + (m0 + mrow) * 72 + ksel);
    v8bf af1 = *(const v8bf*)(Qs + (m0 + mrow) * 72 + 32 + ksel);
    v4f acc[13];
#pragma unroll
    for (int j = 0; j < 13; j++) {
      v8bf bf0 = *(const v8bf*)(Ks + (j * 16 + mrow) * 72 + ksel);
      v8bf bf1 = *(const v8bf*)(Ks + (j * 16 + mrow) * 72 + 32 + ksel);
      v4f t = __builtin_amdgcn_mfma_f32_16x16x32_bf16(af0, bf0, zero, 0, 0, 0);
      acc[j] = __builtin_amdgcn_mfma_f32_16x16x32_bf16(af1, bf1, t, 0, 0, 0);
    }
    // scale + column mask + row max
    float mx[4] = {-1e30f, -1e30f, -1e30f, -1e30f};
#pragma unroll
    for (int j = 0; j < 13; j++) {
      bool colv = (j < 12) || (ncol < 4);
#pragma unroll
      for (int r = 0; r < 4; r++) {
        float sv = colv ? BETA_F * acc[j][r] : -1e30f;
        acc[j][r] = sv;
        mx[r] = fmaxf(mx[r], sv);
      }
    }
#pragma unroll
    for (int o = 1; o < 16; o <<= 1)
#pragma unroll
      for (int r = 0; r < 4; r++) mx[r] = fmaxf(mx[r], __shfl_xor(mx[r], o, 64));
    // exp + row sum
    float zr[4] = {0.f, 0.f, 0.f, 0.f};
#pragma unroll
    for (int j = 0; j < 13; j++)
#pragma unroll
      for (int r = 0; r < 4; r++) {
        float t = (acc[j][r] > -1e29f) ? expf(acc[j][r] - mx[r]) : 0.f;
        acc[j][r] = t;
        zr[r] += t;
      }
#pragma unroll
    for (int o = 1; o < 16; o <<= 1)
#pragma unroll
      for (int r = 0; r < 4; r++) zr[r] += __shfl_xor(zr[r], o, 64);
    // energy (once per row: ncol==0 lanes)
    if (ncol == 0) {
#pragma unroll
      for (int r = 0; r < 4; r++) {
        int q = m0 + quad * 4 + r;
        if (q < SEQ) eacc += (double)(mx[r] + logf(zr[r]));
      }
    }
    if (STOREP) {
      float inv[4];
#pragma unroll
      for (int r = 0; r < 4; r++) inv[r] = 1.f / zr[r];
      size_t Pb = ((size_t)bh * PROWS + (m0 + quad * 4)) * PCOLS;
#pragma unroll
      for (int j = 0; j < 13; j++)
#pragma unroll
        for (int r = 0; r < 4; r++) {
          int q = m0 + quad * 4 + r;
          float pv = (q < SEQ) ? acc[j][r] * inv[r] : 0.f;
          P[Pb + (size_t)r * PCOLS + j * 16 + ncol] = (__bf16)pv;
        }
      // zero pad cols 208..223 (read by bwd K=224 loop)
#pragma unroll
      for (int r = 0; r < 4; r++)
        P[Pb + (size_t)r * PCOLS + 208 + ncol] = (__bf16)0.f;
    }
  }
  for (int o = 32; o; o >>= 1) eacc += __shfl_xor(eacc, o, 64);
  if (lane == 0) er[w] = eacc;
  __syncthreads();
  if (tid == 0)
    ep[ver * 96 + bh] = -(double)INV_BETA * ((er[0] + er[1]) + (er[2] + er[3]));
}

// ------------------------------------------------------------------
// P -> PT transpose (per bh, 32x32 tiles). grid (96, 7, 7).
// PT[k][q] = P[q][k]; pad regions come out zero automatically.
// ------------------------------------------------------------------
__global__ __launch_bounds__(256) void ptrans_k(
    const __bf16* __restrict__ Pg, __bf16* __restrict__ PTg)
{
  __shared__ __bf16 t[32][33];
  int bh = blockIdx.x;
  int q0 = blockIdx.y * 32, k0 = blockIdx.z * 32;
  int tx = threadIdx.x & 31, ty = threadIdx.x >> 5;
  const __bf16* Pb = Pg + (size_t)bh * PAREA;
  __bf16* PTb = PTg + (size_t)bh * PAREA;
  for (int rr = ty; rr < 32; rr += 8)
    t[rr][tx] = (q0 + rr < PROWS) ? Pb[(size_t)(q0 + rr) * PCOLS + k0 + tx] : (__bf16)0.f;
  __syncthreads();
  for (int rr = ty; rr < 32; rr += 8)
    if (k0 + rr < PROWS)
      PTb[(size_t)(k0 + rr) * PCOLS + q0 + tx] = t[tx][rr];
}

// ------------------------------------------------------------------
// MFMA attention backward. grid (96 bh, 2):
//  z=0: dQ[q,y] = -(P @ K)   A=P  rows q, B=K^T rows y
//  z=1: dK[k,y] = -(PT @ Q)  A=PT rows k, B=Q^T rows y
// B^T built in LDS (stride 232). A fragments read direct from global.
// ------------------------------------------------------------------
__global__ __launch_bounds__(256) void attn_bwd_k(
    const __bf16* __restrict__ Kb, const __bf16* __restrict__ Qb,
    const __bf16* __restrict__ Pg, const __bf16* __restrict__ PTg,
    __bf16* __restrict__ dQg, __bf16* __restrict__ dKg)
{
  __shared__ __align__(16) __bf16 BT[64 * 232];
  int bh = blockIdx.x, z = blockIdx.y;
  int b = bh / HN, h = bh - b * HN;
  const __bf16* Bsrc = (z ? Qb : Kb) + (size_t)(b * SEQ) * DIM + h * YD;
  const __bf16* Asrc = (z ? PTg : Pg) + (size_t)bh * PAREA;
  __bf16* Dst = (z ? dKg : dQg) + (size_t)(b * SEQ) * DIM + h * YD;
  int tid = threadIdx.x;
  // zero BT then fill transposed
  for (int i = tid; i < 64 * 232 / 8; i += 256) ((v8bf*)BT)[i] = zero8();
  __syncthreads();
  for (int i = tid; i < SEQ * 8; i += 256) {
    int k = i >> 3, c = i & 7;
    v8bf v = *(const v8bf*)(Bsrc + (size_t)k * DIM + c * 8);
#pragma unroll
    for (int e = 0; e < 8; e++) BT[(c * 8 + e) * 232 + k] = v[e];
  }
  __syncthreads();

  int lane = tid & 63, w = tid >> 6;
  int mrow = lane & 15, quad = lane >> 4, ncol = mrow;
  int ksel = quad * 8;
  for (int mt = w; mt < 13; mt += 4) {
    int m0 = mt * 16;
    v4f acc[4];
    v4f zero = {0.f, 0.f, 0.f, 0.f};
#pragma unroll
    for (int n = 0; n < 4; n++) acc[n] = zero;
#pragma unroll
    for (int s = 0; s < 7; s++) {
      v8bf af = *(const v8bf*)(Asrc + (size_t)(m0 + mrow) * PCOLS + s * 32 + ksel);
#pragma unroll
      for (int n = 0; n < 4; n++) {
        v8bf bf = *(const v8bf*)(BT + (n * 16 + mrow) * 232 + s * 32 + ksel);
        acc[n] = __builtin_amdgcn_mfma_f32_16x16x32_bf16(af, bf, acc[n], 0, 0, 0);
      }
    }
    int row = m0 + quad * 4;
#pragma unroll
    for (int n = 0; n < 4; n++)
#pragma unroll
      for (int r = 0; r < 4; r++)
        if (row + r < SEQ)
          Dst[(size_t)(row + r) * DIM + n * 16 + ncol] = (__bf16)(-acc[n][r]);
  }
}

// ------------------------------------------------------------------
// Reduce energy partials -> slots[0..4]. grid(5).
// ------------------------------------------------------------------
__global__ __launch_bounds__(256) void reduce_k(
    const double* __restrict__ ep, double* __restrict__ slots)
{
  int s = blockIdx.x;
  int tid = threadIdx.x;
  int a0 = 96 * s;
  int b0 = (s == 0) ? EP_HOPB : EP_HOPT + 312 * (s - 1);
  double acc = 0.0;
  for (int i = tid; i < 96; i += 256) acc += ep[a0 + i];
  for (int i = tid; i < 312; i += 256) acc += ep[b0 + i];
  for (int o = 32; o; o >>= 1) acc += __shfl_xor(acc, o, 64);
  __shared__ double sm[4];
  if ((tid & 63) == 0) sm[tid >> 6] = acc;
  __syncthreads();
  if (tid == 0) slots[s] = (sm[0] + sm[1]) + (sm[2] + sm[3]);
}

// ------------------------------------------------------------------
// Setup kernels
// ------------------------------------------------------------------
__global__ __launch_bounds__(256) void init_k(
    __bf16* __restrict__ g, __bf16* __restrict__ gt,
    __bf16* __restrict__ dq, __bf16* __restrict__ dk)
{
  int i = blockIdx.x * 256 + threadIdx.x;
  const int PADN = (MPAD - TOK) * DIM;   // 73728
  if (i < PADN) {
    size_t o = (size_t)TOK * DIM + i;
    g[o] = (__bf16)0.f; dq[o] = (__bf16)0.f; dk[o] = (__bf16)0.f;
#pragma unroll
    for (int t = 0; t < 4; t++)
      gt[(size_t)t * MPAD * DIM + o] = (__bf16)0.f;
  }
}

__global__ __launch_bounds__(256) void cvt_k(
    const float* __restrict__ src, __bf16* __restrict__ dst, int n4)
{
  int i = blockIdx.x * 256 + threadIdx.x;
  if (i < n4) {
    float4 v = ((const float4*)src)[i];
    v4bf o = { (__bf16)v.x, (__bf16)v.y, (__bf16)v.z, (__bf16)v.w };
    *(v4bf*)(dst + 4 * (size_t)i) = o;
  }
}

// dst[c*R + r] = scale * src[r*C + c]
__global__ __launch_bounds__(256) void cvtT_k(
    const float* __restrict__ src, __bf16* __restrict__ dst,
    int R, int C, float scale)
{
  __shared__ float t[32][33];
  int r0 = blockIdx.y * 32, c0 = blockIdx.x * 32;
  int tx = threadIdx.x & 31, ty = threadIdx.x >> 5;
  for (int rr = ty; rr < 32; rr += 8)
    t[rr][tx] = src[(size_t)(r0 + rr) * C + c0 + tx];
  __syncthreads();
  for (int rr = ty; rr < 32; rr += 8)
    dst[(size_t)(c0 + rr) * R + r0 + tx] = (__bf16)(scale * t[tx][rr]);
}

__global__ void choose_k(const double* __restrict__ e, float* __restrict__ chosen) {
  if (threadIdx.x == 0) {
    double e0 = e[0];
    float c = 0.0625f;                 // lr0 * gamma^4
    if (e[4] < e0) c = 0.125f;         // kk=3
    if (e[3] < e0) c = 0.25f;          // kk=2
    if (e[2] < e0) c = 0.5f;           // kk=1
    if (e[1] < e0) c = 1.0f;           // kk=0
    *chosen = c;
  }
}

__global__ __launch_bounds__(256) void update_k(
    const float* __restrict__ x, const float* __restrict__ g,
    const float* __restrict__ chosen, float* __restrict__ out, int n4)
{
  int i = blockIdx.x * 256 + threadIdx.x;
  float lr = *chosen;
  if (i < n4) {
    const float4 xv = ((const float4*)x)[i];
    const float4 gv = ((const float4*)g)[i];
    float4 o;
    o.x = xv.x - lr * gv.x; o.y = xv.y - lr * gv.y;
    o.z = xv.z - lr * gv.z; o.w = xv.w - lr * gv.w;
    ((float4*)out)[i] = o;
  }
}

// ------------------------------------------------------------------
extern "C" void kernel_launch(void* const* d_in, const int* in_sizes, int n_in,
                              void* d_out, int out_size, void* d_ws, size_t ws_size,
                              hipStream_t stream)
{
  const float* x     = (const float*)d_in[0];
  const float* gamma = (const float*)d_in[1];
  const float* delta = (const float*)d_in[2];
  const float* wk    = (const float*)d_in[3];
  const float* wq    = (const float*)d_in[4];
  const float* xi    = (const float*)d_in[5];
  float* out = (float*)d_out;

  const size_t NE = (size_t)TOK * DIM;
  const size_t NP = (size_t)MPAD * DIM;

  double* slots = (double*)d_ws;                 // 16 doubles
  double* eparts = slots + 16;                   // 2040 doubles
  float* fp = (float*)(eparts + EP_TOTAL);
  float* xhat = fp;  fp += NE;
  float* grad = fp;  fp += NE;
  float* rstd = fp;  fp += TOK;
  float* chosen = fp; fp += 16;
  __bf16* bp = (__bf16*)(((uintptr_t)fp + 15) & ~(uintptr_t)15);
  __bf16* g_bf   = bp;  bp += NP;
  __bf16* g_tr   = bp;  bp += 4 * NP;
  __bf16* Kb_bf  = bp;  bp += NP;
  __bf16* Qb_bf  = bp;  bp += NP;
  __bf16* dQg_bf = bp;  bp += NP;
  __bf16* dKg_bf = bp;  bp += NP;
  __bf16* rh_bf  = bp;  bp += (size_t)MPAD * MXI;
  __bf16* wk_bf  = bp;  bp += (size_t)DIM * DIM;
  __bf16* wq_bf  = bp;  bp += (size_t)DIM * DIM;
  __bf16* wkT_bf = bp;  bp += (size_t)DIM * DIM;
  __bf16* wqT_bf = bp;  bp += (size_t)DIM * DIM;
  __bf16* xi_bf  = bp;  bp += (size_t)MXI * DIM;
  __bf16* xiT_bf = bp;  bp += (size_t)DIM * MXI;
  __bf16* P_bf   = bp;  bp += (size_t)96 * PAREA;
  __bf16* PT_bf  = bp;  bp += (size_t)96 * PAREA;
  __bf16* KbT_bf = bp;  bp += 4 * NP;
  __bf16* QbT_bf = bp;  bp += 4 * NP;
  // dG split-K partials alias KbT/QbT (consumed by ln_bwd BEFORE the trial
  // KQ GEMM overwrites): 3*NP floats = 6*NP bf16 <= 8*NP available.
  float* dGp0 = (float*)KbT_bf;
  float* dGp1 = dGp0 + NP;
  float* dGp2 = dGp1 + NP;

  const int n4 = (int)(NE / 4);
  dim3 blk(256);
  dim3 gKQ(DIM / 128, MPAD / 128, 2);       // (6,13,2)
  dim3 gHop(MXI / 128, MPAD / 128);         // (24,13)
  dim3 gBwd(DIM / 128, MPAD / 128, 3);      // (6,13,3)
  dim3 gKQt(DIM / 128, 4 * MPAD / 128, 2);  // (6,52,2)
  dim3 gHopT(MXI / 128, 4 * MPAD / 128);    // (24,52)

  // ---- setup ----
  hipLaunchKernelGGL(init_k, dim3(((MPAD - TOK) * DIM + 255) / 256), blk, 0, stream,
                     g_bf, g_tr, dQg_bf, dKg_bf);
  hipLaunchKernelGGL(cvt_k, dim3((DIM * DIM / 4 + 255) / 256), blk, 0, stream, wk, wk_bf, DIM * DIM / 4);
  hipLaunchKernelGGL(cvt_k, dim3((DIM * DIM / 4 + 255) / 256), blk, 0, stream, wq, wq_bf, DIM * DIM / 4);
  hipLaunchKernelGGL(cvt_k, dim3((MXI * DIM / 4 + 255) / 256), blk, 0, stream, xi, xi_bf, MXI * DIM / 4);
  hipLaunchKernelGGL(cvtT_k, dim3(DIM / 32, DIM / 32), blk, 0, stream, wk, wkT_bf, DIM, DIM, 1.f);
  hipLaunchKernelGGL(cvtT_k, dim3(DIM / 32, DIM / 32), blk, 0, stream, wq, wqT_bf, DIM, DIM, 1.f);
  hipLaunchKernelGGL(cvtT_k, dim3(DIM / 32, MXI / 32), blk, 0, stream, xi, xiT_bf, MXI, DIM, -1.f);

  // ---- base forward ----
  hipLaunchKernelGGL(ln_fwd_k, dim3(TOK), blk, 0, stream, x, gamma, delta, g_bf, xhat, rstd);
  hipLaunchKernelGGL(gemm_k<4>, gKQ, blk, 0, stream,
                     g_bf, wk_bf, DIM, wq_bf, (float*)Kb_bf, Qb_bf, DIM, (double*)nullptr);
  hipLaunchKernelGGL(attn_mfma_k<1>, dim3(96), blk, 0, stream, Kb_bf, Qb_bf, P_bf, eparts);
  hipLaunchKernelGGL(gemm_k<1>, gHop, blk, 0, stream,
                     g_bf, xi_bf, DIM, (const __bf16*)nullptr,
                     (float*)nullptr, rh_bf, MXI, eparts);
  // ---- backward ----
  hipLaunchKernelGGL(ptrans_k, dim3(96, 7, 7), blk, 0, stream, P_bf, PT_bf);
  hipLaunchKernelGGL(attn_bwd_k, dim3(96, 2), blk, 0, stream,
                     Kb_bf, Qb_bf, P_bf, PT_bf, dQg_bf, dKg_bf);
  hipLaunchKernelGGL(gemm_bwd_k, gBwd, blk, 0, stream,
                     dQg_bf, wqT_bf, dKg_bf, wkT_bf, rh_bf, xiT_bf, dGp0, dGp1, dGp2);
  hipLaunchKernelGGL(ln_bwd_k, dim3(TOK), blk, 0, stream,
                     dGp0, dGp1, dGp2, xhat, rstd, gamma, grad);

  // ---- Armijo trials (batched) ----
  hipLaunchKernelGGL(axpyln_k, dim3(TOK, 4), blk, 0, stream, x, grad, gamma, delta, g_tr);
  hipLaunchKernelGGL(gemm_k<4>, gKQt, blk, 0, stream,
                     g_tr, wk_bf, DIM, wq_bf, (float*)KbT_bf, QbT_bf, DIM, (double*)nullptr);
  hipLaunchKernelGGL(attn_mfma_k<0>, dim3(96, 4), blk, 0, stream,
                     KbT_bf, QbT_bf, (__bf16*)nullptr, eparts);
  hipLaunchKernelGGL(gemm_k<5>, gHopT, blk, 0, stream,
                     g_tr, xi_bf, DIM, (const __bf16*)nullptr,
                     (float*)nullptr, (__bf16*)nullptr, MXI, eparts);

  // ---- reduce energies, choose lr, final update ----
  hipLaunchKernelGGL(reduce_k, dim3(5), blk, 0, stream, eparts, slots);
  hipLaunchKernelGGL(choose_k, dim3(1), dim3(64), 0, stream, slots, chosen);
  hipLaunchKernelGGL(update_k, dim3((n4 + 255) / 256), blk, 0, stream, x, grad, chosen, out, n4);
}

// Round 7
// 327.155 us; speedup vs baseline: 13.4140x; 1.0232x over previous
//
#include <hip/hip_runtime.h>
#include <math.h>

#define TOK 1568      // B*N = 8*196
#define MPAD 1664     // 13 * 128
#define DIM 768
#define HN 12
#define SEQ 196
#define YD 64
#define MXI 3072
#define BETA_F 0.125f
#define INV_BETA 8.0f
#define LN_EPS_F 1e-5f

// P/PT padded geometry: rows 208 (13*16), cols 224 (7*32)
#define PROWS 208
#define PCOLS 224
#define PAREA (PROWS * PCOLS)

// energy partials (doubles): attn ver*96+bh, ver 0..4 -> [0,480)
// hop base [480,792) ; hop trial t*312 -> [792,2040)
#define EP_HOPB 480
#define EP_HOPT 792
#define EP_TOTAL 2040

typedef __bf16 v8bf __attribute__((ext_vector_type(8)));
typedef __bf16 v4bf __attribute__((ext_vector_type(4)));
typedef float  v4f  __attribute__((ext_vector_type(4)));

__device__ __forceinline__ v8bf zero8() {
  v8bf v = { (__bf16)0.f, (__bf16)0.f, (__bf16)0.f, (__bf16)0.f,
             (__bf16)0.f, (__bf16)0.f, (__bf16)0.f, (__bf16)0.f };
  return v;
}

// ------------------------------------------------------------------
// LayerNorm forward -> bf16 g + fp32 xhat/rstd
// ------------------------------------------------------------------
__global__ __launch_bounds__(256) void ln_fwd_k(
    const float* __restrict__ x, const float* __restrict__ gamma,
    const float* __restrict__ delta, __bf16* __restrict__ g,
    float* __restrict__ xhat, float* __restrict__ rstd)
{
  __shared__ float s[4];
  int tok = blockIdx.x;
  int tid = threadIdx.x;
  const float* xp = x + (size_t)tok * DIM;
  float v0 = xp[tid], v1 = xp[tid + 256], v2 = xp[tid + 512];
  float sum = v0 + v1 + v2;
  for (int o = 32; o; o >>= 1) sum += __shfl_xor(sum, o, 64);
  if ((tid & 63) == 0) s[tid >> 6] = sum;
  __syncthreads();
  float mu = (s[0] + s[1] + s[2] + s[3]) * (1.0f / DIM);
  __syncthreads();
  float d0 = v0 - mu, d1 = v1 - mu, d2 = v2 - mu;
  float sq = d0 * d0 + d1 * d1 + d2 * d2;
  for (int o = 32; o; o >>= 1) sq += __shfl_xor(sq, o, 64);
  if ((tid & 63) == 0) s[tid >> 6] = sq;
  __syncthreads();
  float var = (s[0] + s[1] + s[2] + s[3]) * (1.0f / DIM);
  float r = rsqrtf(var + LN_EPS_F);
  float xh0 = d0 * r, xh1 = d1 * r, xh2 = d2 * r;
  size_t base = (size_t)tok * DIM;
  g[base + tid]       = (__bf16)(gamma[tid] * xh0 + delta[tid]);
  g[base + tid + 256] = (__bf16)(gamma[tid + 256] * xh1 + delta[tid + 256]);
  g[base + tid + 512] = (__bf16)(gamma[tid + 512] * xh2 + delta[tid + 512]);
  xhat[base + tid] = xh0; xhat[base + tid + 256] = xh1; xhat[base + tid + 512] = xh2;
  if (tid == 0) rstd[tok] = r;
}

// ------------------------------------------------------------------
// Fused trial step + LayerNorm. grid (TOK, 4). Writes bf16 (for KQ GEMM)
// and fp8 e4m3 (for the fp8 trial-hopfield GEMM).
// ------------------------------------------------------------------
__global__ __launch_bounds__(256) void axpyln_k(
    const float* __restrict__ x, const float* __restrict__ grad,
    const float* __restrict__ gamma, const float* __restrict__ delta,
    __bf16* __restrict__ gt, unsigned char* __restrict__ g8)
{
  __shared__ float s[4];
  int tok = blockIdx.x, t = blockIdx.y;
  float lr = 1.0f / (float)(1 << t);   // lr = 0.5^t
  int tid = threadIdx.x;
  const float* xp = x + (size_t)tok * DIM;
  const float* gp = grad + (size_t)tok * DIM;
  float v0 = xp[tid]       - lr * gp[tid];
  float v1 = xp[tid + 256] - lr * gp[tid + 256];
  float v2 = xp[tid + 512] - lr * gp[tid + 512];
  float sum = v0 + v1 + v2;
  for (int o = 32; o; o >>= 1) sum += __shfl_xor(sum, o, 64);
  if ((tid & 63) == 0) s[tid >> 6] = sum;
  __syncthreads();
  float mu = (s[0] + s[1] + s[2] + s[3]) * (1.0f / DIM);
  __syncthreads();
  float d0 = v0 - mu, d1 = v1 - mu, d2 = v2 - mu;
  float sq = d0 * d0 + d1 * d1 + d2 * d2;
  for (int o = 32; o; o >>= 1) sq += __shfl_xor(sq, o, 64);
  if ((tid & 63) == 0) s[tid >> 6] = sq;
  __syncthreads();
  float var = (s[0] + s[1] + s[2] + s[3]) * (1.0f / DIM);
  float r = rsqrtf(var + LN_EPS_F);
  float o0 = gamma[tid] * (d0 * r) + delta[tid];
  float o1 = gamma[tid + 256] * (d1 * r) + delta[tid + 256];
  float o2 = gamma[tid + 512] * (d2 * r) + delta[tid + 512];
  size_t ob = ((size_t)t * MPAD + tok) * DIM;
  gt[ob + tid]       = (__bf16)o0;
  gt[ob + tid + 256] = (__bf16)o1;
  gt[ob + tid + 512] = (__bf16)o2;
  g8[ob + tid]       = (unsigned char)(__builtin_amdgcn_cvt_pk_fp8_f32(o0, o0, 0, false) & 0xff);
  g8[ob + tid + 256] = (unsigned char)(__builtin_amdgcn_cvt_pk_fp8_f32(o1, o1, 0, false) & 0xff);
  g8[ob + tid + 512] = (unsigned char)(__builtin_amdgcn_cvt_pk_fp8_f32(o2, o2, 0, false) & 0xff);
}

// ------------------------------------------------------------------
// LayerNorm backward; dG = p0 + p1 + p2 (split-K partials)
// ------------------------------------------------------------------
__global__ __launch_bounds__(256) void ln_bwd_k(
    const float* __restrict__ p0, const float* __restrict__ p1,
    const float* __restrict__ p2, const float* __restrict__ xhat,
    const float* __restrict__ rstd, const float* __restrict__ gamma,
    float* __restrict__ grad)
{
  __shared__ float s[8];
  int tok = blockIdx.x;
  int tid = threadIdx.x;
  size_t base = (size_t)tok * DIM;
  float g0 = p0[base + tid]       + p1[base + tid]       + p2[base + tid];
  float g1 = p0[base + tid + 256] + p1[base + tid + 256] + p2[base + tid + 256];
  float g2 = p0[base + tid + 512] + p1[base + tid + 512] + p2[base + tid + 512];
  float dh0 = g0 * gamma[tid];
  float dh1 = g1 * gamma[tid + 256];
  float dh2 = g2 * gamma[tid + 512];
  float xh0 = xhat[base + tid], xh1 = xhat[base + tid + 256], xh2 = xhat[base + tid + 512];
  float s1 = dh0 + dh1 + dh2;
  float s2 = dh0 * xh0 + dh1 * xh1 + dh2 * xh2;
  for (int o = 32; o; o >>= 1) { s1 += __shfl_xor(s1, o, 64); s2 += __shfl_xor(s2, o, 64); }
  if ((tid & 63) == 0) { s[tid >> 6] = s1; s[4 + (tid >> 6)] = s2; }
  __syncthreads();
  float m1 = (s[0] + s[1] + s[2] + s[3]) * (1.0f / DIM);
  float m2 = (s[4] + s[5] + s[6] + s[7]) * (1.0f / DIM);
  float r = rstd[tok];
  grad[base + tid]       = r * (dh0 - m1 - xh0 * m2);
  grad[base + tid + 256] = r * (dh1 - m1 - xh1 * m2);
  grad[base + tid + 512] = r * (dh2 - m1 - xh2 * m2);
}

// ------------------------------------------------------------------
// Stage one 128x32 bf16 tile into LDS (global_load_lds width=16),
// K-chunk XOR-swizzled: LDS chunk (row,c) holds global (row, c^((row>>1)&3)).
// Fragment reads then use q^((row>>1)&3) -> 2-way banks (free).
// ------------------------------------------------------------------
__device__ __forceinline__ void stage_tile(
    const __bf16* __restrict__ G, int ldK, int r0, int k0,
    __bf16* S, int tid, int w)
{
#pragma unroll
  for (int r = 0; r < 2; r++) {
    int ch = (r << 8) + tid;
    int row = ch >> 2;
    int col = (ch & 3) ^ ((row >> 1) & 3);
    __builtin_amdgcn_global_load_lds(
        (__attribute__((address_space(1))) uint32_t*)(G + (size_t)(r0 + row) * ldK + k0 + (col << 3)),
        (__attribute__((address_space(3))) uint32_t*)(S + (r << 11) + (w << 9)),
        16, 0, 0);
  }
}

// ------------------------------------------------------------------
// MFMA GEMM: C[M,N] = A[M,K] @ B[N,K]^T, bf16 in, fp32 accum.
// 128x128 tile, BK=32, double-buffered LDS, 4 waves (2x2 of 64x64).
// __launch_bounds__(256,4): cap unified VGPR at 128 -> 4 blocks/CU.
// MODE 1: relu -> bf16 Cb + energy partial ep[EP_HOPB + idx]  [base hop]
// MODE 4: dual bf16 store (z: B0->(bf16*)Cf, B1->Cb)          [KQ]
// ------------------------------------------------------------------
template <int MODE>
__global__ __launch_bounds__(256, 4) void gemm_k(
    const __bf16* __restrict__ A0, const __bf16* __restrict__ B0, int K0,
    const __bf16* __restrict__ B1,
    float* __restrict__ Cf, __bf16* __restrict__ Cb, int N,
    double* __restrict__ ep)
{
  __shared__ __align__(16) __bf16 As[2][4096];
  __shared__ __align__(16) __bf16 Bs[2][4096];
  __shared__ double ered[4];
  int tid = threadIdx.x, lane = tid & 63, w = tid >> 6;
  int wm = (w & 1) << 6, wn = (w >> 1) << 6;
  int m0 = blockIdx.y * 128, n0 = blockIdx.x * 128;

  const __bf16* Bsel = B0;
  if (MODE == 4 && blockIdx.z) Bsel = B1;

  v4f zero = {0.f, 0.f, 0.f, 0.f};
  v4f acc[4][4];
#pragma unroll
  for (int i = 0; i < 4; i++)
#pragma unroll
    for (int j = 0; j < 4; j++) acc[i][j] = zero;

  const int nk = K0 >> 5;
  stage_tile(A0, K0, m0, 0, As[0], tid, w);
  stage_tile(Bsel, K0, n0, 0, Bs[0], tid, w);
  for (int kt = 0; kt < nk; kt++) {
    __syncthreads();
    int nxt = kt + 1;
    if (nxt < nk) {
      stage_tile(A0, K0, m0, nxt << 5, As[nxt & 1], tid, w);
      stage_tile(Bsel, K0, n0, nxt << 5, Bs[nxt & 1], tid, w);
    }
    const __bf16* Ac = As[kt & 1];
    const __bf16* Bc = Bs[kt & 1];
    int mrow = lane & 15, q = lane >> 4;
    v8bf af[4], bfr[4];
#pragma unroll
    for (int i = 0; i < 4; i++) {
      int rA = wm + (i << 4) + mrow;
      int rB = wn + (i << 4) + mrow;
      af[i]  = *(const v8bf*)(Ac + rA * 32 + ((q ^ ((rA >> 1) & 3)) << 3));
      bfr[i] = *(const v8bf*)(Bc + rB * 32 + ((q ^ ((rB >> 1) & 3)) << 3));
    }
#pragma unroll
    for (int i = 0; i < 4; i++)
#pragma unroll
      for (int j = 0; j < 4; j++)
        acc[i][j] = __builtin_amdgcn_mfma_f32_16x16x32_bf16(af[i], bfr[j], acc[i][j], 0, 0, 0);
  }

  // C/D: col = lane&15, row = quad*4 + reg
  int quad = lane >> 4, ncol = lane & 15;
  if (MODE == 4) {
    __bf16* Cout = blockIdx.z ? Cb : (__bf16*)Cf;
#pragma unroll
    for (int i = 0; i < 4; i++)
#pragma unroll
      for (int j = 0; j < 4; j++) {
        int row = m0 + wm + (i << 4) + (quad << 2);
        int col = n0 + wn + (j << 4) + ncol;
#pragma unroll
        for (int r = 0; r < 4; r++)
          Cout[(size_t)(row + r) * N + col] = (__bf16)acc[i][j][r];
      }
  } else {  // MODE 1
    float e = 0.f;
#pragma unroll
    for (int i = 0; i < 4; i++)
#pragma unroll
      for (int j = 0; j < 4; j++) {
        int row = m0 + wm + (i << 4) + (quad << 2);
        int col = n0 + wn + (j << 4) + ncol;
#pragma unroll
        for (int r = 0; r < 4; r++) {
          float v = acc[i][j][r];
          v = v > 0.f ? v : 0.f;
          e += v * v;
          Cb[(size_t)(row + r) * N + col] = (__bf16)v;
        }
      }
    for (int o = 32; o; o >>= 1) e += __shfl_xor(e, o, 64);
    if (lane == 0) ered[w] = (double)e;
    __syncthreads();
    if (tid == 0) {
      double tot = (ered[0] + ered[1]) + (ered[2] + ered[3]);
      ep[EP_HOPB + blockIdx.y * 24 + blockIdx.x] = -0.5 * tot;
    }
  }
}

// ------------------------------------------------------------------
// fp8 e4m3 MFMA GEMM, energy only (trial hopfield). A = g8 [4*MPAD, 768],
// B = xi8 (pre-scaled by 16 -> energy * 1/256). grid (24, 52).
// BK=32 (16x16x32 fp8), LDS 4KB/tile, 16B-chunk swizzle c^((row>>2)&1).
// ------------------------------------------------------------------
__global__ __launch_bounds__(256, 4) void gemm8_k(
    const unsigned char* __restrict__ A0, const unsigned char* __restrict__ B0,
    double* __restrict__ ep)
{
  __shared__ __align__(16) unsigned char As[2][4096];
  __shared__ __align__(16) unsigned char Bs[2][4096];
  __shared__ double ered[4];
  int tid = threadIdx.x, lane = tid & 63, w = tid >> 6;
  int wm = (w & 1) << 6, wn = (w >> 1) << 6;
  int m0 = blockIdx.y * 128, n0 = blockIdx.x * 128;

  v4f zero = {0.f, 0.f, 0.f, 0.f};
  v4f acc[4][4];
#pragma unroll
  for (int i = 0; i < 4; i++)
#pragma unroll
    for (int j = 0; j < 4; j++) acc[i][j] = zero;

  // one 16B chunk per thread per tile
  int srow = tid >> 1;
  int sc16 = (tid & 1) ^ ((srow >> 2) & 1);
  const int nk = DIM >> 5;   // 24
#define STAGE8(buf, k0)                                                          \
  do {                                                                           \
    __builtin_amdgcn_global_load_lds(                                            \
        (__attribute__((address_space(1))) uint32_t*)(A0 + (size_t)(m0 + srow) * DIM + (k0) + (sc16 << 4)), \
        (__attribute__((address_space(3))) uint32_t*)(As[buf] + (w << 10)), 16, 0, 0); \
    __builtin_amdgcn_global_load_lds(                                            \
        (__attribute__((address_space(1))) uint32_t*)(B0 + (size_t)(n0 + srow) * DIM + (k0) + (sc16 << 4)), \
        (__attribute__((address_space(3))) uint32_t*)(Bs[buf] + (w << 10)), 16, 0, 0); \
  } while (0)

  STAGE8(0, 0);
  for (int kt = 0; kt < nk; kt++) {
    __syncthreads();
    int nxt = kt + 1;
    if (nxt < nk) STAGE8(nxt & 1, nxt << 5);
    const unsigned char* Ac = As[kt & 1];
    const unsigned char* Bc = Bs[kt & 1];
    int mrow = lane & 15, q = lane >> 4;
    long af[4], bfr[4];
#pragma unroll
    for (int i = 0; i < 4; i++) {
      int rA = wm + (i << 4) + mrow;
      int rB = wn + (i << 4) + mrow;
      int qa = q ^ ((( rA >> 2) & 1) << 1);
      int qb = q ^ ((( rB >> 2) & 1) << 1);
      af[i]  = *(const long*)(Ac + rA * 32 + (qa << 3));
      bfr[i] = *(const long*)(Bc + rB * 32 + (qb << 3));
    }
#pragma unroll
    for (int i = 0; i < 4; i++)
#pragma unroll
      for (int j = 0; j < 4; j++)
        acc[i][j] = __builtin_amdgcn_mfma_f32_16x16x32_fp8_fp8(af[i], bfr[j], acc[i][j], 0, 0, 0);
  }
#undef STAGE8

  float e = 0.f;
#pragma unroll
  for (int i = 0; i < 4; i++)
#pragma unroll
    for (int j = 0; j < 4; j++)
#pragma unroll
      for (int r = 0; r < 4; r++) {
        float v = acc[i][j][r];
        v = v > 0.f ? v : 0.f;
        e += v * v;
      }
  for (int o = 32; o; o >>= 1) e += __shfl_xor(e, o, 64);
  if (lane == 0) ered[w] = (double)e;
  __syncthreads();
  if (tid == 0) {
    double tot = (ered[0] + ered[1]) + (ered[2] + ered[3]);
    int tt = blockIdx.y / 13, ry = blockIdx.y - tt * 13;
    ep[EP_HOPT + tt * 312 + ry * 24 + blockIdx.x] = (-0.5 / 256.0) * tot;
  }
}

// ------------------------------------------------------------------
// Backward fused GEMM, 3-way z-split. grid (6, 13, 3)
// ------------------------------------------------------------------
__global__ __launch_bounds__(256, 4) void gemm_bwd_k(
    const __bf16* __restrict__ dQg, const __bf16* __restrict__ wqT,
    const __bf16* __restrict__ dKg, const __bf16* __restrict__ wkT,
    const __bf16* __restrict__ rh, const __bf16* __restrict__ xiT,
    float* __restrict__ C0, float* __restrict__ C1, float* __restrict__ C2)
{
  __shared__ __align__(16) __bf16 As[2][4096];
  __shared__ __align__(16) __bf16 Bs[2][4096];
  int tid = threadIdx.x, lane = tid & 63, w = tid >> 6;
  int wm = (w & 1) << 6, wn = (w >> 1) << 6;
  int m0 = blockIdx.y * 128, n0 = blockIdx.x * 128;
  int z = blockIdx.z;

  const __bf16 *Aa, *Ba;
  int lda, ka;
#define TILE_OF(t)                                                        \
  do {                                                                    \
    if (z == 0) {                                                         \
      if ((t) < 24) { Aa = dQg; Ba = wqT; lda = 768; ka = (t) << 5; }     \
      else { Aa = dKg; Ba = wkT; lda = 768; ka = ((t) - 24) << 5; }       \
    } else if (z == 1) { Aa = rh; Ba = xiT; lda = 3072; ka = (t) << 5; }  \
    else { Aa = rh; Ba = xiT; lda = 3072; ka = 1536 + ((t) << 5); }       \
  } while (0)

  v4f zero = {0.f, 0.f, 0.f, 0.f};
  v4f acc[4][4];
#pragma unroll
  for (int i = 0; i < 4; i++)
#pragma unroll
    for (int j = 0; j < 4; j++) acc[i][j] = zero;

  TILE_OF(0);
  stage_tile(Aa, lda, m0, ka, As[0], tid, w);
  stage_tile(Ba, lda, n0, ka, Bs[0], tid, w);
  for (int kt = 0; kt < 48; kt++) {
    __syncthreads();
    int nxt = kt + 1;
    if (nxt < 48) {
      TILE_OF(nxt);
      stage_tile(Aa, lda, m0, ka, As[nxt & 1], tid, w);
      stage_tile(Ba, lda, n0, ka, Bs[nxt & 1], tid, w);
    }
    const __bf16* Ac = As[kt & 1];
    const __bf16* Bc = Bs[kt & 1];
    int mrow = lane & 15, q = lane >> 4;
    v8bf af[4], bfr[4];
#pragma unroll
    for (int i = 0; i < 4; i++) {
      int rA = wm + (i << 4) + mrow;
      int rB = wn + (i << 4) + mrow;
      af[i]  = *(const v8bf*)(Ac + rA * 32 + ((q ^ ((rA >> 1) & 3)) << 3));
      bfr[i] = *(const v8bf*)(Bc + rB * 32 + ((q ^ ((rB >> 1) & 3)) << 3));
    }
#pragma unroll
    for (int i = 0; i < 4; i++)
#pragma unroll
      for (int j = 0; j < 4; j++)
        acc[i][j] = __builtin_amdgcn_mfma_f32_16x16x32_bf16(af[i], bfr[j], acc[i][j], 0, 0, 0);
  }
#undef TILE_OF

  float* Cz = (z == 0) ? C0 : (z == 1) ? C1 : C2;
  int quad = lane >> 4, ncol = lane & 15;
#pragma unroll
  for (int i = 0; i < 4; i++)
#pragma unroll
    for (int j = 0; j < 4; j++) {
      int row = m0 + wm + (i << 4) + (quad << 2);
      int col = n0 + wn + (j << 4) + ncol;
#pragma unroll
      for (int r = 0; r < 4; r++)
        Cz[(size_t)(row + r) * DIM + col] = acc[i][j][r];
    }
}

// ------------------------------------------------------------------
// MFMA attention forward. STOREP=1: base (grid 96), stores P + energy.
// STOREP=0: trials (grid 96 x 4), energy only.
// ------------------------------------------------------------------
template <int STOREP>
__global__ __launch_bounds__(256) void attn_mfma_k(
    const __bf16* __restrict__ Ksrc, const __bf16* __restrict__ Qsrc,
    __bf16* __restrict__ P, double* __restrict__ ep)
{
  __shared__ __align__(16) __bf16 Ks[PROWS * 72];
  __shared__ __align__(16) __bf16 Qs[PROWS * 72];
  __shared__ double er[4];
  int bh = blockIdx.x;
  int ver = STOREP ? 0 : (blockIdx.y + 1);
  int b = bh / HN, h = bh - b * HN;
  size_t voff = STOREP ? 0 : (size_t)blockIdx.y * MPAD * DIM;
  const __bf16* Kp = Ksrc + voff + (size_t)(b * SEQ) * DIM + h * YD;
  const __bf16* Qp = Qsrc + voff + (size_t)(b * SEQ) * DIM + h * YD;
  int tid = threadIdx.x;

  for (int i = tid; i < PROWS * 8; i += 256) {
    int row = i >> 3, c = i & 7;
    v8bf kv = zero8(), qv = zero8();
    if (row < SEQ) {
      kv = *(const v8bf*)(Kp + (size_t)row * DIM + c * 8);
      qv = *(const v8bf*)(Qp + (size_t)row * DIM + c * 8);
    }
    *(v8bf*)(Ks + row * 72 + c * 8) = kv;
    *(v8bf*)(Qs + row * 72 + c * 8) = qv;
  }
  __syncthreads();

  int lane = tid & 63, w = tid >> 6;
  int mrow = lane & 15, quad = lane >> 4, ncol = mrow;
  int ksel = quad * 8;
  v4f zero = {0.f, 0.f, 0.f, 0.f};
  double eacc = 0.0;

  for (int mt = w; mt < 13; mt += 4) {
    int m0 = mt * 16;
    v8bf af0 = *(const v8bf*)(Qs + (m0 + mrow) * 72 + ksel);
    v8bf af1 = *(const v8bf*)(Qs + (m0 + mrow) * 72 + 32 + ksel);
    v4f acc[13];
#pragma unroll
    for (int j = 0; j < 13; j++) {
      v8bf bf0 = *(const v8bf*)(Ks + (j * 16 + mrow) * 72 + ksel);
      v8bf bf1 = *(const v8bf*)(Ks + (j * 16 + mrow) * 72 + 32 + ksel);
      v4f t = __builtin_amdgcn_mfma_f32_16x16x32_bf16(af0, bf0, zero, 0, 0, 0);
      acc[j] = __builtin_amdgcn_mfma_f32_16x16x32_bf16(af1, bf1, t, 0, 0, 0);
    }
    float mx[4] = {-1e30f, -1e30f, -1e30f, -1e30f};
#pragma unroll
    for (int j = 0; j < 13; j++) {
      bool colv = (j < 12) || (ncol < 4);
#pragma unroll
      for (int r = 0; r < 4; r++) {
        float sv = colv ? BETA_F * acc[j][r] : -1e30f;
        acc[j][r] = sv;
        mx[r] = fmaxf(mx[r], sv);
      }
    }
#pragma unroll
    for (int o = 1; o < 16; o <<= 1)
#pragma unroll
      for (int r = 0; r < 4; r++) mx[r] = fmaxf(mx[r], __shfl_xor(mx[r], o, 64));
    float zr[4] = {0.f, 0.f, 0.f, 0.f};
#pragma unroll
    for (int j = 0; j < 13; j++)
#pragma unroll
      for (int r = 0; r < 4; r++) {
        float t = (acc[j][r] > -1e29f) ? expf(acc[j][r] - mx[r]) : 0.f;
        acc[j][r] = t;
        zr[r] += t;
      }
#pragma unroll
    for (int o = 1; o < 16; o <<= 1)
#pragma unroll
      for (int r = 0; r < 4; r++) zr[r] += __shfl_xor(zr[r], o, 64);
    if (ncol == 0) {
#pragma unroll
      for (int r = 0; r < 4; r++) {
        int q = m0 + quad * 4 + r;
        if (q < SEQ) eacc += (double)(mx[r] + logf(zr[r]));
      }
    }
    if (STOREP) {
      float inv[4];
#pragma unroll
      for (int r = 0; r < 4; r++) inv[r] = 1.f / zr[r];
      size_t Pb = ((size_t)bh * PROWS + (m0 + quad * 4)) * PCOLS;
#pragma unroll
      for (int j = 0; j < 13; j++)
#pragma unroll
        for (int r = 0; r < 4; r++) {
          int q = m0 + quad * 4 + r;
          float pv = (q < SEQ) ? acc[j][r] * inv[r] : 0.f;
          P[Pb + (size_t)r * PCOLS + j * 16 + ncol] = (__bf16)pv;
        }
#pragma unroll
      for (int r = 0; r < 4; r++)
        P[Pb + (size_t)r * PCOLS + 208 + ncol] = (__bf16)0.f;
    }
  }
  for (int o = 32; o; o >>= 1) eacc += __shfl_xor(eacc, o, 64);
  if (lane == 0) er[w] = eacc;
  __syncthreads();
  if (tid == 0)
    ep[ver * 96 + bh] = -(double)INV_BETA * ((er[0] + er[1]) + (er[2] + er[3]));
}

// ------------------------------------------------------------------
// P -> PT transpose (per bh, 32x32 tiles). grid (96, 7, 7).
// ------------------------------------------------------------------
__global__ __launch_bounds__(256) void ptrans_k(
    const __bf16* __restrict__ Pg, __bf16* __restrict__ PTg)
{
  __shared__ __bf16 t[32][33];
  int bh = blockIdx.x;
  int q0 = blockIdx.y * 32, k0 = blockIdx.z * 32;
  int tx = threadIdx.x & 31, ty = threadIdx.x >> 5;
  const __bf16* Pb = Pg + (size_t)bh * PAREA;
  __bf16* PTb = PTg + (size_t)bh * PAREA;
  for (int rr = ty; rr < 32; rr += 8)
    t[rr][tx] = (q0 + rr < PROWS) ? Pb[(size_t)(q0 + rr) * PCOLS + k0 + tx] : (__bf16)0.f;
  __syncthreads();
  for (int rr = ty; rr < 32; rr += 8)
    if (k0 + rr < PROWS)
      PTb[(size_t)(k0 + rr) * PCOLS + q0 + tx] = t[tx][rr];
}

// ------------------------------------------------------------------
// MFMA attention backward. grid (96 bh, 2).
// ------------------------------------------------------------------
__global__ __launch_bounds__(256) void attn_bwd_k(
    const __bf16* __restrict__ Kb, const __bf16* __restrict__ Qb,
    const __bf16* __restrict__ Pg, const __bf16* __restrict__ PTg,
    __bf16* __restrict__ dQg, __bf16* __restrict__ dKg)
{
  __shared__ __align__(16) __bf16 BT[64 * 232];
  int bh = blockIdx.x, z = blockIdx.y;
  int b = bh / HN, h = bh - b * HN;
  const __bf16* Bsrc = (z ? Qb : Kb) + (size_t)(b * SEQ) * DIM + h * YD;
  const __bf16* Asrc = (z ? PTg : Pg) + (size_t)bh * PAREA;
  __bf16* Dst = (z ? dKg : dQg) + (size_t)(b * SEQ) * DIM + h * YD;
  int tid = threadIdx.x;
  for (int i = tid; i < 64 * 232 / 8; i += 256) ((v8bf*)BT)[i] = zero8();
  __syncthreads();
  for (int i = tid; i < SEQ * 8; i += 256) {
    int k = i >> 3, c = i & 7;
    v8bf v = *(const v8bf*)(Bsrc + (size_t)k * DIM + c * 8);
#pragma unroll
    for (int e = 0; e < 8; e++) BT[(c * 8 + e) * 232 + k] = v[e];
  }
  __syncthreads();

  int lane = tid & 63, w = tid >> 6;
  int mrow = lane & 15, quad = lane >> 4, ncol = mrow;
  int ksel = quad * 8;
  for (int mt = w; mt < 13; mt += 4) {
    int m0 = mt * 16;
    v4f acc[4];
    v4f zero = {0.f, 0.f, 0.f, 0.f};
#pragma unroll
    for (int n = 0; n < 4; n++) acc[n] = zero;
#pragma unroll
    for (int s = 0; s < 7; s++) {
      v8bf af = *(const v8bf*)(Asrc + (size_t)(m0 + mrow) * PCOLS + s * 32 + ksel);
#pragma unroll
      for (int n = 0; n < 4; n++) {
        v8bf bf = *(const v8bf*)(BT + (n * 16 + mrow) * 232 + s * 32 + ksel);
        acc[n] = __builtin_amdgcn_mfma_f32_16x16x32_bf16(af, bf, acc[n], 0, 0, 0);
      }
    }
    int row = m0 + quad * 4;
#pragma unroll
    for (int n = 0; n < 4; n++)
#pragma unroll
      for (int r = 0; r < 4; r++)
        if (row + r < SEQ)
          Dst[(size_t)(row + r) * DIM + n * 16 + ncol] = (__bf16)(-acc[n][r]);
  }
}

// ------------------------------------------------------------------
// Fused energy reduce + lr choose. grid(1).
// ------------------------------------------------------------------
__global__ __launch_bounds__(256) void reduce_choose_k(
    const double* __restrict__ ep, float* __restrict__ chosen)
{
  int tid = threadIdx.x;
  __shared__ double sm[4];
  double e[5];
  for (int s = 0; s < 5; s++) {
    double acc = 0.0;
    int a0 = 96 * s;
    for (int i = tid; i < 96; i += 256) acc += ep[a0 + i];
    int b0 = (s == 0) ? EP_HOPB : EP_HOPT + 312 * (s - 1);
    for (int i = tid; i < 312; i += 256) acc += ep[b0 + i];
    for (int o = 32; o; o >>= 1) acc += __shfl_xor(acc, o, 64);
    if ((tid & 63) == 0) sm[tid >> 6] = acc;
    __syncthreads();
    e[s] = (sm[0] + sm[1]) + (sm[2] + sm[3]);
    __syncthreads();
  }
  if (tid == 0) {
    double e0 = e[0];
    float c = 0.0625f;
    if (e[4] < e0) c = 0.125f;
    if (e[3] < e0) c = 0.25f;
    if (e[2] < e0) c = 0.5f;
    if (e[1] < e0) c = 1.0f;
    *chosen = c;
  }
}

// ------------------------------------------------------------------
// Setup kernels
// ------------------------------------------------------------------
__global__ __launch_bounds__(256) void init_k(
    __bf16* __restrict__ g, __bf16* __restrict__ gt,
    unsigned char* __restrict__ g8,
    __bf16* __restrict__ dq, __bf16* __restrict__ dk)
{
  int i = blockIdx.x * 256 + threadIdx.x;
  const int PADN = (MPAD - TOK) * DIM;   // 73728
  if (i < PADN) {
    size_t o = (size_t)TOK * DIM + i;
    g[o] = (__bf16)0.f; dq[o] = (__bf16)0.f; dk[o] = (__bf16)0.f;
#pragma unroll
    for (int t = 0; t < 4; t++) {
      gt[(size_t)t * MPAD * DIM + o] = (__bf16)0.f;
      g8[(size_t)t * MPAD * DIM + o] = 0;
    }
  }
}

// wk -> wk_bf, wq -> wq_bf, xi -> xi_bf + xi8 (x16, fp8). linear float4 grid.
__global__ __launch_bounds__(256) void cvtall_k(
    const float* __restrict__ wk, const float* __restrict__ wq,
    const float* __restrict__ xi, __bf16* __restrict__ wk_bf,
    __bf16* __restrict__ wq_bf, __bf16* __restrict__ xi_bf,
    int* __restrict__ xi8)
{
  const int W4 = DIM * DIM / 4;      // 147456
  const int X4 = MXI * DIM / 4;      // 589824
  int i = blockIdx.x * 256 + threadIdx.x;
  if (i < W4) {
    float4 v = ((const float4*)wk)[i];
    v4bf o = { (__bf16)v.x, (__bf16)v.y, (__bf16)v.z, (__bf16)v.w };
    *(v4bf*)(wk_bf + 4 * (size_t)i) = o;
  } else if (i < 2 * W4) {
    int j = i - W4;
    float4 v = ((const float4*)wq)[j];
    v4bf o = { (__bf16)v.x, (__bf16)v.y, (__bf16)v.z, (__bf16)v.w };
    *(v4bf*)(wq_bf + 4 * (size_t)j) = o;
  } else if (i < 2 * W4 + X4) {
    int j = i - 2 * W4;
    float4 v = ((const float4*)xi)[j];
    v4bf o = { (__bf16)v.x, (__bf16)v.y, (__bf16)v.z, (__bf16)v.w };
    *(v4bf*)(xi_bf + 4 * (size_t)j) = o;
    int pk = __builtin_amdgcn_cvt_pk_fp8_f32(16.f * v.x, 16.f * v.y, 0, false);
    pk = __builtin_amdgcn_cvt_pk_fp8_f32(16.f * v.z, 16.f * v.w, pk, true);
    xi8[j] = pk;
  }
}

// z=0: wk->wkT (768x768, s=1); z=1: wq->wqT; z=2: xi->xiT (3072x768, s=-1)
__global__ __launch_bounds__(256) void cvtTall_k(
    const float* __restrict__ wk, const float* __restrict__ wq,
    const float* __restrict__ xi, __bf16* __restrict__ wkT,
    __bf16* __restrict__ wqT, __bf16* __restrict__ xiT)
{
  __shared__ float t[32][33];
  int z = blockIdx.z;
  int R = (z == 2) ? MXI : DIM;
  if (blockIdx.y * 32 >= R) return;
  const float* src = (z == 0) ? wk : (z == 1) ? wq : xi;
  __bf16* dst = (z == 0) ? wkT : (z == 1) ? wqT : xiT;
  float scale = (z == 2) ? -1.f : 1.f;
  int r0 = blockIdx.y * 32, c0 = blockIdx.x * 32;
  int tx = threadIdx.x & 31, ty = threadIdx.x >> 5;
  for (int rr = ty; rr < 32; rr += 8)
    t[rr][tx] = src[(size_t)(r0 + rr) * DIM + c0 + tx];
  __syncthreads();
  for (int rr = ty; rr < 32; rr += 8)
    dst[(size_t)(c0 + rr) * R + r0 + tx] = (__bf16)(scale * t[tx][rr]);
}

__global__ __launch_bounds__(256) void update_k(
    const float* __restrict__ x, const float* __restrict__ g,
    const float* __restrict__ chosen, float* __restrict__ out, int n4)
{
  int i = blockIdx.x * 256 + threadIdx.x;
  float lr = *chosen;
  if (i < n4) {
    const float4 xv = ((const float4*)x)[i];
    const float4 gv = ((const float4*)g)[i];
    float4 o;
    o.x = xv.x - lr * gv.x; o.y = xv.y - lr * gv.y;
    o.z = xv.z - lr * gv.z; o.w = xv.w - lr * gv.w;
    ((float4*)out)[i] = o;
  }
}

// ------------------------------------------------------------------
extern "C" void kernel_launch(void* const* d_in, const int* in_sizes, int n_in,
                              void* d_out, int out_size, void* d_ws, size_t ws_size,
                              hipStream_t stream)
{
  const float* x     = (const float*)d_in[0];
  const float* gamma = (const float*)d_in[1];
  const float* delta = (const float*)d_in[2];
  const float* wk    = (const float*)d_in[3];
  const float* wq    = (const float*)d_in[4];
  const float* xi    = (const float*)d_in[5];
  float* out = (float*)d_out;

  const size_t NE = (size_t)TOK * DIM;
  const size_t NP = (size_t)MPAD * DIM;

  double* eparts = (double*)d_ws;                // 2040 doubles
  float* fp = (float*)(eparts + EP_TOTAL + 8);
  float* xhat = fp;  fp += NE;
  float* grad = fp;  fp += NE;
  float* rstd = fp;  fp += TOK;
  float* chosen = fp; fp += 16;
  __bf16* bp = (__bf16*)(((uintptr_t)fp + 15) & ~(uintptr_t)15);
  __bf16* g_bf   = bp;  bp += NP;
  __bf16* g_tr   = bp;  bp += 4 * NP;
  __bf16* Kb_bf  = bp;  bp += NP;
  __bf16* Qb_bf  = bp;  bp += NP;
  __bf16* dQg_bf = bp;  bp += NP;
  __bf16* dKg_bf = bp;  bp += NP;
  __bf16* rh_bf  = bp;  bp += (size_t)MPAD * MXI;
  __bf16* wk_bf  = bp;  bp += (size_t)DIM * DIM;
  __bf16* wq_bf  = bp;  bp += (size_t)DIM * DIM;
  __bf16* wkT_bf = bp;  bp += (size_t)DIM * DIM;
  __bf16* wqT_bf = bp;  bp += (size_t)DIM * DIM;
  __bf16* xi_bf  = bp;  bp += (size_t)MXI * DIM;
  __bf16* xiT_bf = bp;  bp += (size_t)DIM * MXI;
  __bf16* P_bf   = bp;  bp += (size_t)96 * PAREA;
  __bf16* PT_bf  = bp;  bp += (size_t)96 * PAREA;
  __bf16* KbT_bf = bp;  bp += 4 * NP;
  __bf16* QbT_bf = bp;  bp += 4 * NP;
  unsigned char* g8 = (unsigned char*)bp;  bp += 2 * NP;       // 4*NP bytes
  unsigned char* xi8 = (unsigned char*)bp; bp += (size_t)MXI * DIM / 2;  // MXI*DIM bytes
  // dG split-K partials alias KbT/QbT (consumed by ln_bwd BEFORE the trial
  // KQ GEMM overwrites): 3*NP floats = 6*NP bf16 <= 8*NP available.
  float* dGp0 = (float*)KbT_bf;
  float* dGp1 = dGp0 + NP;
  float* dGp2 = dGp1 + NP;

  const int n4 = (int)(NE / 4);
  dim3 blk(256);
  dim3 gKQ(DIM / 128, MPAD / 128, 2);       // (6,13,2)
  dim3 gHop(MXI / 128, MPAD / 128);         // (24,13)
  dim3 gBwd(DIM / 128, MPAD / 128, 3);      // (6,13,3)
  dim3 gKQt(DIM / 128, 4 * MPAD / 128, 2);  // (6,52,2)
  dim3 gHopT(MXI / 128, 4 * MPAD / 128);    // (24,52)
  const int CV = 2 * (DIM * DIM / 4) + MXI * DIM / 4;  // 884736

  // ---- setup ----
  hipLaunchKernelGGL(init_k, dim3(((MPAD - TOK) * DIM + 255) / 256), blk, 0, stream,
                     g_bf, g_tr, g8, dQg_bf, dKg_bf);
  hipLaunchKernelGGL(cvtall_k, dim3((CV + 255) / 256), blk, 0, stream,
                     wk, wq, xi, wk_bf, wq_bf, xi_bf, (int*)xi8);
  hipLaunchKernelGGL(cvtTall_k, dim3(DIM / 32, MXI / 32, 3), blk, 0, stream,
                     wk, wq, xi, wkT_bf, wqT_bf, xiT_bf);

  // ---- base forward ----
  hipLaunchKernelGGL(ln_fwd_k, dim3(TOK), blk, 0, stream, x, gamma, delta, g_bf, xhat, rstd);
  hipLaunchKernelGGL(gemm_k<4>, gKQ, blk, 0, stream,
                     g_bf, wk_bf, DIM, wq_bf, (float*)Kb_bf, Qb_bf, DIM, (double*)nullptr);
  hipLaunchKernelGGL(attn_mfma_k<1>, dim3(96), blk, 0, stream, Kb_bf, Qb_bf, P_bf, eparts);
  hipLaunchKernelGGL(gemm_k<1>, gHop, blk, 0, stream,
                     g_bf, xi_bf, DIM, (const __bf16*)nullptr,
                     (float*)nullptr, rh_bf, MXI, eparts);
  // ---- backward ----
  hipLaunchKernelGGL(ptrans_k, dim3(96, 7, 7), blk, 0, stream, P_bf, PT_bf);
  hipLaunchKernelGGL(attn_bwd_k, dim3(96, 2), blk, 0, stream,
                     Kb_bf, Qb_bf, P_bf, PT_bf, dQg_bf, dKg_bf);
  hipLaunchKernelGGL(gemm_bwd_k, gBwd, blk, 0, stream,
                     dQg_bf, wqT_bf, dKg_bf, wkT_bf, rh_bf, xiT_bf, dGp0, dGp1, dGp2);
  hipLaunchKernelGGL(ln_bwd_k, dim3(TOK), blk, 0, stream,
                     dGp0, dGp1, dGp2, xhat, rstd, gamma, grad);

  // ---- Armijo trials (batched) ----
  hipLaunchKernelGGL(axpyln_k, dim3(TOK, 4), blk, 0, stream, x, grad, gamma, delta, g_tr, g8);
  hipLaunchKernelGGL(gemm_k<4>, gKQt, blk, 0, stream,
                     g_tr, wk_bf, DIM, wq_bf, (float*)KbT_bf, QbT_bf, DIM, (double*)nullptr);
  hipLaunchKernelGGL(attn_mfma_k<0>, dim3(96, 4), blk, 0, stream,
                     KbT_bf, QbT_bf, (__bf16*)nullptr, eparts);
  hipLaunchKernelGGL(gemm8_k, gHopT, blk, 0, stream, g8, xi8, eparts);

  // ---- reduce+choose, final update ----
  hipLaunchKernelGGL(reduce_choose_k, dim3(1), blk, 0, stream, eparts, chosen);
  hipLaunchKernelGGL(update_k, dim3((n4 + 255) / 256), blk, 0, stream, x, grad, chosen, out, n4);
}